// Round 8
// baseline (693.077 us; speedup 1.0000x reference)
//
#include <hip/hip_runtime.h>
#include <math.h>

// ---------------------------------------------------------------------------
// GraphUNet + GAT pipeline. N=4096, E=65536, IN=3, H=64, OUT=128, HEADS=4
// Round 8: dispatch-count reduction. Direct CSR build from edges (no dense
// A0), fused top-k (rank+perm+vals+invp in one kernel), fused unpool,
// Cp zeroing folded into build_yT, direct-store bt projections.
// ---------------------------------------------------------------------------

#define TPB 256
#define LDK 88
#define MAXN 128

typedef __attribute__((ext_vector_type(8))) short bf16x8;
typedef __attribute__((ext_vector_type(4))) float f32x4;

__device__ inline ushort f32_to_bf16(float v) {
    unsigned b = __float_as_uint(v);
    return (ushort)((b + 0x7FFF + ((b >> 16) & 1)) >> 16);
}
__device__ inline float bf2f(ushort u) { return __uint_as_float(((unsigned)u) << 16); }

// ---------------- CSR build (direct from edges) ----------------
// slot 0 of each row pre-seeded with the +I self entry (weight 1).
__global__ void csr_init(int n, int* __restrict__ nbr, float* __restrict__ awt) {
    int id = blockIdx.x * TPB + threadIdx.x;
    if (id >= n * MAXN) return;
    int i = id >> 7, slot = id & (MAXN - 1);
    nbr[id] = (slot == 0) ? i : -1;
    awt[id] = (slot == 0) ? 1.0f : 0.0f;
}

__global__ void csr_insert(const int* __restrict__ ei, int E, int* __restrict__ nbr,
                           float* __restrict__ awt, int* __restrict__ deg,
                           int* __restrict__ diag) {
    int e = blockIdx.x * TPB + threadIdx.x;
    if (e >= E) return;
    int src = ei[e];
    int dst = ei[E + e];
    atomicAdd(&deg[dst], 1);
    if (src == dst) diag[src] = 1;
    int base = dst * MAXN;
    for (int p = 0; p < MAXN; ++p) {
        int cur = nbr[base + p];
        if (cur == src) { atomicAdd(&awt[base + p], 1.0f); break; }
        if (cur == -1) {
            int old = atomicCAS(&nbr[base + p], -1, src);
            if (old == -1 || old == src) { atomicAdd(&awt[base + p], 1.0f); break; }
        }
    }
}

__global__ void csr_finalize(const int* __restrict__ nbr, const int* __restrict__ deg,
                             const int* __restrict__ diag, int n, int* __restrict__ acnt,
                             float* __restrict__ dinv, float* __restrict__ selfw) {
    int i = blockIdx.x * TPB + threadIdx.x;
    if (i >= n) return;
    int cnt = 0;
    for (int p = 0; p < MAXN; ++p) {
        if (nbr[i * MAXN + p] == -1) break;
        ++cnt;
    }
    acnt[i] = cnt;
    float sw = diag[i] ? 0.f : 2.f;
    dinv[i] = 1.0f / sqrtf((float)deg[i] + sw);
    selfw[i] = sw;
}

// ---------------- xw projection ----------------
__global__ void xw_gemm(const float* __restrict__ xin, const float* __restrict__ W,
                        float* __restrict__ C, int n, int fin, int f) {
    __shared__ float sW[64 * 128];
    int tid = threadIdx.x;
    for (int t = tid; t < fin * f; t += TPB) sW[t] = W[t];
    __syncthreads();
    int rpb = TPB / f;
    int r = blockIdx.x * rpb + tid / f;
    int c = tid - (tid / f) * f;
    if (r >= n) return;
    const float* xr = xin + (size_t)r * fin;
    float acc = 0.f;
    for (int k = 0; k < fin; ++k) acc += xr[k] * sW[k * f + c];
    C[(size_t)r * f + c] = acc;
}

// ---------------- level-0 GCN: fused sparse SpMV ----------------
__global__ void spmv_gcn(const int* __restrict__ nbr, const float* __restrict__ awt,
                         const int* __restrict__ acnt, const float* __restrict__ xw,
                         const float* __restrict__ dinv, const float* __restrict__ selfw,
                         const float* __restrict__ bias, float* __restrict__ out,
                         int f, int relu) {
    int i = blockIdx.x;
    int o = threadIdx.x;
    __shared__ int sj[MAXN];
    __shared__ float sw_[MAXN];
    int cnt = acnt[i];
    for (int a = o; a < cnt; a += blockDim.x) {
        sj[a] = nbr[i * MAXN + a];
        sw_[a] = awt[i * MAXN + a];
    }
    __syncthreads();
    if (o >= f) return;
    float sum = 0.f;
    for (int a = 0; a < cnt; ++a) {
        int j = sj[a];
        sum += sw_[a] * (xw[(size_t)j * f + o] * dinv[j]);
    }
    float yi = xw[(size_t)i * f + o] * dinv[i];
    sum -= yi;
    float v = dinv[i] * (sum + selfw[i] * yi) + bias[o];
    if (relu) v = fmaxf(v, 0.f);
    out[(size_t)i * f + o] = v;
}

// ---------------- pooling: score (norm inline) + fused top-k ----------------
__global__ void score_kernel2(const float* __restrict__ x, const float* __restrict__ p,
                              float* __restrict__ s, int n) {
    int i = blockIdx.x * TPB + threadIdx.x;
    if (i >= n) return;
    float a = 0.f, nrm = 0.f;
    for (int c = 0; c < 64; ++c) {
        float pc = p[c];
        nrm += pc * pc;
        a += x[(size_t)i * 64 + c] * pc;
    }
    s[i] = tanhf(a / sqrtf(nrm));
}

// rank = #(s[j]>s[i]) + #(s[j]==s[i] && j<i); writes perm/vals/invp in one pass
__global__ void rank_topk_all(const float* __restrict__ s, int n, int k,
                              int* __restrict__ perm, float* __restrict__ vals,
                              int* __restrict__ invp) {
    __shared__ float sj[256];
    int i = blockIdx.x * 256 + threadIdx.x;
    float si = s[i];
    int r = 0;
    for (int j0 = 0; j0 < n; j0 += 256) {
        __syncthreads();
        sj[threadIdx.x] = s[j0 + threadIdx.x];
        __syncthreads();
#pragma unroll 8
        for (int jj = 0; jj < 256; ++jj) {
            float v = sj[jj];
            r += (v > si) || (v == si && (j0 + jj) < i);
        }
    }
    if (r < k) { perm[r] = i; vals[r] = si; invp[i] = r; }
    else invp[i] = -1;
}

__global__ void gather_feat(const float* __restrict__ x, const int* __restrict__ perm,
                            const float* __restrict__ vals, int k, int f, float* __restrict__ h) {
    int id = blockIdx.x * TPB + threadIdx.x;
    if (id >= k * f) return;
    int r = id / f, c = id - r * f;
    h[id] = x[(size_t)perm[r] * f + c] * vals[r];
}

// ---------------- level-1 augment: sparse SpGEMM ----------------
__global__ void spgemm_aug(const int* __restrict__ nbr, const float* __restrict__ awt,
                           const int* __restrict__ acnt, const int* __restrict__ perm,
                           const int* __restrict__ invp, int k,
                           ushort* __restrict__ Chi, ushort* __restrict__ Clo,
                           float* __restrict__ dinv, float* __restrict__ selfw) {
    __shared__ float row[2048];
    int r = blockIdx.x, tid = threadIdx.x;
    int pi = perm[r];
    for (int j = tid; j < k; j += TPB) row[j] = 0.f;
    __syncthreads();
    int cnt = acnt[pi];
    for (int a = 0; a < cnt; ++a) {
        int t = nbr[pi * MAXN + a];
        float w1 = awt[pi * MAXN + a];
        int c2 = acnt[t];
        for (int b = tid; b < c2; b += TPB) {
            int s = nbr[t * MAXN + b];
            int j = invp[s];
            if (j >= 0) atomicAdd(&row[j], w1 * awt[t * MAXN + b]);
        }
    }
    __syncthreads();
    float psum = 0.f;
    for (int j = tid; j < k; j += TPB) {
        float v = (j == r) ? 0.f : row[j];
        psum += v;
        ushort hi = f32_to_bf16(v);
        size_t o = (size_t)r * k + j;
        Chi[o] = hi;
        Clo[o] = f32_to_bf16(v - bf2f(hi));
    }
    for (int o = 32; o; o >>= 1) psum += __shfl_xor(psum, o);
    __shared__ float sh[4];
    if ((tid & 63) == 0) sh[tid >> 6] = psum;
    __syncthreads();
    if (tid == 0) {
        float tot = sh[0] + sh[1] + sh[2] + sh[3];
        dinv[r] = 1.0f / sqrtf(tot + 2.0f);
        selfw[r] = 2.0f;
    }
}

// ---------------- dense augment (levels 2,3): split-K + finalize -----------
__global__ void transpose_aug_hl(const ushort* __restrict__ Ahi, const ushort* __restrict__ Alo,
                                 ushort* __restrict__ T, int n) {
    __shared__ float tile[64][65];
    int c0 = blockIdx.x * 64, r0 = blockIdx.y * 64;
    for (int t = threadIdx.x; t < 4096; t += TPB) {
        int r = t >> 6, c = t & 63;
        size_t o = (size_t)(r0 + r) * n + (c0 + c);
        float v = bf2f(Ahi[o]) + bf2f(Alo[o]);
        if (r0 + r == c0 + c) v += 1.0f;
        tile[c][r] = v;
    }
    __syncthreads();
    for (int t = threadIdx.x; t < 4096; t += TPB) {
        int c = t >> 6, r = t & 63;
        T[(size_t)(c0 + c) * n + (r0 + r)] = f32_to_bf16(tile[c][r]);
    }
}

__global__ void gather_rows_aug_hl(const ushort* __restrict__ Ahi, const ushort* __restrict__ Alo,
                                   const int* __restrict__ perm, ushort* __restrict__ Ag,
                                   int n, int rows) {
    int id = blockIdx.x * TPB + threadIdx.x;
    if (id >= rows * n) return;
    int r = id / n, t = id - r * n;
    int pr = perm[r];
    size_t o = (size_t)pr * n + t;
    float v = bf2f(Ahi[o]) + bf2f(Alo[o]);
    if (pr == t) v += 1.0f;
    Ag[id] = f32_to_bf16(v);
}

__global__ void gather_rows_u16(const ushort* __restrict__ T, const int* __restrict__ perm,
                                ushort* __restrict__ Bg, int n, int rows) {
    int id = blockIdx.x * TPB + threadIdx.x;
    if (id >= rows * n) return;
    int r = id / n, t = id - r * n;
    Bg[id] = T[(size_t)perm[r] * n + t];
}

__global__ void __launch_bounds__(256)
aug_gemm_acc(const ushort* __restrict__ Ag, const ushort* __restrict__ Bg,
             float* __restrict__ Caug, int K, int ldc, int kpb) {
    __shared__ __align__(16) ushort As[64 * LDK];
    __shared__ __align__(16) ushort Bs[64 * LDK];
    int tid = threadIdx.x;
    int wave = tid >> 6, lane = tid & 63;
    int wr = wave >> 1, wc = wave & 1;
    int m = lane & 15, quad = lane >> 4;
    int i0 = blockIdx.y * 64, j0 = blockIdx.x * 64;
    int kbeg = blockIdx.z * kpb;
    f32x4 acc[2][2];
#pragma unroll
    for (int a = 0; a < 2; ++a)
#pragma unroll
        for (int b = 0; b < 2; ++b) acc[a][b] = (f32x4){0.f, 0.f, 0.f, 0.f};
    const ushort* Ab = Ag + (size_t)i0 * K;
    const ushort* Bb = Bg + (size_t)j0 * K;
    for (int k0 = kbeg; k0 < kbeg + kpb; k0 += 64) {
#pragma unroll
        for (int v = 0; v < 2; ++v) {
            int idx = tid + (v << 8);
            int r = idx >> 3, c8 = idx & 7;
            *(uint4*)&As[r * LDK + c8 * 8] = *(const uint4*)&Ab[(size_t)r * K + k0 + c8 * 8];
            *(uint4*)&Bs[r * LDK + c8 * 8] = *(const uint4*)&Bb[(size_t)r * K + k0 + c8 * 8];
        }
        __syncthreads();
#pragma unroll
        for (int kk = 0; kk < 2; ++kk) {
            bf16x8 af[2], bfr[2];
#pragma unroll
            for (int mi = 0; mi < 2; ++mi)
                af[mi] = *(const bf16x8*)&As[(wr * 32 + mi * 16 + m) * LDK + kk * 32 + quad * 8];
#pragma unroll
            for (int ni = 0; ni < 2; ++ni)
                bfr[ni] = *(const bf16x8*)&Bs[(wc * 32 + ni * 16 + m) * LDK + kk * 32 + quad * 8];
#pragma unroll
            for (int mi = 0; mi < 2; ++mi)
#pragma unroll
                for (int ni = 0; ni < 2; ++ni)
                    acc[mi][ni] = __builtin_amdgcn_mfma_f32_16x16x32_bf16(
                        af[mi], bfr[ni], acc[mi][ni], 0, 0, 0);
        }
        __syncthreads();
    }
#pragma unroll
    for (int mi = 0; mi < 2; ++mi)
#pragma unroll
        for (int ni = 0; ni < 2; ++ni)
#pragma unroll
            for (int r = 0; r < 4; ++r) {
                int gi = i0 + wr * 32 + mi * 16 + quad * 4 + r;
                int gj = j0 + wc * 32 + ni * 16 + m;
                atomicAdd(&Caug[(size_t)gi * ldc + gj], acc[mi][ni][r]);
            }
}

__global__ void aug_finalize(const float* __restrict__ Caug, int k,
                             ushort* __restrict__ Chi, ushort* __restrict__ Clo,
                             float* __restrict__ dinv, float* __restrict__ selfw) {
    int r = blockIdx.x, tid = threadIdx.x;
    const float* row = Caug + (size_t)r * k;
    float psum = 0.f;
    for (int j = tid; j < k; j += TPB) {
        float v = (j == r) ? 0.f : row[j];
        psum += v;
        ushort hi = f32_to_bf16(v);
        size_t o = (size_t)r * k + j;
        Chi[o] = hi;
        Clo[o] = f32_to_bf16(v - bf2f(hi));
    }
    for (int o = 32; o; o >>= 1) psum += __shfl_xor(psum, o);
    __shared__ float sh[4];
    if ((tid & 63) == 0) sh[tid >> 6] = psum;
    __syncthreads();
    if (tid == 0) {
        float tot = sh[0] + sh[1] + sh[2] + sh[3];
        dinv[r] = 1.0f / sqrtf(tot + 2.0f);
        selfw[r] = 2.0f;
    }
}

// ---------------- dense GCN aggregation (levels >=1) ----------------
__global__ void __launch_bounds__(256)
gcn_gemm(const ushort* __restrict__ Ahi, const ushort* __restrict__ Alo,
         const ushort* __restrict__ Bhi, const ushort* __restrict__ Blo,
         float* __restrict__ C, int K, int ldc, int kpb) {
    __shared__ __align__(16) ushort sAh[64 * LDK];
    __shared__ __align__(16) ushort sAl[64 * LDK];
    __shared__ __align__(16) ushort sBh[64 * LDK];
    __shared__ __align__(16) ushort sBl[64 * LDK];
    int tid = threadIdx.x;
    int wave = tid >> 6, lane = tid & 63;
    int wr = wave >> 1, wc = wave & 1;
    int m = lane & 15, quad = lane >> 4;
    int i0 = blockIdx.y * 64, j0 = blockIdx.x * 64;
    int kbeg = blockIdx.z * kpb;
    f32x4 acc[2][2];
#pragma unroll
    for (int a = 0; a < 2; ++a)
#pragma unroll
        for (int b = 0; b < 2; ++b) acc[a][b] = (f32x4){0.f, 0.f, 0.f, 0.f};
    for (int k0 = kbeg; k0 < kbeg + kpb; k0 += 64) {
#pragma unroll
        for (int v = 0; v < 2; ++v) {
            int idx = tid + (v << 8);
            int r = idx >> 3, c8 = idx & 7;
            size_t boff = (size_t)(j0 + r) * K + k0 + c8 * 8;
            *(uint4*)&sBh[r * LDK + c8 * 8] = *(const uint4*)&Bhi[boff];
            *(uint4*)&sBl[r * LDK + c8 * 8] = *(const uint4*)&Blo[boff];
            size_t aoff = (size_t)(i0 + r) * K + k0 + c8 * 8;
            *(uint4*)&sAh[r * LDK + c8 * 8] = *(const uint4*)&Ahi[aoff];
            *(uint4*)&sAl[r * LDK + c8 * 8] = *(const uint4*)&Alo[aoff];
        }
        __syncthreads();
#pragma unroll
        for (int kk = 0; kk < 2; ++kk) {
            bf16x8 ah[2], al[2], bh[2], bl[2];
#pragma unroll
            for (int mi = 0; mi < 2; ++mi) {
                ah[mi] = *(const bf16x8*)&sAh[(wr * 32 + mi * 16 + m) * LDK + kk * 32 + quad * 8];
                al[mi] = *(const bf16x8*)&sAl[(wr * 32 + mi * 16 + m) * LDK + kk * 32 + quad * 8];
            }
#pragma unroll
            for (int ni = 0; ni < 2; ++ni) {
                bh[ni] = *(const bf16x8*)&sBh[(wc * 32 + ni * 16 + m) * LDK + kk * 32 + quad * 8];
                bl[ni] = *(const bf16x8*)&sBl[(wc * 32 + ni * 16 + m) * LDK + kk * 32 + quad * 8];
            }
#pragma unroll
            for (int mi = 0; mi < 2; ++mi)
#pragma unroll
                for (int ni = 0; ni < 2; ++ni) {
                    acc[mi][ni] = __builtin_amdgcn_mfma_f32_16x16x32_bf16(ah[mi], bh[ni], acc[mi][ni], 0, 0, 0);
                    acc[mi][ni] = __builtin_amdgcn_mfma_f32_16x16x32_bf16(ah[mi], bl[ni], acc[mi][ni], 0, 0, 0);
                    acc[mi][ni] = __builtin_amdgcn_mfma_f32_16x16x32_bf16(al[mi], bh[ni], acc[mi][ni], 0, 0, 0);
                }
        }
        __syncthreads();
    }
#pragma unroll
    for (int mi = 0; mi < 2; ++mi)
#pragma unroll
        for (int ni = 0; ni < 2; ++ni)
#pragma unroll
            for (int r = 0; r < 4; ++r) {
                int gi = i0 + wr * 32 + mi * 16 + quad * 4 + r;
                int gj = j0 + wc * 32 + ni * 16 + m;
                atomicAdd(&C[(size_t)gi * ldc + gj], acc[mi][ni][r]);
            }
}

// build yT hi/lo AND zero the Cp accumulator (same n x f index space)
__global__ void build_yT_z(const float* __restrict__ xw, const float* __restrict__ dinv,
                           ushort* __restrict__ Bhi, ushort* __restrict__ Blo,
                           float* __restrict__ Cp, int n, int f) {
    __shared__ float t[64][65];
    int k0 = blockIdx.x * 64, c0 = blockIdx.y * 64;
#pragma unroll
    for (int v = 0; v < 16; ++v) {
        int idx = threadIdx.x + v * 256;
        int r = idx >> 6, c = idx & 63;
        t[r][c] = xw[(size_t)(k0 + r) * f + (c0 + c)] * dinv[k0 + r];
        Cp[(size_t)(k0 + r) * f + (c0 + c)] = 0.f;
    }
    __syncthreads();
#pragma unroll
    for (int v = 0; v < 16; ++v) {
        int idx = threadIdx.x + v * 256;
        int c = idx >> 6, k = idx & 63;
        float val = t[k][c];
        ushort hi = f32_to_bf16(val);
        size_t o = (size_t)(c0 + c) * n + (k0 + k);
        Bhi[o] = hi;
        Blo[o] = f32_to_bf16(val - bf2f(hi));
    }
}

__global__ void gcn_epilogue(const float* __restrict__ C, const float* __restrict__ xw,
                             const float* __restrict__ dinv, const float* __restrict__ selfw,
                             const float* __restrict__ b, float* __restrict__ out,
                             int n, int f, int relu) {
    int id = blockIdx.x * TPB + threadIdx.x;
    if (id >= n * f) return;
    int i = id / f, c = id - i * f;
    float y = xw[id] * dinv[i];
    float v = dinv[i] * (C[id] + selfw[i] * y) + b[c];
    if (relu) v = fmaxf(v, 0.f);
    out[id] = v;
}

// ---------------- up path: fused unpool (copy + scatter-add) ----------------
__global__ void unpool_add(const float* __restrict__ xsrc, const float* __restrict__ h,
                           const int* __restrict__ invp, int n, int f, float* __restrict__ t) {
    int id = blockIdx.x * TPB + threadIdx.x;
    if (id >= n * f) return;
    int i = id / f, c = id - i * f;
    int r = invp[i];
    float v = xsrc[id];
    if (r >= 0) v += h[(size_t)r * f + c];
    t[id] = v;
}

// ---------------- layernorm ----------------
__global__ void layernorm(const float* __restrict__ h, const float* __restrict__ g,
                          const float* __restrict__ b, float* __restrict__ u, int n) {
    int i = blockIdx.x;
    int t = threadIdx.x;
    float v = h[(size_t)i * 128 + t];
    __shared__ float s0[2], s1[2];
    float sum = v;
    for (int o = 32; o; o >>= 1) sum += __shfl_xor(sum, o);
    if ((t & 63) == 0) s0[t >> 6] = sum;
    __syncthreads();
    float mu = (s0[0] + s0[1]) * (1.0f / 128.0f);
    float d = v - mu;
    float sq = d * d;
    for (int o = 32; o; o >>= 1) sq += __shfl_xor(sq, o);
    if ((t & 63) == 0) s1[t >> 6] = sq;
    __syncthreads();
    float var = (s1[0] + s1[1]) * (1.0f / 128.0f);
    u[(size_t)i * 128 + t] = d / sqrtf(var + 1e-6f) * g[t] + b[t];
}

// ---------------- dense projections via split-bf16 MFMA --------------------
__global__ void transpose_split(const float* __restrict__ W, ushort* __restrict__ Bhi,
                                ushort* __restrict__ Blo, int K, int N) {
    __shared__ float tile[64][65];
    int n0 = blockIdx.x * 64, k0 = blockIdx.y * 64;
    for (int t = threadIdx.x; t < 4096; t += TPB) {
        int r = t >> 6, c = t & 63;
        tile[r][c] = W[(size_t)(k0 + r) * N + (n0 + c)];
    }
    __syncthreads();
    for (int t = threadIdx.x; t < 4096; t += TPB) {
        int c = t >> 6, r = t & 63;
        float v = tile[r][c];
        ushort hi = f32_to_bf16(v);
        size_t o = (size_t)(n0 + c) * K + (k0 + r);
        Bhi[o] = hi;
        Blo[o] = f32_to_bf16(v - bf2f(hi));
    }
}

// direct-store variant (z=1): C[i][j] = sum_k A[i][k]*B[j][k] + bias
__global__ void __launch_bounds__(256)
gemm_bt_store(const float* __restrict__ A, const ushort* __restrict__ Bhi,
              const ushort* __restrict__ Blo, const float* __restrict__ bias,
              float* __restrict__ C, int K, int N) {
    __shared__ __align__(16) ushort sAh[64 * LDK];
    __shared__ __align__(16) ushort sAl[64 * LDK];
    __shared__ __align__(16) ushort sBh[64 * LDK];
    __shared__ __align__(16) ushort sBl[64 * LDK];
    int tid = threadIdx.x;
    int wave = tid >> 6, lane = tid & 63;
    int wr = wave >> 1, wc = wave & 1;
    int m = lane & 15, quad = lane >> 4;
    int i0 = blockIdx.y * 64, j0 = blockIdx.x * 64;
    f32x4 acc[2][2];
#pragma unroll
    for (int a = 0; a < 2; ++a)
#pragma unroll
        for (int b = 0; b < 2; ++b) acc[a][b] = (f32x4){0.f, 0.f, 0.f, 0.f};
    for (int k0 = 0; k0 < K; k0 += 64) {
#pragma unroll
        for (int v = 0; v < 2; ++v) {
            int idx = tid + (v << 8);
            int r = idx >> 3, c8 = idx & 7;
            size_t boff = (size_t)(j0 + r) * K + k0 + c8 * 8;
            *(uint4*)&sBh[r * LDK + c8 * 8] = *(const uint4*)&Bhi[boff];
            *(uint4*)&sBl[r * LDK + c8 * 8] = *(const uint4*)&Blo[boff];
            size_t aoff = (size_t)(i0 + r) * K + k0 + c8 * 8;
            float4 fa = *(const float4*)&A[aoff];
            float4 fb = *(const float4*)&A[aoff + 4];
            ushort h0 = f32_to_bf16(fa.x), h1 = f32_to_bf16(fa.y);
            ushort h2 = f32_to_bf16(fa.z), h3 = f32_to_bf16(fa.w);
            ushort h4 = f32_to_bf16(fb.x), h5 = f32_to_bf16(fb.y);
            ushort h6 = f32_to_bf16(fb.z), h7 = f32_to_bf16(fb.w);
            uint4 ph, pl;
            ph.x = (uint)h0 | ((uint)h1 << 16);
            ph.y = (uint)h2 | ((uint)h3 << 16);
            ph.z = (uint)h4 | ((uint)h5 << 16);
            ph.w = (uint)h6 | ((uint)h7 << 16);
            pl.x = (uint)f32_to_bf16(fa.x - bf2f(h0)) | ((uint)f32_to_bf16(fa.y - bf2f(h1)) << 16);
            pl.y = (uint)f32_to_bf16(fa.z - bf2f(h2)) | ((uint)f32_to_bf16(fa.w - bf2f(h3)) << 16);
            pl.z = (uint)f32_to_bf16(fb.x - bf2f(h4)) | ((uint)f32_to_bf16(fb.y - bf2f(h5)) << 16);
            pl.w = (uint)f32_to_bf16(fb.z - bf2f(h6)) | ((uint)f32_to_bf16(fb.w - bf2f(h7)) << 16);
            *(uint4*)&sAh[r * LDK + c8 * 8] = ph;
            *(uint4*)&sAl[r * LDK + c8 * 8] = pl;
        }
        __syncthreads();
#pragma unroll
        for (int kk = 0; kk < 2; ++kk) {
            bf16x8 ah[2], al[2], bh[2], bl[2];
#pragma unroll
            for (int mi = 0; mi < 2; ++mi) {
                ah[mi] = *(const bf16x8*)&sAh[(wr * 32 + mi * 16 + m) * LDK + kk * 32 + quad * 8];
                al[mi] = *(const bf16x8*)&sAl[(wr * 32 + mi * 16 + m) * LDK + kk * 32 + quad * 8];
            }
#pragma unroll
            for (int ni = 0; ni < 2; ++ni) {
                bh[ni] = *(const bf16x8*)&sBh[(wc * 32 + ni * 16 + m) * LDK + kk * 32 + quad * 8];
                bl[ni] = *(const bf16x8*)&sBl[(wc * 32 + ni * 16 + m) * LDK + kk * 32 + quad * 8];
            }
#pragma unroll
            for (int mi = 0; mi < 2; ++mi)
#pragma unroll
                for (int ni = 0; ni < 2; ++ni) {
                    acc[mi][ni] = __builtin_amdgcn_mfma_f32_16x16x32_bf16(ah[mi], bh[ni], acc[mi][ni], 0, 0, 0);
                    acc[mi][ni] = __builtin_amdgcn_mfma_f32_16x16x32_bf16(ah[mi], bl[ni], acc[mi][ni], 0, 0, 0);
                    acc[mi][ni] = __builtin_amdgcn_mfma_f32_16x16x32_bf16(al[mi], bh[ni], acc[mi][ni], 0, 0, 0);
                }
        }
        __syncthreads();
    }
#pragma unroll
    for (int mi = 0; mi < 2; ++mi)
#pragma unroll
        for (int ni = 0; ni < 2; ++ni)
#pragma unroll
            for (int r = 0; r < 4; ++r) {
                int gi = i0 + wr * 32 + mi * 16 + quad * 4 + r;
                int gj = j0 + wc * 32 + ni * 16 + m;
                float v = acc[mi][ni][r];
                if (bias) v += bias[gj];
                C[(size_t)gi * N + gj] = v;
            }
}

// split-K atomic variant (hf2)
__global__ void __launch_bounds__(256)
gemm_bt_split(const float* __restrict__ A, const ushort* __restrict__ Bhi,
              const ushort* __restrict__ Blo, float* __restrict__ C,
              int K, int N, int kpb) {
    __shared__ __align__(16) ushort sAh[64 * LDK];
    __shared__ __align__(16) ushort sAl[64 * LDK];
    __shared__ __align__(16) ushort sBh[64 * LDK];
    __shared__ __align__(16) ushort sBl[64 * LDK];
    int tid = threadIdx.x;
    int wave = tid >> 6, lane = tid & 63;
    int wr = wave >> 1, wc = wave & 1;
    int m = lane & 15, quad = lane >> 4;
    int i0 = blockIdx.y * 64, j0 = blockIdx.x * 64;
    int kbeg = blockIdx.z * kpb;
    f32x4 acc[2][2];
#pragma unroll
    for (int a = 0; a < 2; ++a)
#pragma unroll
        for (int b = 0; b < 2; ++b) acc[a][b] = (f32x4){0.f, 0.f, 0.f, 0.f};
    for (int k0 = kbeg; k0 < kbeg + kpb; k0 += 64) {
#pragma unroll
        for (int v = 0; v < 2; ++v) {
            int idx = tid + (v << 8);
            int r = idx >> 3, c8 = idx & 7;
            size_t boff = (size_t)(j0 + r) * K + k0 + c8 * 8;
            *(uint4*)&sBh[r * LDK + c8 * 8] = *(const uint4*)&Bhi[boff];
            *(uint4*)&sBl[r * LDK + c8 * 8] = *(const uint4*)&Blo[boff];
            size_t aoff = (size_t)(i0 + r) * K + k0 + c8 * 8;
            float4 fa = *(const float4*)&A[aoff];
            float4 fb = *(const float4*)&A[aoff + 4];
            ushort h0 = f32_to_bf16(fa.x), h1 = f32_to_bf16(fa.y);
            ushort h2 = f32_to_bf16(fa.z), h3 = f32_to_bf16(fa.w);
            ushort h4 = f32_to_bf16(fb.x), h5 = f32_to_bf16(fb.y);
            ushort h6 = f32_to_bf16(fb.z), h7 = f32_to_bf16(fb.w);
            uint4 ph, pl;
            ph.x = (uint)h0 | ((uint)h1 << 16);
            ph.y = (uint)h2 | ((uint)h3 << 16);
            ph.z = (uint)h4 | ((uint)h5 << 16);
            ph.w = (uint)h6 | ((uint)h7 << 16);
            pl.x = (uint)f32_to_bf16(fa.x - bf2f(h0)) | ((uint)f32_to_bf16(fa.y - bf2f(h1)) << 16);
            pl.y = (uint)f32_to_bf16(fa.z - bf2f(h2)) | ((uint)f32_to_bf16(fa.w - bf2f(h3)) << 16);
            pl.z = (uint)f32_to_bf16(fb.x - bf2f(h4)) | ((uint)f32_to_bf16(fb.y - bf2f(h5)) << 16);
            pl.w = (uint)f32_to_bf16(fb.z - bf2f(h6)) | ((uint)f32_to_bf16(fb.w - bf2f(h7)) << 16);
            *(uint4*)&sAh[r * LDK + c8 * 8] = ph;
            *(uint4*)&sAl[r * LDK + c8 * 8] = pl;
        }
        __syncthreads();
#pragma unroll
        for (int kk = 0; kk < 2; ++kk) {
            bf16x8 ah[2], al[2], bh[2], bl[2];
#pragma unroll
            for (int mi = 0; mi < 2; ++mi) {
                ah[mi] = *(const bf16x8*)&sAh[(wr * 32 + mi * 16 + m) * LDK + kk * 32 + quad * 8];
                al[mi] = *(const bf16x8*)&sAl[(wr * 32 + mi * 16 + m) * LDK + kk * 32 + quad * 8];
            }
#pragma unroll
            for (int ni = 0; ni < 2; ++ni) {
                bh[ni] = *(const bf16x8*)&sBh[(wc * 32 + ni * 16 + m) * LDK + kk * 32 + quad * 8];
                bl[ni] = *(const bf16x8*)&sBl[(wc * 32 + ni * 16 + m) * LDK + kk * 32 + quad * 8];
            }
#pragma unroll
            for (int mi = 0; mi < 2; ++mi)
#pragma unroll
                for (int ni = 0; ni < 2; ++ni) {
                    acc[mi][ni] = __builtin_amdgcn_mfma_f32_16x16x32_bf16(ah[mi], bh[ni], acc[mi][ni], 0, 0, 0);
                    acc[mi][ni] = __builtin_amdgcn_mfma_f32_16x16x32_bf16(ah[mi], bl[ni], acc[mi][ni], 0, 0, 0);
                    acc[mi][ni] = __builtin_amdgcn_mfma_f32_16x16x32_bf16(al[mi], bh[ni], acc[mi][ni], 0, 0, 0);
                }
        }
        __syncthreads();
    }
#pragma unroll
    for (int mi = 0; mi < 2; ++mi)
#pragma unroll
        for (int ni = 0; ni < 2; ++ni)
#pragma unroll
            for (int r = 0; r < 4; ++r) {
                int gi = i0 + wr * 32 + mi * 16 + quad * 4 + r;
                int gj = j0 + wc * 32 + ni * 16 + m;
                atomicAdd(&C[(size_t)gi * N + gj], acc[mi][ni][r]);
            }
}

// ---------------- GAT ----------------
__global__ void attn_coef2(const float* __restrict__ hf, const float* __restrict__ asrc,
                           const float* __restrict__ adst, float* __restrict__ es,
                           float* __restrict__ ed, int heads) {
    int j = blockIdx.x;
    int wave = threadIdx.x >> 6, lane = threadIdx.x & 63;
    if (wave >= heads) return;
    const float* hp = hf + (size_t)j * heads * 128 + wave * 128;
    float v0 = hp[lane], v1 = hp[lane + 64];
    float a = v0 * asrc[wave * 128 + lane] + v1 * asrc[wave * 128 + lane + 64];
    float d = v0 * adst[wave * 128 + lane] + v1 * adst[wave * 128 + lane + 64];
    for (int o = 32; o; o >>= 1) { a += __shfl_xor(a, o); d += __shfl_xor(d, o); }
    if (lane == 0) { es[j * heads + wave] = a; ed[j * heads + wave] = d; }
}

__global__ void gat_sparse(const int* __restrict__ nbr, const int* __restrict__ ncnt, int n,
                           const float* __restrict__ hf, const float* __restrict__ es,
                           const float* __restrict__ ed, const float* __restrict__ bias,
                           const float* __restrict__ resid, float* __restrict__ out,
                           int heads, int mode) {
    int i = blockIdx.x;
    int tid = threadIdx.x;
    __shared__ int idx[MAXN];
    __shared__ float lg[MAXN * 4];
    __shared__ float hmax[4], hsum[4];
    int m = ncnt[i];
    for (int t = tid; t < m; t += TPB) idx[t] = nbr[i * MAXN + t];
    __syncthreads();
    for (int t = tid; t < m * heads; t += TPB) {
        int jl = t / heads, h = t - jl * heads;
        float l = ed[i * heads + h] + es[idx[jl] * heads + h];
        lg[jl * heads + h] = (l > 0.f) ? l : 0.2f * l;
    }
    __syncthreads();
    int h = tid >> 6, lane = tid & 63;
    if (h < heads) {
        float mx = -3.4e38f;
        for (int jl = lane; jl < m; jl += 64) mx = fmaxf(mx, lg[jl * heads + h]);
        for (int o = 32; o; o >>= 1) mx = fmaxf(mx, __shfl_xor(mx, o));
        if (lane == 0) hmax[h] = mx;
    }
    __syncthreads();
    if (h < heads) {
        float mx = hmax[h];
        float sm = 0.f;
        for (int jl = lane; jl < m; jl += 64) {
            float p = expf(lg[jl * heads + h] - mx);
            lg[jl * heads + h] = p;
            sm += p;
        }
        for (int o = 32; o; o >>= 1) sm += __shfl_xor(sm, o);
        if (lane == 0) hsum[h] = sm;
    }
    __syncthreads();
    int width = heads * 128;
    for (int o = tid; o < width; o += TPB) {
        int hh = o >> 7;
        float acc = 0.f;
        for (int jl = 0; jl < m; ++jl)
            acc += lg[jl * heads + hh] * hf[(size_t)idx[jl] * width + o];
        float v = acc / hsum[hh] + bias[o];
        if (mode == 0) v = (v > 0.f) ? v : expm1f(v);
        else v += resid[(size_t)i * width + o];
        out[(size_t)i * width + o] = v;
    }
}

// ---------------------------------------------------------------------------
static inline int cdiv(int a, int b) { return (a + b - 1) / b; }

static int pick_z(int gx, int gy, int K) {
    int z = 1;
    while (gx * gy * z < 384 && K / (2 * z) >= 64) z <<= 1;
    return z;
}

static void run_gcn_dense(hipStream_t stream, const ushort* Ahi, const ushort* Alo,
                          int n, const float* xin, int fin,
                          const float* W, const float* bias, int f,
                          const float* dinv, const float* selfw,
                          float* xw, ushort* yThi, ushort* yTlo, float* Cp,
                          float* out, int relu) {
    xw_gemm<<<cdiv(n, TPB / f), TPB, 0, stream>>>(xin, W, xw, n, fin, f);
    build_yT_z<<<dim3(n / 64, f / 64), TPB, 0, stream>>>(xw, dinv, yThi, yTlo, Cp, n, f);
    int z = pick_z(f / 64, n / 64, n);
    gcn_gemm<<<dim3(f / 64, n / 64, z), TPB, 0, stream>>>(Ahi, Alo, yThi, yTlo, Cp, n, f, n / z);
    gcn_epilogue<<<cdiv(n * f, TPB), TPB, 0, stream>>>(Cp, xw, dinv, selfw, bias, out, n, f, relu);
}

static void run_gcn_sparse(hipStream_t stream, const int* nbr, const float* awt,
                           const int* acnt, int n, const float* xin, int fin,
                           const float* W, const float* bias, int f,
                           const float* dinv, const float* selfw,
                           float* xw, float* out, int relu) {
    xw_gemm<<<cdiv(n, TPB / f), TPB, 0, stream>>>(xin, W, xw, n, fin, f);
    spmv_gcn<<<n, f, 0, stream>>>(nbr, awt, acnt, xw, dinv, selfw, bias, out, f, relu);
}

static void run_aug_dense(hipStream_t stream, const ushort* Ahi, const ushort* Alo, int n,
                          const int* perm, int k, ushort* Tbf, ushort* Agb, ushort* Bgb,
                          float* Caug, ushort* Chi, ushort* Clo, float* dinv, float* selfw) {
    transpose_aug_hl<<<dim3(n / 64, n / 64), TPB, 0, stream>>>(Ahi, Alo, Tbf, n);
    gather_rows_aug_hl<<<cdiv(k * n, TPB), TPB, 0, stream>>>(Ahi, Alo, perm, Agb, n, k);
    gather_rows_u16<<<cdiv(k * n, TPB), TPB, 0, stream>>>(Tbf, perm, Bgb, n, k);
    hipMemsetAsync(Caug, 0, (size_t)k * k * sizeof(float), stream);
    int z = 8;
    aug_gemm_acc<<<dim3(k / 64, k / 64, z), TPB, 0, stream>>>(Agb, Bgb, Caug, n, k, n / z);
    aug_finalize<<<k, TPB, 0, stream>>>(Caug, k, Chi, Clo, dinv, selfw);
}

extern "C" void kernel_launch(void* const* d_in, const int* in_sizes, int n_in,
                              void* d_out, int out_size, void* d_ws, size_t ws_size,
                              hipStream_t stream) {
    const float* x   = (const float*)d_in[0];
    const int*   ei  = (const int*)d_in[1];
    const float* w0  = (const float*)d_in[2];  const float* b0  = (const float*)d_in[3];
    const float* w1  = (const float*)d_in[4];  const float* b1  = (const float*)d_in[5];
    const float* w2  = (const float*)d_in[6];  const float* b2  = (const float*)d_in[7];
    const float* w3  = (const float*)d_in[8];  const float* b3  = (const float*)d_in[9];
    const float* p1  = (const float*)d_in[10];
    const float* p2  = (const float*)d_in[11];
    const float* p3  = (const float*)d_in[12];
    const float* uw0 = (const float*)d_in[13]; const float* ub0 = (const float*)d_in[14];
    const float* uw1 = (const float*)d_in[15]; const float* ub1 = (const float*)d_in[16];
    const float* uw2 = (const float*)d_in[17]; const float* ub2 = (const float*)d_in[18];
    const float* lng = (const float*)d_in[19]; const float* lnb = (const float*)d_in[20];
    const float* rw  = (const float*)d_in[21]; const float* rb  = (const float*)d_in[22];
    const float* g1w = (const float*)d_in[23];
    const float* g1as = (const float*)d_in[24]; const float* g1ad = (const float*)d_in[25];
    const float* g1b = (const float*)d_in[26];
    const float* g2w = (const float*)d_in[27];
    const float* g2as = (const float*)d_in[28]; const float* g2ad = (const float*)d_in[29];
    const float* g2b = (const float*)d_in[30];

    const int N = 4096, E = 65536;
    const int K1 = 2048, K2 = 1024, K3 = 512;

    float* base = (float*)d_ws;
    size_t off = 0;
    auto alloc = [&](size_t nf) { float* p = base + off; off += (nf + 63) & ~(size_t)63; return p; };

    ushort* A1hi = (ushort*)alloc((size_t)K1 * K1 / 2);
    ushort* A1lo = (ushort*)alloc((size_t)K1 * K1 / 2);
    ushort* A2hi = (ushort*)alloc((size_t)K2 * K2 / 2);
    ushort* A2lo = (ushort*)alloc((size_t)K2 * K2 / 2);
    ushort* A3hi = (ushort*)alloc((size_t)K3 * K3 / 2);
    ushort* A3lo = (ushort*)alloc((size_t)K3 * K3 / 2);
    ushort* Tbf  = (ushort*)alloc((size_t)K1 * K1 / 2);
    ushort* Agb  = (ushort*)alloc((size_t)K2 * K1 / 2);
    ushort* Bgb  = (ushort*)alloc((size_t)K2 * K1 / 2);
    ushort* yThi = (ushort*)alloc((size_t)128 * N / 2);
    ushort* yTlo = (ushort*)alloc((size_t)128 * N / 2);
    ushort* Whi  = (ushort*)alloc((size_t)512 * 128 / 2);
    ushort* Wlo  = (ushort*)alloc((size_t)512 * 128 / 2);
    float* Caug  = alloc((size_t)K2 * K2);
    float* Cp    = alloc((size_t)N * 128);
    float* x0    = alloc((size_t)N * 64);
    float* x1    = alloc((size_t)K1 * 64);
    float* x2    = alloc((size_t)K2 * 64);
    float* x3    = alloc((size_t)K3 * 64);
    float* h1    = alloc((size_t)K1 * 64);
    float* h2    = alloc((size_t)K2 * 64);
    float* h3    = alloc((size_t)K3 * 64);
    float* xw    = alloc((size_t)N * 128);
    float* dinv0 = alloc(N);  float* selfw0 = alloc(N);
    float* dinv1 = alloc(K1); float* selfw1 = alloc(K1);
    float* dinv2 = alloc(K2); float* selfw2 = alloc(K2);
    float* dinv3 = alloc(K3); float* selfw3 = alloc(K3);
    int*   deg   = (int*)alloc(2 * N);       // deg[0..N) + diag[N..2N) contiguous
    int*   diag  = deg + N;
    float* score = alloc(N);
    float* vals1 = alloc(K1); float* vals2 = alloc(K2); float* vals3 = alloc(K3);
    int*   perm1 = (int*)alloc(K1); int* perm2 = (int*)alloc(K2); int* perm3 = (int*)alloc(K3);
    int*   invp1 = (int*)alloc(N);  int* invp2 = (int*)alloc(K1); int* invp3 = (int*)alloc(K2);
    int*   nbr   = (int*)alloc((size_t)N * MAXN);
    float* awt   = alloc((size_t)N * MAXN);
    int*   acnt  = (int*)alloc(N);
    float* t2    = alloc((size_t)K2 * 64);
    float* t1    = alloc((size_t)K1 * 64);
    float* t0    = alloc((size_t)N * 64);
    float* hfin  = alloc((size_t)N * 128);
    float* u     = alloc((size_t)N * 128);
    float* resid = alloc((size_t)N * 128);
    float* hf1   = alloc((size_t)N * 512);
    float* es1   = alloc((size_t)N * 4); float* ed1 = alloc((size_t)N * 4);
    float* g1    = alloc((size_t)N * 512);
    float* hf2   = alloc((size_t)N * 128);
    float* es2   = alloc(N); float* ed2 = alloc(N);
    (void)ws_size; (void)n_in; (void)in_sizes; (void)out_size;

    // ---- CSR build directly from edge list ----
    csr_init<<<cdiv(N * MAXN, TPB), TPB, 0, stream>>>(N, nbr, awt);
    hipMemsetAsync(deg, 0, 2 * N * sizeof(int), stream);
    csr_insert<<<cdiv(E, TPB), TPB, 0, stream>>>(ei, E, nbr, awt, deg, diag);
    csr_finalize<<<cdiv(N, TPB), TPB, 0, stream>>>(nbr, deg, diag, N, acnt, dinv0, selfw0);

    // ---- down level 0 (sparse) ----
    run_gcn_sparse(stream, nbr, awt, acnt, N, x, 3, w0, b0, 64, dinv0, selfw0, xw, x0, 1);

    // ---- level 1: topk + sparse SpGEMM augment ----
    score_kernel2<<<cdiv(N, TPB), TPB, 0, stream>>>(x0, p1, score, N);
    rank_topk_all<<<N / 256, 256, 0, stream>>>(score, N, K1, perm1, vals1, invp1);
    spgemm_aug<<<K1, TPB, 0, stream>>>(nbr, awt, acnt, perm1, invp1, K1,
                                       A1hi, A1lo, dinv1, selfw1);
    gather_feat<<<cdiv(K1 * 64, TPB), TPB, 0, stream>>>(x0, perm1, vals1, K1, 64, h1);
    run_gcn_dense(stream, A1hi, A1lo, K1, h1, 64, w1, b1, 64,
                  dinv1, selfw1, xw, yThi, yTlo, Cp, x1, 1);

    // ---- level 2 (dense split-K augment) ----
    score_kernel2<<<cdiv(K1, TPB), TPB, 0, stream>>>(x1, p2, score, K1);
    rank_topk_all<<<K1 / 256, 256, 0, stream>>>(score, K1, K2, perm2, vals2, invp2);
    run_aug_dense(stream, A1hi, A1lo, K1, perm2, K2, Tbf, Agb, Bgb, Caug,
                  A2hi, A2lo, dinv2, selfw2);
    gather_feat<<<cdiv(K2 * 64, TPB), TPB, 0, stream>>>(x1, perm2, vals2, K2, 64, h2);
    run_gcn_dense(stream, A2hi, A2lo, K2, h2, 64, w2, b2, 64,
                  dinv2, selfw2, xw, yThi, yTlo, Cp, x2, 1);

    // ---- level 3 (dense split-K augment) ----
    score_kernel2<<<cdiv(K2, TPB), TPB, 0, stream>>>(x2, p3, score, K2);
    rank_topk_all<<<K2 / 256, 256, 0, stream>>>(score, K2, K3, perm3, vals3, invp3);
    run_aug_dense(stream, A2hi, A2lo, K2, perm3, K3, Tbf, Agb, Bgb, Caug,
                  A3hi, A3lo, dinv3, selfw3);
    gather_feat<<<cdiv(K3 * 64, TPB), TPB, 0, stream>>>(x2, perm3, vals3, K3, 64, h3);
    run_gcn_dense(stream, A3hi, A3lo, K3, h3, 64, w3, b3, 64,
                  dinv3, selfw3, xw, yThi, yTlo, Cp, x3, 1);

    // ---- up path (fused unpool) ----
    unpool_add<<<cdiv(K2 * 64, TPB), TPB, 0, stream>>>(x2, x3, invp3, K2, 64, t2);
    run_gcn_dense(stream, A2hi, A2lo, K2, t2, 64, uw0, ub0, 64,
                  dinv2, selfw2, xw, yThi, yTlo, Cp, h2, 1);

    unpool_add<<<cdiv(K1 * 64, TPB), TPB, 0, stream>>>(x1, h2, invp2, K1, 64, t1);
    run_gcn_dense(stream, A1hi, A1lo, K1, t1, 64, uw1, ub1, 64,
                  dinv1, selfw1, xw, yThi, yTlo, Cp, h1, 1);

    unpool_add<<<cdiv(N * 64, TPB), TPB, 0, stream>>>(x0, h1, invp1, N, 64, t0);
    run_gcn_sparse(stream, nbr, awt, acnt, N, t0, 64, uw2, ub2, 128,
                   dinv0, selfw0, xw, hfin, 0);

    // ---- layernorm + residual (direct store) ----
    layernorm<<<N, 128, 0, stream>>>(hfin, lng, lnb, u, N);
    transpose_split<<<dim3(2, 2), TPB, 0, stream>>>(rw, Whi, Wlo, 128, 128);
    gemm_bt_store<<<dim3(2, N / 64), TPB, 0, stream>>>(u, Whi, Wlo, rb, resid, 128, 128);

    // ---- GAT layer 1 (4 heads, concat, ELU) ----
    transpose_split<<<dim3(8, 2), TPB, 0, stream>>>(g1w, Whi, Wlo, 128, 512);
    gemm_bt_store<<<dim3(8, N / 64), TPB, 0, stream>>>(u, Whi, Wlo, nullptr, hf1, 128, 512);
    attn_coef2<<<N, 256, 0, stream>>>(hf1, g1as, g1ad, es1, ed1, 4);
    gat_sparse<<<N, TPB, 0, stream>>>(nbr, acnt, N, hf1, es1, ed1, g1b, nullptr, g1, 4, 0);

    // ---- GAT layer 2 (1 head) + residual ----
    transpose_split<<<dim3(2, 8), TPB, 0, stream>>>(g2w, Whi, Wlo, 512, 128);
    hipMemsetAsync(hf2, 0, (size_t)N * 128 * sizeof(float), stream);
    gemm_bt_split<<<dim3(2, N / 64, 4), TPB, 0, stream>>>(g1, Whi, Wlo, hf2, 512, 128, 128);
    attn_coef2<<<N, 64, 0, stream>>>(hf2, g2as, g2ad, es2, ed2, 1);
    gat_sparse<<<N, TPB, 0, stream>>>(nbr, acnt, N, hf2, es2, ed2, g2b, resid, (float*)d_out, 1, 1);
}

// Round 9
// 546.792 us; speedup vs baseline: 1.2675x; 1.2675x over previous
//
#include <hip/hip_runtime.h>
#include <math.h>

// ---------------------------------------------------------------------------
// GraphUNet + GAT pipeline. N=4096, E=65536, IN=3, H=64, OUT=128, HEADS=4
// Round 9: revert top-k to 2D rank_count grid (R8's 1D fusion starved the
// GPU: 16 blocks, 104 µs). invp folded into scatter pass. All other R8
// fusions retained (direct CSR, fused unpool, build_yT_z, direct-store bt).
// ---------------------------------------------------------------------------

#define TPB 256
#define LDK 88
#define MAXN 128

typedef __attribute__((ext_vector_type(8))) short bf16x8;
typedef __attribute__((ext_vector_type(4))) float f32x4;

__device__ inline ushort f32_to_bf16(float v) {
    unsigned b = __float_as_uint(v);
    return (ushort)((b + 0x7FFF + ((b >> 16) & 1)) >> 16);
}
__device__ inline float bf2f(ushort u) { return __uint_as_float(((unsigned)u) << 16); }

// ---------------- CSR build (direct from edges) ----------------
__global__ void csr_init(int n, int* __restrict__ nbr, float* __restrict__ awt) {
    int id = blockIdx.x * TPB + threadIdx.x;
    if (id >= n * MAXN) return;
    int i = id >> 7, slot = id & (MAXN - 1);
    nbr[id] = (slot == 0) ? i : -1;
    awt[id] = (slot == 0) ? 1.0f : 0.0f;
}

__global__ void csr_insert(const int* __restrict__ ei, int E, int* __restrict__ nbr,
                           float* __restrict__ awt, int* __restrict__ deg,
                           int* __restrict__ diag) {
    int e = blockIdx.x * TPB + threadIdx.x;
    if (e >= E) return;
    int src = ei[e];
    int dst = ei[E + e];
    atomicAdd(&deg[dst], 1);
    if (src == dst) diag[src] = 1;
    int base = dst * MAXN;
    for (int p = 0; p < MAXN; ++p) {
        int cur = nbr[base + p];
        if (cur == src) { atomicAdd(&awt[base + p], 1.0f); break; }
        if (cur == -1) {
            int old = atomicCAS(&nbr[base + p], -1, src);
            if (old == -1 || old == src) { atomicAdd(&awt[base + p], 1.0f); break; }
        }
    }
}

__global__ void csr_finalize(const int* __restrict__ nbr, const int* __restrict__ deg,
                             const int* __restrict__ diag, int n, int* __restrict__ acnt,
                             float* __restrict__ dinv, float* __restrict__ selfw) {
    int i = blockIdx.x * TPB + threadIdx.x;
    if (i >= n) return;
    int cnt = 0;
    for (int p = 0; p < MAXN; ++p) {
        if (nbr[i * MAXN + p] == -1) break;
        ++cnt;
    }
    acnt[i] = cnt;
    float sw = diag[i] ? 0.f : 2.f;
    dinv[i] = 1.0f / sqrtf((float)deg[i] + sw);
    selfw[i] = sw;
}

// ---------------- xw projection ----------------
__global__ void xw_gemm(const float* __restrict__ xin, const float* __restrict__ W,
                        float* __restrict__ C, int n, int fin, int f) {
    __shared__ float sW[64 * 128];
    int tid = threadIdx.x;
    for (int t = tid; t < fin * f; t += TPB) sW[t] = W[t];
    __syncthreads();
    int rpb = TPB / f;
    int r = blockIdx.x * rpb + tid / f;
    int c = tid - (tid / f) * f;
    if (r >= n) return;
    const float* xr = xin + (size_t)r * fin;
    float acc = 0.f;
    for (int k = 0; k < fin; ++k) acc += xr[k] * sW[k * f + c];
    C[(size_t)r * f + c] = acc;
}

// ---------------- level-0 GCN: fused sparse SpMV ----------------
__global__ void spmv_gcn(const int* __restrict__ nbr, const float* __restrict__ awt,
                         const int* __restrict__ acnt, const float* __restrict__ xw,
                         const float* __restrict__ dinv, const float* __restrict__ selfw,
                         const float* __restrict__ bias, float* __restrict__ out,
                         int f, int relu) {
    int i = blockIdx.x;
    int o = threadIdx.x;
    __shared__ int sj[MAXN];
    __shared__ float sw_[MAXN];
    int cnt = acnt[i];
    for (int a = o; a < cnt; a += blockDim.x) {
        sj[a] = nbr[i * MAXN + a];
        sw_[a] = awt[i * MAXN + a];
    }
    __syncthreads();
    if (o >= f) return;
    float sum = 0.f;
    for (int a = 0; a < cnt; ++a) {
        int j = sj[a];
        sum += sw_[a] * (xw[(size_t)j * f + o] * dinv[j]);
    }
    float yi = xw[(size_t)i * f + o] * dinv[i];
    sum -= yi;
    float v = dinv[i] * (sum + selfw[i] * yi) + bias[o];
    if (relu) v = fmaxf(v, 0.f);
    out[(size_t)i * f + o] = v;
}

// ---------------- pooling: score + 2D rank-count top-k ----------------
__global__ void score_kernel2(const float* __restrict__ x, const float* __restrict__ p,
                              float* __restrict__ s, int n) {
    int i = blockIdx.x * TPB + threadIdx.x;
    if (i >= n) return;
    float a = 0.f, nrm = 0.f;
    for (int c = 0; c < 64; ++c) {
        float pc = p[c];
        nrm += pc * pc;
        a += x[(size_t)i * 64 + c] * pc;
    }
    s[i] = tanhf(a / sqrtf(nrm));
}

// 2D grid: block (i-chunk, j-chunk); partial ranks accumulated via atomics.
__global__ void rank_count(const float* __restrict__ s, int n, int* __restrict__ rank) {
    __shared__ float sj[256];
    int i = blockIdx.x * 256 + threadIdx.x;
    int j0 = blockIdx.y * 256;
    sj[threadIdx.x] = s[j0 + threadIdx.x];
    float si = s[i];
    __syncthreads();
    int r = 0;
#pragma unroll 8
    for (int jj = 0; jj < 256; ++jj) {
        float v = sj[jj];
        r += (v > si) || (v == si && (j0 + jj) < i);
    }
    atomicAdd(&rank[i], r);
}

// scatter perm/vals AND invp in one pass
__global__ void scatter_topk_all(const float* __restrict__ s, const int* __restrict__ rank,
                                 int n, int k, int* __restrict__ perm,
                                 float* __restrict__ vals, int* __restrict__ invp) {
    int i = blockIdx.x * TPB + threadIdx.x;
    if (i >= n) return;
    int r = rank[i];
    if (r < k) { perm[r] = i; vals[r] = s[i]; invp[i] = r; }
    else invp[i] = -1;
}

__global__ void gather_feat(const float* __restrict__ x, const int* __restrict__ perm,
                            const float* __restrict__ vals, int k, int f, float* __restrict__ h) {
    int id = blockIdx.x * TPB + threadIdx.x;
    if (id >= k * f) return;
    int r = id / f, c = id - r * f;
    h[id] = x[(size_t)perm[r] * f + c] * vals[r];
}

// ---------------- level-1 augment: sparse SpGEMM ----------------
__global__ void spgemm_aug(const int* __restrict__ nbr, const float* __restrict__ awt,
                           const int* __restrict__ acnt, const int* __restrict__ perm,
                           const int* __restrict__ invp, int k,
                           ushort* __restrict__ Chi, ushort* __restrict__ Clo,
                           float* __restrict__ dinv, float* __restrict__ selfw) {
    __shared__ float row[2048];
    int r = blockIdx.x, tid = threadIdx.x;
    int pi = perm[r];
    for (int j = tid; j < k; j += TPB) row[j] = 0.f;
    __syncthreads();
    int cnt = acnt[pi];
    for (int a = 0; a < cnt; ++a) {
        int t = nbr[pi * MAXN + a];
        float w1 = awt[pi * MAXN + a];
        int c2 = acnt[t];
        for (int b = tid; b < c2; b += TPB) {
            int s = nbr[t * MAXN + b];
            int j = invp[s];
            if (j >= 0) atomicAdd(&row[j], w1 * awt[t * MAXN + b]);
        }
    }
    __syncthreads();
    float psum = 0.f;
    for (int j = tid; j < k; j += TPB) {
        float v = (j == r) ? 0.f : row[j];
        psum += v;
        ushort hi = f32_to_bf16(v);
        size_t o = (size_t)r * k + j;
        Chi[o] = hi;
        Clo[o] = f32_to_bf16(v - bf2f(hi));
    }
    for (int o = 32; o; o >>= 1) psum += __shfl_xor(psum, o);
    __shared__ float sh[4];
    if ((tid & 63) == 0) sh[tid >> 6] = psum;
    __syncthreads();
    if (tid == 0) {
        float tot = sh[0] + sh[1] + sh[2] + sh[3];
        dinv[r] = 1.0f / sqrtf(tot + 2.0f);
        selfw[r] = 2.0f;
    }
}

// ---------------- dense augment (levels 2,3): split-K + finalize -----------
__global__ void transpose_aug_hl(const ushort* __restrict__ Ahi, const ushort* __restrict__ Alo,
                                 ushort* __restrict__ T, int n) {
    __shared__ float tile[64][65];
    int c0 = blockIdx.x * 64, r0 = blockIdx.y * 64;
    for (int t = threadIdx.x; t < 4096; t += TPB) {
        int r = t >> 6, c = t & 63;
        size_t o = (size_t)(r0 + r) * n + (c0 + c);
        float v = bf2f(Ahi[o]) + bf2f(Alo[o]);
        if (r0 + r == c0 + c) v += 1.0f;
        tile[c][r] = v;
    }
    __syncthreads();
    for (int t = threadIdx.x; t < 4096; t += TPB) {
        int c = t >> 6, r = t & 63;
        T[(size_t)(c0 + c) * n + (r0 + r)] = f32_to_bf16(tile[c][r]);
    }
}

__global__ void gather_rows_aug_hl(const ushort* __restrict__ Ahi, const ushort* __restrict__ Alo,
                                   const int* __restrict__ perm, ushort* __restrict__ Ag,
                                   int n, int rows) {
    int id = blockIdx.x * TPB + threadIdx.x;
    if (id >= rows * n) return;
    int r = id / n, t = id - r * n;
    int pr = perm[r];
    size_t o = (size_t)pr * n + t;
    float v = bf2f(Ahi[o]) + bf2f(Alo[o]);
    if (pr == t) v += 1.0f;
    Ag[id] = f32_to_bf16(v);
}

__global__ void gather_rows_u16(const ushort* __restrict__ T, const int* __restrict__ perm,
                                ushort* __restrict__ Bg, int n, int rows) {
    int id = blockIdx.x * TPB + threadIdx.x;
    if (id >= rows * n) return;
    int r = id / n, t = id - r * n;
    Bg[id] = T[(size_t)perm[r] * n + t];
}

__global__ void __launch_bounds__(256)
aug_gemm_acc(const ushort* __restrict__ Ag, const ushort* __restrict__ Bg,
             float* __restrict__ Caug, int K, int ldc, int kpb) {
    __shared__ __align__(16) ushort As[64 * LDK];
    __shared__ __align__(16) ushort Bs[64 * LDK];
    int tid = threadIdx.x;
    int wave = tid >> 6, lane = tid & 63;
    int wr = wave >> 1, wc = wave & 1;
    int m = lane & 15, quad = lane >> 4;
    int i0 = blockIdx.y * 64, j0 = blockIdx.x * 64;
    int kbeg = blockIdx.z * kpb;
    f32x4 acc[2][2];
#pragma unroll
    for (int a = 0; a < 2; ++a)
#pragma unroll
        for (int b = 0; b < 2; ++b) acc[a][b] = (f32x4){0.f, 0.f, 0.f, 0.f};
    const ushort* Ab = Ag + (size_t)i0 * K;
    const ushort* Bb = Bg + (size_t)j0 * K;
    for (int k0 = kbeg; k0 < kbeg + kpb; k0 += 64) {
#pragma unroll
        for (int v = 0; v < 2; ++v) {
            int idx = tid + (v << 8);
            int r = idx >> 3, c8 = idx & 7;
            *(uint4*)&As[r * LDK + c8 * 8] = *(const uint4*)&Ab[(size_t)r * K + k0 + c8 * 8];
            *(uint4*)&Bs[r * LDK + c8 * 8] = *(const uint4*)&Bb[(size_t)r * K + k0 + c8 * 8];
        }
        __syncthreads();
#pragma unroll
        for (int kk = 0; kk < 2; ++kk) {
            bf16x8 af[2], bfr[2];
#pragma unroll
            for (int mi = 0; mi < 2; ++mi)
                af[mi] = *(const bf16x8*)&As[(wr * 32 + mi * 16 + m) * LDK + kk * 32 + quad * 8];
#pragma unroll
            for (int ni = 0; ni < 2; ++ni)
                bfr[ni] = *(const bf16x8*)&Bs[(wc * 32 + ni * 16 + m) * LDK + kk * 32 + quad * 8];
#pragma unroll
            for (int mi = 0; mi < 2; ++mi)
#pragma unroll
                for (int ni = 0; ni < 2; ++ni)
                    acc[mi][ni] = __builtin_amdgcn_mfma_f32_16x16x32_bf16(
                        af[mi], bfr[ni], acc[mi][ni], 0, 0, 0);
        }
        __syncthreads();
    }
#pragma unroll
    for (int mi = 0; mi < 2; ++mi)
#pragma unroll
        for (int ni = 0; ni < 2; ++ni)
#pragma unroll
            for (int r = 0; r < 4; ++r) {
                int gi = i0 + wr * 32 + mi * 16 + quad * 4 + r;
                int gj = j0 + wc * 32 + ni * 16 + m;
                atomicAdd(&Caug[(size_t)gi * ldc + gj], acc[mi][ni][r]);
            }
}

__global__ void aug_finalize(const float* __restrict__ Caug, int k,
                             ushort* __restrict__ Chi, ushort* __restrict__ Clo,
                             float* __restrict__ dinv, float* __restrict__ selfw) {
    int r = blockIdx.x, tid = threadIdx.x;
    const float* row = Caug + (size_t)r * k;
    float psum = 0.f;
    for (int j = tid; j < k; j += TPB) {
        float v = (j == r) ? 0.f : row[j];
        psum += v;
        ushort hi = f32_to_bf16(v);
        size_t o = (size_t)r * k + j;
        Chi[o] = hi;
        Clo[o] = f32_to_bf16(v - bf2f(hi));
    }
    for (int o = 32; o; o >>= 1) psum += __shfl_xor(psum, o);
    __shared__ float sh[4];
    if ((tid & 63) == 0) sh[tid >> 6] = psum;
    __syncthreads();
    if (tid == 0) {
        float tot = sh[0] + sh[1] + sh[2] + sh[3];
        dinv[r] = 1.0f / sqrtf(tot + 2.0f);
        selfw[r] = 2.0f;
    }
}

// ---------------- dense GCN aggregation (levels >=1) ----------------
__global__ void __launch_bounds__(256)
gcn_gemm(const ushort* __restrict__ Ahi, const ushort* __restrict__ Alo,
         const ushort* __restrict__ Bhi, const ushort* __restrict__ Blo,
         float* __restrict__ C, int K, int ldc, int kpb) {
    __shared__ __align__(16) ushort sAh[64 * LDK];
    __shared__ __align__(16) ushort sAl[64 * LDK];
    __shared__ __align__(16) ushort sBh[64 * LDK];
    __shared__ __align__(16) ushort sBl[64 * LDK];
    int tid = threadIdx.x;
    int wave = tid >> 6, lane = tid & 63;
    int wr = wave >> 1, wc = wave & 1;
    int m = lane & 15, quad = lane >> 4;
    int i0 = blockIdx.y * 64, j0 = blockIdx.x * 64;
    int kbeg = blockIdx.z * kpb;
    f32x4 acc[2][2];
#pragma unroll
    for (int a = 0; a < 2; ++a)
#pragma unroll
        for (int b = 0; b < 2; ++b) acc[a][b] = (f32x4){0.f, 0.f, 0.f, 0.f};
    for (int k0 = kbeg; k0 < kbeg + kpb; k0 += 64) {
#pragma unroll
        for (int v = 0; v < 2; ++v) {
            int idx = tid + (v << 8);
            int r = idx >> 3, c8 = idx & 7;
            size_t boff = (size_t)(j0 + r) * K + k0 + c8 * 8;
            *(uint4*)&sBh[r * LDK + c8 * 8] = *(const uint4*)&Bhi[boff];
            *(uint4*)&sBl[r * LDK + c8 * 8] = *(const uint4*)&Blo[boff];
            size_t aoff = (size_t)(i0 + r) * K + k0 + c8 * 8;
            *(uint4*)&sAh[r * LDK + c8 * 8] = *(const uint4*)&Ahi[aoff];
            *(uint4*)&sAl[r * LDK + c8 * 8] = *(const uint4*)&Alo[aoff];
        }
        __syncthreads();
#pragma unroll
        for (int kk = 0; kk < 2; ++kk) {
            bf16x8 ah[2], al[2], bh[2], bl[2];
#pragma unroll
            for (int mi = 0; mi < 2; ++mi) {
                ah[mi] = *(const bf16x8*)&sAh[(wr * 32 + mi * 16 + m) * LDK + kk * 32 + quad * 8];
                al[mi] = *(const bf16x8*)&sAl[(wr * 32 + mi * 16 + m) * LDK + kk * 32 + quad * 8];
            }
#pragma unroll
            for (int ni = 0; ni < 2; ++ni) {
                bh[ni] = *(const bf16x8*)&sBh[(wc * 32 + ni * 16 + m) * LDK + kk * 32 + quad * 8];
                bl[ni] = *(const bf16x8*)&sBl[(wc * 32 + ni * 16 + m) * LDK + kk * 32 + quad * 8];
            }
#pragma unroll
            for (int mi = 0; mi < 2; ++mi)
#pragma unroll
                for (int ni = 0; ni < 2; ++ni) {
                    acc[mi][ni] = __builtin_amdgcn_mfma_f32_16x16x32_bf16(ah[mi], bh[ni], acc[mi][ni], 0, 0, 0);
                    acc[mi][ni] = __builtin_amdgcn_mfma_f32_16x16x32_bf16(ah[mi], bl[ni], acc[mi][ni], 0, 0, 0);
                    acc[mi][ni] = __builtin_amdgcn_mfma_f32_16x16x32_bf16(al[mi], bh[ni], acc[mi][ni], 0, 0, 0);
                }
        }
        __syncthreads();
    }
#pragma unroll
    for (int mi = 0; mi < 2; ++mi)
#pragma unroll
        for (int ni = 0; ni < 2; ++ni)
#pragma unroll
            for (int r = 0; r < 4; ++r) {
                int gi = i0 + wr * 32 + mi * 16 + quad * 4 + r;
                int gj = j0 + wc * 32 + ni * 16 + m;
                atomicAdd(&C[(size_t)gi * ldc + gj], acc[mi][ni][r]);
            }
}

// build yT hi/lo AND zero the Cp accumulator
__global__ void build_yT_z(const float* __restrict__ xw, const float* __restrict__ dinv,
                           ushort* __restrict__ Bhi, ushort* __restrict__ Blo,
                           float* __restrict__ Cp, int n, int f) {
    __shared__ float t[64][65];
    int k0 = blockIdx.x * 64, c0 = blockIdx.y * 64;
#pragma unroll
    for (int v = 0; v < 16; ++v) {
        int idx = threadIdx.x + v * 256;
        int r = idx >> 6, c = idx & 63;
        t[r][c] = xw[(size_t)(k0 + r) * f + (c0 + c)] * dinv[k0 + r];
        Cp[(size_t)(k0 + r) * f + (c0 + c)] = 0.f;
    }
    __syncthreads();
#pragma unroll
    for (int v = 0; v < 16; ++v) {
        int idx = threadIdx.x + v * 256;
        int c = idx >> 6, k = idx & 63;
        float val = t[k][c];
        ushort hi = f32_to_bf16(val);
        size_t o = (size_t)(c0 + c) * n + (k0 + k);
        Bhi[o] = hi;
        Blo[o] = f32_to_bf16(val - bf2f(hi));
    }
}

__global__ void gcn_epilogue(const float* __restrict__ C, const float* __restrict__ xw,
                             const float* __restrict__ dinv, const float* __restrict__ selfw,
                             const float* __restrict__ b, float* __restrict__ out,
                             int n, int f, int relu) {
    int id = blockIdx.x * TPB + threadIdx.x;
    if (id >= n * f) return;
    int i = id / f, c = id - i * f;
    float y = xw[id] * dinv[i];
    float v = dinv[i] * (C[id] + selfw[i] * y) + b[c];
    if (relu) v = fmaxf(v, 0.f);
    out[id] = v;
}

// ---------------- up path: fused unpool ----------------
__global__ void unpool_add(const float* __restrict__ xsrc, const float* __restrict__ h,
                           const int* __restrict__ invp, int n, int f, float* __restrict__ t) {
    int id = blockIdx.x * TPB + threadIdx.x;
    if (id >= n * f) return;
    int i = id / f, c = id - i * f;
    int r = invp[i];
    float v = xsrc[id];
    if (r >= 0) v += h[(size_t)r * f + c];
    t[id] = v;
}

// ---------------- layernorm ----------------
__global__ void layernorm(const float* __restrict__ h, const float* __restrict__ g,
                          const float* __restrict__ b, float* __restrict__ u, int n) {
    int i = blockIdx.x;
    int t = threadIdx.x;
    float v = h[(size_t)i * 128 + t];
    __shared__ float s0[2], s1[2];
    float sum = v;
    for (int o = 32; o; o >>= 1) sum += __shfl_xor(sum, o);
    if ((t & 63) == 0) s0[t >> 6] = sum;
    __syncthreads();
    float mu = (s0[0] + s0[1]) * (1.0f / 128.0f);
    float d = v - mu;
    float sq = d * d;
    for (int o = 32; o; o >>= 1) sq += __shfl_xor(sq, o);
    if ((t & 63) == 0) s1[t >> 6] = sq;
    __syncthreads();
    float var = (s1[0] + s1[1]) * (1.0f / 128.0f);
    u[(size_t)i * 128 + t] = d / sqrtf(var + 1e-6f) * g[t] + b[t];
}

// ---------------- dense projections via split-bf16 MFMA --------------------
__global__ void transpose_split(const float* __restrict__ W, ushort* __restrict__ Bhi,
                                ushort* __restrict__ Blo, int K, int N) {
    __shared__ float tile[64][65];
    int n0 = blockIdx.x * 64, k0 = blockIdx.y * 64;
    for (int t = threadIdx.x; t < 4096; t += TPB) {
        int r = t >> 6, c = t & 63;
        tile[r][c] = W[(size_t)(k0 + r) * N + (n0 + c)];
    }
    __syncthreads();
    for (int t = threadIdx.x; t < 4096; t += TPB) {
        int c = t >> 6, r = t & 63;
        float v = tile[r][c];
        ushort hi = f32_to_bf16(v);
        size_t o = (size_t)(n0 + c) * K + (k0 + r);
        Bhi[o] = hi;
        Blo[o] = f32_to_bf16(v - bf2f(hi));
    }
}

__global__ void __launch_bounds__(256)
gemm_bt_store(const float* __restrict__ A, const ushort* __restrict__ Bhi,
              const ushort* __restrict__ Blo, const float* __restrict__ bias,
              float* __restrict__ C, int K, int N) {
    __shared__ __align__(16) ushort sAh[64 * LDK];
    __shared__ __align__(16) ushort sAl[64 * LDK];
    __shared__ __align__(16) ushort sBh[64 * LDK];
    __shared__ __align__(16) ushort sBl[64 * LDK];
    int tid = threadIdx.x;
    int wave = tid >> 6, lane = tid & 63;
    int wr = wave >> 1, wc = wave & 1;
    int m = lane & 15, quad = lane >> 4;
    int i0 = blockIdx.y * 64, j0 = blockIdx.x * 64;
    f32x4 acc[2][2];
#pragma unroll
    for (int a = 0; a < 2; ++a)
#pragma unroll
        for (int b = 0; b < 2; ++b) acc[a][b] = (f32x4){0.f, 0.f, 0.f, 0.f};
    for (int k0 = 0; k0 < K; k0 += 64) {
#pragma unroll
        for (int v = 0; v < 2; ++v) {
            int idx = tid + (v << 8);
            int r = idx >> 3, c8 = idx & 7;
            size_t boff = (size_t)(j0 + r) * K + k0 + c8 * 8;
            *(uint4*)&sBh[r * LDK + c8 * 8] = *(const uint4*)&Bhi[boff];
            *(uint4*)&sBl[r * LDK + c8 * 8] = *(const uint4*)&Blo[boff];
            size_t aoff = (size_t)(i0 + r) * K + k0 + c8 * 8;
            float4 fa = *(const float4*)&A[aoff];
            float4 fb = *(const float4*)&A[aoff + 4];
            ushort h0 = f32_to_bf16(fa.x), h1 = f32_to_bf16(fa.y);
            ushort h2 = f32_to_bf16(fa.z), h3 = f32_to_bf16(fa.w);
            ushort h4 = f32_to_bf16(fb.x), h5 = f32_to_bf16(fb.y);
            ushort h6 = f32_to_bf16(fb.z), h7 = f32_to_bf16(fb.w);
            uint4 ph, pl;
            ph.x = (uint)h0 | ((uint)h1 << 16);
            ph.y = (uint)h2 | ((uint)h3 << 16);
            ph.z = (uint)h4 | ((uint)h5 << 16);
            ph.w = (uint)h6 | ((uint)h7 << 16);
            pl.x = (uint)f32_to_bf16(fa.x - bf2f(h0)) | ((uint)f32_to_bf16(fa.y - bf2f(h1)) << 16);
            pl.y = (uint)f32_to_bf16(fa.z - bf2f(h2)) | ((uint)f32_to_bf16(fa.w - bf2f(h3)) << 16);
            pl.z = (uint)f32_to_bf16(fb.x - bf2f(h4)) | ((uint)f32_to_bf16(fb.y - bf2f(h5)) << 16);
            pl.w = (uint)f32_to_bf16(fb.z - bf2f(h6)) | ((uint)f32_to_bf16(fb.w - bf2f(h7)) << 16);
            *(uint4*)&sAh[r * LDK + c8 * 8] = ph;
            *(uint4*)&sAl[r * LDK + c8 * 8] = pl;
        }
        __syncthreads();
#pragma unroll
        for (int kk = 0; kk < 2; ++kk) {
            bf16x8 ah[2], al[2], bh[2], bl[2];
#pragma unroll
            for (int mi = 0; mi < 2; ++mi) {
                ah[mi] = *(const bf16x8*)&sAh[(wr * 32 + mi * 16 + m) * LDK + kk * 32 + quad * 8];
                al[mi] = *(const bf16x8*)&sAl[(wr * 32 + mi * 16 + m) * LDK + kk * 32 + quad * 8];
            }
#pragma unroll
            for (int ni = 0; ni < 2; ++ni) {
                bh[ni] = *(const bf16x8*)&sBh[(wc * 32 + ni * 16 + m) * LDK + kk * 32 + quad * 8];
                bl[ni] = *(const bf16x8*)&sBl[(wc * 32 + ni * 16 + m) * LDK + kk * 32 + quad * 8];
            }
#pragma unroll
            for (int mi = 0; mi < 2; ++mi)
#pragma unroll
                for (int ni = 0; ni < 2; ++ni) {
                    acc[mi][ni] = __builtin_amdgcn_mfma_f32_16x16x32_bf16(ah[mi], bh[ni], acc[mi][ni], 0, 0, 0);
                    acc[mi][ni] = __builtin_amdgcn_mfma_f32_16x16x32_bf16(ah[mi], bl[ni], acc[mi][ni], 0, 0, 0);
                    acc[mi][ni] = __builtin_amdgcn_mfma_f32_16x16x32_bf16(al[mi], bh[ni], acc[mi][ni], 0, 0, 0);
                }
        }
        __syncthreads();
    }
#pragma unroll
    for (int mi = 0; mi < 2; ++mi)
#pragma unroll
        for (int ni = 0; ni < 2; ++ni)
#pragma unroll
            for (int r = 0; r < 4; ++r) {
                int gi = i0 + wr * 32 + mi * 16 + quad * 4 + r;
                int gj = j0 + wc * 32 + ni * 16 + m;
                float v = acc[mi][ni][r];
                if (bias) v += bias[gj];
                C[(size_t)gi * N + gj] = v;
            }
}

__global__ void __launch_bounds__(256)
gemm_bt_split(const float* __restrict__ A, const ushort* __restrict__ Bhi,
              const ushort* __restrict__ Blo, float* __restrict__ C,
              int K, int N, int kpb) {
    __shared__ __align__(16) ushort sAh[64 * LDK];
    __shared__ __align__(16) ushort sAl[64 * LDK];
    __shared__ __align__(16) ushort sBh[64 * LDK];
    __shared__ __align__(16) ushort sBl[64 * LDK];
    int tid = threadIdx.x;
    int wave = tid >> 6, lane = tid & 63;
    int wr = wave >> 1, wc = wave & 1;
    int m = lane & 15, quad = lane >> 4;
    int i0 = blockIdx.y * 64, j0 = blockIdx.x * 64;
    int kbeg = blockIdx.z * kpb;
    f32x4 acc[2][2];
#pragma unroll
    for (int a = 0; a < 2; ++a)
#pragma unroll
        for (int b = 0; b < 2; ++b) acc[a][b] = (f32x4){0.f, 0.f, 0.f, 0.f};
    for (int k0 = kbeg; k0 < kbeg + kpb; k0 += 64) {
#pragma unroll
        for (int v = 0; v < 2; ++v) {
            int idx = tid + (v << 8);
            int r = idx >> 3, c8 = idx & 7;
            size_t boff = (size_t)(j0 + r) * K + k0 + c8 * 8;
            *(uint4*)&sBh[r * LDK + c8 * 8] = *(const uint4*)&Bhi[boff];
            *(uint4*)&sBl[r * LDK + c8 * 8] = *(const uint4*)&Blo[boff];
            size_t aoff = (size_t)(i0 + r) * K + k0 + c8 * 8;
            float4 fa = *(const float4*)&A[aoff];
            float4 fb = *(const float4*)&A[aoff + 4];
            ushort h0 = f32_to_bf16(fa.x), h1 = f32_to_bf16(fa.y);
            ushort h2 = f32_to_bf16(fa.z), h3 = f32_to_bf16(fa.w);
            ushort h4 = f32_to_bf16(fb.x), h5 = f32_to_bf16(fb.y);
            ushort h6 = f32_to_bf16(fb.z), h7 = f32_to_bf16(fb.w);
            uint4 ph, pl;
            ph.x = (uint)h0 | ((uint)h1 << 16);
            ph.y = (uint)h2 | ((uint)h3 << 16);
            ph.z = (uint)h4 | ((uint)h5 << 16);
            ph.w = (uint)h6 | ((uint)h7 << 16);
            pl.x = (uint)f32_to_bf16(fa.x - bf2f(h0)) | ((uint)f32_to_bf16(fa.y - bf2f(h1)) << 16);
            pl.y = (uint)f32_to_bf16(fa.z - bf2f(h2)) | ((uint)f32_to_bf16(fa.w - bf2f(h3)) << 16);
            pl.z = (uint)f32_to_bf16(fb.x - bf2f(h4)) | ((uint)f32_to_bf16(fb.y - bf2f(h5)) << 16);
            pl.w = (uint)f32_to_bf16(fb.z - bf2f(h6)) | ((uint)f32_to_bf16(fb.w - bf2f(h7)) << 16);
            *(uint4*)&sAh[r * LDK + c8 * 8] = ph;
            *(uint4*)&sAl[r * LDK + c8 * 8] = pl;
        }
        __syncthreads();
#pragma unroll
        for (int kk = 0; kk < 2; ++kk) {
            bf16x8 ah[2], al[2], bh[2], bl[2];
#pragma unroll
            for (int mi = 0; mi < 2; ++mi) {
                ah[mi] = *(const bf16x8*)&sAh[(wr * 32 + mi * 16 + m) * LDK + kk * 32 + quad * 8];
                al[mi] = *(const bf16x8*)&sAl[(wr * 32 + mi * 16 + m) * LDK + kk * 32 + quad * 8];
            }
#pragma unroll
            for (int ni = 0; ni < 2; ++ni) {
                bh[ni] = *(const bf16x8*)&sBh[(wc * 32 + ni * 16 + m) * LDK + kk * 32 + quad * 8];
                bl[ni] = *(const bf16x8*)&sBl[(wc * 32 + ni * 16 + m) * LDK + kk * 32 + quad * 8];
            }
#pragma unroll
            for (int mi = 0; mi < 2; ++mi)
#pragma unroll
                for (int ni = 0; ni < 2; ++ni) {
                    acc[mi][ni] = __builtin_amdgcn_mfma_f32_16x16x32_bf16(ah[mi], bh[ni], acc[mi][ni], 0, 0, 0);
                    acc[mi][ni] = __builtin_amdgcn_mfma_f32_16x16x32_bf16(ah[mi], bl[ni], acc[mi][ni], 0, 0, 0);
                    acc[mi][ni] = __builtin_amdgcn_mfma_f32_16x16x32_bf16(al[mi], bh[ni], acc[mi][ni], 0, 0, 0);
                }
        }
        __syncthreads();
    }
#pragma unroll
    for (int mi = 0; mi < 2; ++mi)
#pragma unroll
        for (int ni = 0; ni < 2; ++ni)
#pragma unroll
            for (int r = 0; r < 4; ++r) {
                int gi = i0 + wr * 32 + mi * 16 + quad * 4 + r;
                int gj = j0 + wc * 32 + ni * 16 + m;
                atomicAdd(&C[(size_t)gi * N + gj], acc[mi][ni][r]);
            }
}

// ---------------- GAT ----------------
__global__ void attn_coef2(const float* __restrict__ hf, const float* __restrict__ asrc,
                           const float* __restrict__ adst, float* __restrict__ es,
                           float* __restrict__ ed, int heads) {
    int j = blockIdx.x;
    int wave = threadIdx.x >> 6, lane = threadIdx.x & 63;
    if (wave >= heads) return;
    const float* hp = hf + (size_t)j * heads * 128 + wave * 128;
    float v0 = hp[lane], v1 = hp[lane + 64];
    float a = v0 * asrc[wave * 128 + lane] + v1 * asrc[wave * 128 + lane + 64];
    float d = v0 * adst[wave * 128 + lane] + v1 * adst[wave * 128 + lane + 64];
    for (int o = 32; o; o >>= 1) { a += __shfl_xor(a, o); d += __shfl_xor(d, o); }
    if (lane == 0) { es[j * heads + wave] = a; ed[j * heads + wave] = d; }
}

__global__ void gat_sparse(const int* __restrict__ nbr, const int* __restrict__ ncnt, int n,
                           const float* __restrict__ hf, const float* __restrict__ es,
                           const float* __restrict__ ed, const float* __restrict__ bias,
                           const float* __restrict__ resid, float* __restrict__ out,
                           int heads, int mode) {
    int i = blockIdx.x;
    int tid = threadIdx.x;
    __shared__ int idx[MAXN];
    __shared__ float lg[MAXN * 4];
    __shared__ float hmax[4], hsum[4];
    int m = ncnt[i];
    for (int t = tid; t < m; t += TPB) idx[t] = nbr[i * MAXN + t];
    __syncthreads();
    for (int t = tid; t < m * heads; t += TPB) {
        int jl = t / heads, h = t - jl * heads;
        float l = ed[i * heads + h] + es[idx[jl] * heads + h];
        lg[jl * heads + h] = (l > 0.f) ? l : 0.2f * l;
    }
    __syncthreads();
    int h = tid >> 6, lane = tid & 63;
    if (h < heads) {
        float mx = -3.4e38f;
        for (int jl = lane; jl < m; jl += 64) mx = fmaxf(mx, lg[jl * heads + h]);
        for (int o = 32; o; o >>= 1) mx = fmaxf(mx, __shfl_xor(mx, o));
        if (lane == 0) hmax[h] = mx;
    }
    __syncthreads();
    if (h < heads) {
        float mx = hmax[h];
        float sm = 0.f;
        for (int jl = lane; jl < m; jl += 64) {
            float p = expf(lg[jl * heads + h] - mx);
            lg[jl * heads + h] = p;
            sm += p;
        }
        for (int o = 32; o; o >>= 1) sm += __shfl_xor(sm, o);
        if (lane == 0) hsum[h] = sm;
    }
    __syncthreads();
    int width = heads * 128;
    for (int o = tid; o < width; o += TPB) {
        int hh = o >> 7;
        float acc = 0.f;
        for (int jl = 0; jl < m; ++jl)
            acc += lg[jl * heads + hh] * hf[(size_t)idx[jl] * width + o];
        float v = acc / hsum[hh] + bias[o];
        if (mode == 0) v = (v > 0.f) ? v : expm1f(v);
        else v += resid[(size_t)i * width + o];
        out[(size_t)i * width + o] = v;
    }
}

// ---------------------------------------------------------------------------
static inline int cdiv(int a, int b) { return (a + b - 1) / b; }

static int pick_z(int gx, int gy, int K) {
    int z = 1;
    while (gx * gy * z < 384 && K / (2 * z) >= 64) z <<= 1;
    return z;
}

static void run_gcn_dense(hipStream_t stream, const ushort* Ahi, const ushort* Alo,
                          int n, const float* xin, int fin,
                          const float* W, const float* bias, int f,
                          const float* dinv, const float* selfw,
                          float* xw, ushort* yThi, ushort* yTlo, float* Cp,
                          float* out, int relu) {
    xw_gemm<<<cdiv(n, TPB / f), TPB, 0, stream>>>(xin, W, xw, n, fin, f);
    build_yT_z<<<dim3(n / 64, f / 64), TPB, 0, stream>>>(xw, dinv, yThi, yTlo, Cp, n, f);
    int z = pick_z(f / 64, n / 64, n);
    gcn_gemm<<<dim3(f / 64, n / 64, z), TPB, 0, stream>>>(Ahi, Alo, yThi, yTlo, Cp, n, f, n / z);
    gcn_epilogue<<<cdiv(n * f, TPB), TPB, 0, stream>>>(Cp, xw, dinv, selfw, bias, out, n, f, relu);
}

static void run_gcn_sparse(hipStream_t stream, const int* nbr, const float* awt,
                           const int* acnt, int n, const float* xin, int fin,
                           const float* W, const float* bias, int f,
                           const float* dinv, const float* selfw,
                           float* xw, float* out, int relu) {
    xw_gemm<<<cdiv(n, TPB / f), TPB, 0, stream>>>(xin, W, xw, n, fin, f);
    spmv_gcn<<<n, f, 0, stream>>>(nbr, awt, acnt, xw, dinv, selfw, bias, out, f, relu);
}

static void run_topk(hipStream_t stream, const float* score, int n, int k, int* rank,
                     int* perm, float* vals, int* invp) {
    hipMemsetAsync(rank, 0, n * sizeof(int), stream);
    rank_count<<<dim3(n / 256, n / 256), 256, 0, stream>>>(score, n, rank);
    scatter_topk_all<<<cdiv(n, TPB), TPB, 0, stream>>>(score, rank, n, k, perm, vals, invp);
}

static void run_aug_dense(hipStream_t stream, const ushort* Ahi, const ushort* Alo, int n,
                          const int* perm, int k, ushort* Tbf, ushort* Agb, ushort* Bgb,
                          float* Caug, ushort* Chi, ushort* Clo, float* dinv, float* selfw) {
    transpose_aug_hl<<<dim3(n / 64, n / 64), TPB, 0, stream>>>(Ahi, Alo, Tbf, n);
    gather_rows_aug_hl<<<cdiv(k * n, TPB), TPB, 0, stream>>>(Ahi, Alo, perm, Agb, n, k);
    gather_rows_u16<<<cdiv(k * n, TPB), TPB, 0, stream>>>(Tbf, perm, Bgb, n, k);
    hipMemsetAsync(Caug, 0, (size_t)k * k * sizeof(float), stream);
    int z = 8;
    aug_gemm_acc<<<dim3(k / 64, k / 64, z), TPB, 0, stream>>>(Agb, Bgb, Caug, n, k, n / z);
    aug_finalize<<<k, TPB, 0, stream>>>(Caug, k, Chi, Clo, dinv, selfw);
}

extern "C" void kernel_launch(void* const* d_in, const int* in_sizes, int n_in,
                              void* d_out, int out_size, void* d_ws, size_t ws_size,
                              hipStream_t stream) {
    const float* x   = (const float*)d_in[0];
    const int*   ei  = (const int*)d_in[1];
    const float* w0  = (const float*)d_in[2];  const float* b0  = (const float*)d_in[3];
    const float* w1  = (const float*)d_in[4];  const float* b1  = (const float*)d_in[5];
    const float* w2  = (const float*)d_in[6];  const float* b2  = (const float*)d_in[7];
    const float* w3  = (const float*)d_in[8];  const float* b3  = (const float*)d_in[9];
    const float* p1  = (const float*)d_in[10];
    const float* p2  = (const float*)d_in[11];
    const float* p3  = (const float*)d_in[12];
    const float* uw0 = (const float*)d_in[13]; const float* ub0 = (const float*)d_in[14];
    const float* uw1 = (const float*)d_in[15]; const float* ub1 = (const float*)d_in[16];
    const float* uw2 = (const float*)d_in[17]; const float* ub2 = (const float*)d_in[18];
    const float* lng = (const float*)d_in[19]; const float* lnb = (const float*)d_in[20];
    const float* rw  = (const float*)d_in[21]; const float* rb  = (const float*)d_in[22];
    const float* g1w = (const float*)d_in[23];
    const float* g1as = (const float*)d_in[24]; const float* g1ad = (const float*)d_in[25];
    const float* g1b = (const float*)d_in[26];
    const float* g2w = (const float*)d_in[27];
    const float* g2as = (const float*)d_in[28]; const float* g2ad = (const float*)d_in[29];
    const float* g2b = (const float*)d_in[30];

    const int N = 4096, E = 65536;
    const int K1 = 2048, K2 = 1024, K3 = 512;

    float* base = (float*)d_ws;
    size_t off = 0;
    auto alloc = [&](size_t nf) { float* p = base + off; off += (nf + 63) & ~(size_t)63; return p; };

    ushort* A1hi = (ushort*)alloc((size_t)K1 * K1 / 2);
    ushort* A1lo = (ushort*)alloc((size_t)K1 * K1 / 2);
    ushort* A2hi = (ushort*)alloc((size_t)K2 * K2 / 2);
    ushort* A2lo = (ushort*)alloc((size_t)K2 * K2 / 2);
    ushort* A3hi = (ushort*)alloc((size_t)K3 * K3 / 2);
    ushort* A3lo = (ushort*)alloc((size_t)K3 * K3 / 2);
    ushort* Tbf  = (ushort*)alloc((size_t)K1 * K1 / 2);
    ushort* Agb  = (ushort*)alloc((size_t)K2 * K1 / 2);
    ushort* Bgb  = (ushort*)alloc((size_t)K2 * K1 / 2);
    ushort* yThi = (ushort*)alloc((size_t)128 * N / 2);
    ushort* yTlo = (ushort*)alloc((size_t)128 * N / 2);
    ushort* Whi  = (ushort*)alloc((size_t)512 * 128 / 2);
    ushort* Wlo  = (ushort*)alloc((size_t)512 * 128 / 2);
    float* Caug  = alloc((size_t)K2 * K2);
    float* Cp    = alloc((size_t)N * 128);
    float* x0    = alloc((size_t)N * 64);
    float* x1    = alloc((size_t)K1 * 64);
    float* x2    = alloc((size_t)K2 * 64);
    float* x3    = alloc((size_t)K3 * 64);
    float* h1    = alloc((size_t)K1 * 64);
    float* h2    = alloc((size_t)K2 * 64);
    float* h3    = alloc((size_t)K3 * 64);
    float* xw    = alloc((size_t)N * 128);
    float* dinv0 = alloc(N);  float* selfw0 = alloc(N);
    float* dinv1 = alloc(K1); float* selfw1 = alloc(K1);
    float* dinv2 = alloc(K2); float* selfw2 = alloc(K2);
    float* dinv3 = alloc(K3); float* selfw3 = alloc(K3);
    int*   deg   = (int*)alloc(2 * N);
    int*   diag  = deg + N;
    float* score = alloc(N);
    int*   rank  = (int*)alloc(N);
    float* vals1 = alloc(K1); float* vals2 = alloc(K2); float* vals3 = alloc(K3);
    int*   perm1 = (int*)alloc(K1); int* perm2 = (int*)alloc(K2); int* perm3 = (int*)alloc(K3);
    int*   invp1 = (int*)alloc(N);  int* invp2 = (int*)alloc(K1); int* invp3 = (int*)alloc(K2);
    int*   nbr   = (int*)alloc((size_t)N * MAXN);
    float* awt   = alloc((size_t)N * MAXN);
    int*   acnt  = (int*)alloc(N);
    float* t2    = alloc((size_t)K2 * 64);
    float* t1    = alloc((size_t)K1 * 64);
    float* t0    = alloc((size_t)N * 64);
    float* hfin  = alloc((size_t)N * 128);
    float* u     = alloc((size_t)N * 128);
    float* resid = alloc((size_t)N * 128);
    float* hf1   = alloc((size_t)N * 512);
    float* es1   = alloc((size_t)N * 4); float* ed1 = alloc((size_t)N * 4);
    float* g1    = alloc((size_t)N * 512);
    float* hf2   = alloc((size_t)N * 128);
    float* es2   = alloc(N); float* ed2 = alloc(N);
    (void)ws_size; (void)n_in; (void)in_sizes; (void)out_size;

    // ---- CSR build directly from edge list ----
    csr_init<<<cdiv(N * MAXN, TPB), TPB, 0, stream>>>(N, nbr, awt);
    hipMemsetAsync(deg, 0, 2 * N * sizeof(int), stream);
    csr_insert<<<cdiv(E, TPB), TPB, 0, stream>>>(ei, E, nbr, awt, deg, diag);
    csr_finalize<<<cdiv(N, TPB), TPB, 0, stream>>>(nbr, deg, diag, N, acnt, dinv0, selfw0);

    // ---- down level 0 (sparse) ----
    run_gcn_sparse(stream, nbr, awt, acnt, N, x, 3, w0, b0, 64, dinv0, selfw0, xw, x0, 1);

    // ---- level 1: topk + sparse SpGEMM augment ----
    score_kernel2<<<cdiv(N, TPB), TPB, 0, stream>>>(x0, p1, score, N);
    run_topk(stream, score, N, K1, rank, perm1, vals1, invp1);
    spgemm_aug<<<K1, TPB, 0, stream>>>(nbr, awt, acnt, perm1, invp1, K1,
                                       A1hi, A1lo, dinv1, selfw1);
    gather_feat<<<cdiv(K1 * 64, TPB), TPB, 0, stream>>>(x0, perm1, vals1, K1, 64, h1);
    run_gcn_dense(stream, A1hi, A1lo, K1, h1, 64, w1, b1, 64,
                  dinv1, selfw1, xw, yThi, yTlo, Cp, x1, 1);

    // ---- level 2 (dense split-K augment) ----
    score_kernel2<<<cdiv(K1, TPB), TPB, 0, stream>>>(x1, p2, score, K1);
    run_topk(stream, score, K1, K2, rank, perm2, vals2, invp2);
    run_aug_dense(stream, A1hi, A1lo, K1, perm2, K2, Tbf, Agb, Bgb, Caug,
                  A2hi, A2lo, dinv2, selfw2);
    gather_feat<<<cdiv(K2 * 64, TPB), TPB, 0, stream>>>(x1, perm2, vals2, K2, 64, h2);
    run_gcn_dense(stream, A2hi, A2lo, K2, h2, 64, w2, b2, 64,
                  dinv2, selfw2, xw, yThi, yTlo, Cp, x2, 1);

    // ---- level 3 (dense split-K augment) ----
    score_kernel2<<<cdiv(K2, TPB), TPB, 0, stream>>>(x2, p3, score, K2);
    run_topk(stream, score, K2, K3, rank, perm3, vals3, invp3);
    run_aug_dense(stream, A2hi, A2lo, K2, perm3, K3, Tbf, Agb, Bgb, Caug,
                  A3hi, A3lo, dinv3, selfw3);
    gather_feat<<<cdiv(K3 * 64, TPB), TPB, 0, stream>>>(x2, perm3, vals3, K3, 64, h3);
    run_gcn_dense(stream, A3hi, A3lo, K3, h3, 64, w3, b3, 64,
                  dinv3, selfw3, xw, yThi, yTlo, Cp, x3, 1);

    // ---- up path (fused unpool) ----
    unpool_add<<<cdiv(K2 * 64, TPB), TPB, 0, stream>>>(x2, x3, invp3, K2, 64, t2);
    run_gcn_dense(stream, A2hi, A2lo, K2, t2, 64, uw0, ub0, 64,
                  dinv2, selfw2, xw, yThi, yTlo, Cp, h2, 1);

    unpool_add<<<cdiv(K1 * 64, TPB), TPB, 0, stream>>>(x1, h2, invp2, K1, 64, t1);
    run_gcn_dense(stream, A1hi, A1lo, K1, t1, 64, uw1, ub1, 64,
                  dinv1, selfw1, xw, yThi, yTlo, Cp, h1, 1);

    unpool_add<<<cdiv(N * 64, TPB), TPB, 0, stream>>>(x0, h1, invp1, N, 64, t0);
    run_gcn_sparse(stream, nbr, awt, acnt, N, t0, 64, uw2, ub2, 128,
                   dinv0, selfw0, xw, hfin, 0);

    // ---- layernorm + residual (direct store) ----
    layernorm<<<N, 128, 0, stream>>>(hfin, lng, lnb, u, N);
    transpose_split<<<dim3(2, 2), TPB, 0, stream>>>(rw, Whi, Wlo, 128, 128);
    gemm_bt_store<<<dim3(2, N / 64), TPB, 0, stream>>>(u, Whi, Wlo, rb, resid, 128, 128);

    // ---- GAT layer 1 (4 heads, concat, ELU) ----
    transpose_split<<<dim3(8, 2), TPB, 0, stream>>>(g1w, Whi, Wlo, 128, 512);
    gemm_bt_store<<<dim3(8, N / 64), TPB, 0, stream>>>(u, Whi, Wlo, nullptr, hf1, 128, 512);
    attn_coef2<<<N, 256, 0, stream>>>(hf1, g1as, g1ad, es1, ed1, 4);
    gat_sparse<<<N, TPB, 0, stream>>>(nbr, acnt, N, hf1, es1, ed1, g1b, nullptr, g1, 4, 0);

    // ---- GAT layer 2 (1 head) + residual ----
    transpose_split<<<dim3(2, 8), TPB, 0, stream>>>(g2w, Whi, Wlo, 512, 128);
    hipMemsetAsync(hf2, 0, (size_t)N * 128 * sizeof(float), stream);
    gemm_bt_split<<<dim3(2, N / 64, 4), TPB, 0, stream>>>(g1, Whi, Wlo, hf2, 512, 128, 128);
    attn_coef2<<<N, 64, 0, stream>>>(hf2, g2as, g2ad, es2, ed2, 1);
    gat_sparse<<<N, TPB, 0, stream>>>(nbr, acnt, N, hf2, es2, ed2, g2b, resid, (float*)d_out, 1, 1);
}

// Round 10
// 486.489 us; speedup vs baseline: 1.4246x; 1.1240x over previous
//
#include <hip/hip_runtime.h>
#include <math.h>

// ---------------------------------------------------------------------------
// GraphUNet + GAT pipeline. N=4096, E=65536, IN=3, H=64, OUT=128, HEADS=4
// Round 10: CSR build via bucket scatter + per-row wave dedupe (replaces the
// 66 µs global-memory probing insert). Everything else = Round 9.
// ---------------------------------------------------------------------------

#define TPB 256
#define LDK 88
#define MAXN 128

typedef __attribute__((ext_vector_type(8))) short bf16x8;
typedef __attribute__((ext_vector_type(4))) float f32x4;

__device__ inline ushort f32_to_bf16(float v) {
    unsigned b = __float_as_uint(v);
    return (ushort)((b + 0x7FFF + ((b >> 16) & 1)) >> 16);
}
__device__ inline float bf2f(ushort u) { return __uint_as_float(((unsigned)u) << 16); }

// ---------------- CSR build (bucket scatter + dedupe) ----------------
__global__ void bucket_scatter(const int* __restrict__ ei, int E, int* __restrict__ buck,
                               int* __restrict__ cursor) {
    int e = blockIdx.x * TPB + threadIdx.x;
    if (e >= E) return;
    int src = ei[e];
    int dst = ei[E + e];
    int pos = atomicAdd(&cursor[dst], 1);
    if (pos < MAXN) buck[dst * MAXN + pos] = src;
}

// one wave per row: dedupe bucket -> (nbr, awt) with +I folded in; emit
// acnt / dinv / selfw. awt[j] = multiplicity + (j==i ? 1 : 0).
__global__ void build_csr(const int* __restrict__ buck, const int* __restrict__ cursor,
                          int n, int* __restrict__ nbr, float* __restrict__ awt,
                          int* __restrict__ acnt, float* __restrict__ dinv,
                          float* __restrict__ selfw) {
    int i = blockIdx.x;
    int tid = threadIdx.x;          // 64 threads
    __shared__ int s[MAXN];
    __shared__ int outcnt, selfFound;
    int raw = cursor[i];
    int d = min(raw, MAXN);
    if (tid == 0) { outcnt = 0; selfFound = 0; }
    for (int p = tid; p < d; p += 64) s[p] = buck[i * MAXN + p];
    __syncthreads();
    for (int p = tid; p < d; p += 64)
        if (s[p] == i) atomicOr(&selfFound, 1);
    __syncthreads();
    for (int p = tid; p < d; p += 64) {
        int v = s[p];
        bool first = true;
        for (int q = 0; q < p; ++q)
            if (s[q] == v) { first = false; break; }
        if (first) {
            int w = 1;
            for (int q = p + 1; q < d; ++q) w += (s[q] == v);
            int slot = atomicAdd(&outcnt, 1);
            nbr[i * MAXN + slot] = v;
            awt[i * MAXN + slot] = (float)w + (v == i ? 1.0f : 0.0f);
        }
    }
    __syncthreads();
    if (tid == 0) {
        int cnt = outcnt;
        if (!selfFound && cnt < MAXN) {
            nbr[i * MAXN + cnt] = i;
            awt[i * MAXN + cnt] = 1.0f;
            ++cnt;
        }
        acnt[i] = cnt;
        float sw = selfFound ? 0.f : 2.f;
        dinv[i] = 1.0f / sqrtf((float)raw + sw);
        selfw[i] = sw;
    }
}

// ---------------- xw projection ----------------
__global__ void xw_gemm(const float* __restrict__ xin, const float* __restrict__ W,
                        float* __restrict__ C, int n, int fin, int f) {
    __shared__ float sW[64 * 128];
    int tid = threadIdx.x;
    for (int t = tid; t < fin * f; t += TPB) sW[t] = W[t];
    __syncthreads();
    int rpb = TPB / f;
    int r = blockIdx.x * rpb + tid / f;
    int c = tid - (tid / f) * f;
    if (r >= n) return;
    const float* xr = xin + (size_t)r * fin;
    float acc = 0.f;
    for (int k = 0; k < fin; ++k) acc += xr[k] * sW[k * f + c];
    C[(size_t)r * f + c] = acc;
}

// ---------------- level-0 GCN: fused sparse SpMV ----------------
__global__ void spmv_gcn(const int* __restrict__ nbr, const float* __restrict__ awt,
                         const int* __restrict__ acnt, const float* __restrict__ xw,
                         const float* __restrict__ dinv, const float* __restrict__ selfw,
                         const float* __restrict__ bias, float* __restrict__ out,
                         int f, int relu) {
    int i = blockIdx.x;
    int o = threadIdx.x;
    __shared__ int sj[MAXN];
    __shared__ float sw_[MAXN];
    int cnt = acnt[i];
    for (int a = o; a < cnt; a += blockDim.x) {
        sj[a] = nbr[i * MAXN + a];
        sw_[a] = awt[i * MAXN + a];
    }
    __syncthreads();
    if (o >= f) return;
    float sum = 0.f;
    for (int a = 0; a < cnt; ++a) {
        int j = sj[a];
        sum += sw_[a] * (xw[(size_t)j * f + o] * dinv[j]);
    }
    float yi = xw[(size_t)i * f + o] * dinv[i];
    sum -= yi;
    float v = dinv[i] * (sum + selfw[i] * yi) + bias[o];
    if (relu) v = fmaxf(v, 0.f);
    out[(size_t)i * f + o] = v;
}

// ---------------- pooling: score + 2D rank-count top-k ----------------
__global__ void score_kernel2(const float* __restrict__ x, const float* __restrict__ p,
                              float* __restrict__ s, int n) {
    int i = blockIdx.x * TPB + threadIdx.x;
    if (i >= n) return;
    float a = 0.f, nrm = 0.f;
    for (int c = 0; c < 64; ++c) {
        float pc = p[c];
        nrm += pc * pc;
        a += x[(size_t)i * 64 + c] * pc;
    }
    s[i] = tanhf(a / sqrtf(nrm));
}

__global__ void rank_count(const float* __restrict__ s, int n, int* __restrict__ rank) {
    __shared__ float sj[256];
    int i = blockIdx.x * 256 + threadIdx.x;
    int j0 = blockIdx.y * 256;
    sj[threadIdx.x] = s[j0 + threadIdx.x];
    float si = s[i];
    __syncthreads();
    int r = 0;
#pragma unroll 8
    for (int jj = 0; jj < 256; ++jj) {
        float v = sj[jj];
        r += (v > si) || (v == si && (j0 + jj) < i);
    }
    atomicAdd(&rank[i], r);
}

__global__ void scatter_topk_all(const float* __restrict__ s, const int* __restrict__ rank,
                                 int n, int k, int* __restrict__ perm,
                                 float* __restrict__ vals, int* __restrict__ invp) {
    int i = blockIdx.x * TPB + threadIdx.x;
    if (i >= n) return;
    int r = rank[i];
    if (r < k) { perm[r] = i; vals[r] = s[i]; invp[i] = r; }
    else invp[i] = -1;
}

__global__ void gather_feat(const float* __restrict__ x, const int* __restrict__ perm,
                            const float* __restrict__ vals, int k, int f, float* __restrict__ h) {
    int id = blockIdx.x * TPB + threadIdx.x;
    if (id >= k * f) return;
    int r = id / f, c = id - r * f;
    h[id] = x[(size_t)perm[r] * f + c] * vals[r];
}

// ---------------- level-1 augment: sparse SpGEMM ----------------
__global__ void spgemm_aug(const int* __restrict__ nbr, const float* __restrict__ awt,
                           const int* __restrict__ acnt, const int* __restrict__ perm,
                           const int* __restrict__ invp, int k,
                           ushort* __restrict__ Chi, ushort* __restrict__ Clo,
                           float* __restrict__ dinv, float* __restrict__ selfw) {
    __shared__ float row[2048];
    int r = blockIdx.x, tid = threadIdx.x;
    int pi = perm[r];
    for (int j = tid; j < k; j += TPB) row[j] = 0.f;
    __syncthreads();
    int cnt = acnt[pi];
    for (int a = 0; a < cnt; ++a) {
        int t = nbr[pi * MAXN + a];
        float w1 = awt[pi * MAXN + a];
        int c2 = acnt[t];
        for (int b = tid; b < c2; b += TPB) {
            int s = nbr[t * MAXN + b];
            int j = invp[s];
            if (j >= 0) atomicAdd(&row[j], w1 * awt[t * MAXN + b]);
        }
    }
    __syncthreads();
    float psum = 0.f;
    for (int j = tid; j < k; j += TPB) {
        float v = (j == r) ? 0.f : row[j];
        psum += v;
        ushort hi = f32_to_bf16(v);
        size_t o = (size_t)r * k + j;
        Chi[o] = hi;
        Clo[o] = f32_to_bf16(v - bf2f(hi));
    }
    for (int o = 32; o; o >>= 1) psum += __shfl_xor(psum, o);
    __shared__ float sh[4];
    if ((tid & 63) == 0) sh[tid >> 6] = psum;
    __syncthreads();
    if (tid == 0) {
        float tot = sh[0] + sh[1] + sh[2] + sh[3];
        dinv[r] = 1.0f / sqrtf(tot + 2.0f);
        selfw[r] = 2.0f;
    }
}

// ---------------- dense augment (levels 2,3): split-K + finalize -----------
__global__ void transpose_aug_hl(const ushort* __restrict__ Ahi, const ushort* __restrict__ Alo,
                                 ushort* __restrict__ T, int n) {
    __shared__ float tile[64][65];
    int c0 = blockIdx.x * 64, r0 = blockIdx.y * 64;
    for (int t = threadIdx.x; t < 4096; t += TPB) {
        int r = t >> 6, c = t & 63;
        size_t o = (size_t)(r0 + r) * n + (c0 + c);
        float v = bf2f(Ahi[o]) + bf2f(Alo[o]);
        if (r0 + r == c0 + c) v += 1.0f;
        tile[c][r] = v;
    }
    __syncthreads();
    for (int t = threadIdx.x; t < 4096; t += TPB) {
        int c = t >> 6, r = t & 63;
        T[(size_t)(c0 + c) * n + (r0 + r)] = f32_to_bf16(tile[c][r]);
    }
}

__global__ void gather_rows_aug_hl(const ushort* __restrict__ Ahi, const ushort* __restrict__ Alo,
                                   const int* __restrict__ perm, ushort* __restrict__ Ag,
                                   int n, int rows) {
    int id = blockIdx.x * TPB + threadIdx.x;
    if (id >= rows * n) return;
    int r = id / n, t = id - r * n;
    int pr = perm[r];
    size_t o = (size_t)pr * n + t;
    float v = bf2f(Ahi[o]) + bf2f(Alo[o]);
    if (pr == t) v += 1.0f;
    Ag[id] = f32_to_bf16(v);
}

__global__ void gather_rows_u16(const ushort* __restrict__ T, const int* __restrict__ perm,
                                ushort* __restrict__ Bg, int n, int rows) {
    int id = blockIdx.x * TPB + threadIdx.x;
    if (id >= rows * n) return;
    int r = id / n, t = id - r * n;
    Bg[id] = T[(size_t)perm[r] * n + t];
}

__global__ void __launch_bounds__(256)
aug_gemm_acc(const ushort* __restrict__ Ag, const ushort* __restrict__ Bg,
             float* __restrict__ Caug, int K, int ldc, int kpb) {
    __shared__ __align__(16) ushort As[64 * LDK];
    __shared__ __align__(16) ushort Bs[64 * LDK];
    int tid = threadIdx.x;
    int wave = tid >> 6, lane = tid & 63;
    int wr = wave >> 1, wc = wave & 1;
    int m = lane & 15, quad = lane >> 4;
    int i0 = blockIdx.y * 64, j0 = blockIdx.x * 64;
    int kbeg = blockIdx.z * kpb;
    f32x4 acc[2][2];
#pragma unroll
    for (int a = 0; a < 2; ++a)
#pragma unroll
        for (int b = 0; b < 2; ++b) acc[a][b] = (f32x4){0.f, 0.f, 0.f, 0.f};
    const ushort* Ab = Ag + (size_t)i0 * K;
    const ushort* Bb = Bg + (size_t)j0 * K;
    for (int k0 = kbeg; k0 < kbeg + kpb; k0 += 64) {
#pragma unroll
        for (int v = 0; v < 2; ++v) {
            int idx = tid + (v << 8);
            int r = idx >> 3, c8 = idx & 7;
            *(uint4*)&As[r * LDK + c8 * 8] = *(const uint4*)&Ab[(size_t)r * K + k0 + c8 * 8];
            *(uint4*)&Bs[r * LDK + c8 * 8] = *(const uint4*)&Bb[(size_t)r * K + k0 + c8 * 8];
        }
        __syncthreads();
#pragma unroll
        for (int kk = 0; kk < 2; ++kk) {
            bf16x8 af[2], bfr[2];
#pragma unroll
            for (int mi = 0; mi < 2; ++mi)
                af[mi] = *(const bf16x8*)&As[(wr * 32 + mi * 16 + m) * LDK + kk * 32 + quad * 8];
#pragma unroll
            for (int ni = 0; ni < 2; ++ni)
                bfr[ni] = *(const bf16x8*)&Bs[(wc * 32 + ni * 16 + m) * LDK + kk * 32 + quad * 8];
#pragma unroll
            for (int mi = 0; mi < 2; ++mi)
#pragma unroll
                for (int ni = 0; ni < 2; ++ni)
                    acc[mi][ni] = __builtin_amdgcn_mfma_f32_16x16x32_bf16(
                        af[mi], bfr[ni], acc[mi][ni], 0, 0, 0);
        }
        __syncthreads();
    }
#pragma unroll
    for (int mi = 0; mi < 2; ++mi)
#pragma unroll
        for (int ni = 0; ni < 2; ++ni)
#pragma unroll
            for (int r = 0; r < 4; ++r) {
                int gi = i0 + wr * 32 + mi * 16 + quad * 4 + r;
                int gj = j0 + wc * 32 + ni * 16 + m;
                atomicAdd(&Caug[(size_t)gi * ldc + gj], acc[mi][ni][r]);
            }
}

__global__ void aug_finalize(const float* __restrict__ Caug, int k,
                             ushort* __restrict__ Chi, ushort* __restrict__ Clo,
                             float* __restrict__ dinv, float* __restrict__ selfw) {
    int r = blockIdx.x, tid = threadIdx.x;
    const float* row = Caug + (size_t)r * k;
    float psum = 0.f;
    for (int j = tid; j < k; j += TPB) {
        float v = (j == r) ? 0.f : row[j];
        psum += v;
        ushort hi = f32_to_bf16(v);
        size_t o = (size_t)r * k + j;
        Chi[o] = hi;
        Clo[o] = f32_to_bf16(v - bf2f(hi));
    }
    for (int o = 32; o; o >>= 1) psum += __shfl_xor(psum, o);
    __shared__ float sh[4];
    if ((tid & 63) == 0) sh[tid >> 6] = psum;
    __syncthreads();
    if (tid == 0) {
        float tot = sh[0] + sh[1] + sh[2] + sh[3];
        dinv[r] = 1.0f / sqrtf(tot + 2.0f);
        selfw[r] = 2.0f;
    }
}

// ---------------- dense GCN aggregation (levels >=1) ----------------
__global__ void __launch_bounds__(256)
gcn_gemm(const ushort* __restrict__ Ahi, const ushort* __restrict__ Alo,
         const ushort* __restrict__ Bhi, const ushort* __restrict__ Blo,
         float* __restrict__ C, int K, int ldc, int kpb) {
    __shared__ __align__(16) ushort sAh[64 * LDK];
    __shared__ __align__(16) ushort sAl[64 * LDK];
    __shared__ __align__(16) ushort sBh[64 * LDK];
    __shared__ __align__(16) ushort sBl[64 * LDK];
    int tid = threadIdx.x;
    int wave = tid >> 6, lane = tid & 63;
    int wr = wave >> 1, wc = wave & 1;
    int m = lane & 15, quad = lane >> 4;
    int i0 = blockIdx.y * 64, j0 = blockIdx.x * 64;
    int kbeg = blockIdx.z * kpb;
    f32x4 acc[2][2];
#pragma unroll
    for (int a = 0; a < 2; ++a)
#pragma unroll
        for (int b = 0; b < 2; ++b) acc[a][b] = (f32x4){0.f, 0.f, 0.f, 0.f};
    for (int k0 = kbeg; k0 < kbeg + kpb; k0 += 64) {
#pragma unroll
        for (int v = 0; v < 2; ++v) {
            int idx = tid + (v << 8);
            int r = idx >> 3, c8 = idx & 7;
            size_t boff = (size_t)(j0 + r) * K + k0 + c8 * 8;
            *(uint4*)&sBh[r * LDK + c8 * 8] = *(const uint4*)&Bhi[boff];
            *(uint4*)&sBl[r * LDK + c8 * 8] = *(const uint4*)&Blo[boff];
            size_t aoff = (size_t)(i0 + r) * K + k0 + c8 * 8;
            *(uint4*)&sAh[r * LDK + c8 * 8] = *(const uint4*)&Ahi[aoff];
            *(uint4*)&sAl[r * LDK + c8 * 8] = *(const uint4*)&Alo[aoff];
        }
        __syncthreads();
#pragma unroll
        for (int kk = 0; kk < 2; ++kk) {
            bf16x8 ah[2], al[2], bh[2], bl[2];
#pragma unroll
            for (int mi = 0; mi < 2; ++mi) {
                ah[mi] = *(const bf16x8*)&sAh[(wr * 32 + mi * 16 + m) * LDK + kk * 32 + quad * 8];
                al[mi] = *(const bf16x8*)&sAl[(wr * 32 + mi * 16 + m) * LDK + kk * 32 + quad * 8];
            }
#pragma unroll
            for (int ni = 0; ni < 2; ++ni) {
                bh[ni] = *(const bf16x8*)&sBh[(wc * 32 + ni * 16 + m) * LDK + kk * 32 + quad * 8];
                bl[ni] = *(const bf16x8*)&sBl[(wc * 32 + ni * 16 + m) * LDK + kk * 32 + quad * 8];
            }
#pragma unroll
            for (int mi = 0; mi < 2; ++mi)
#pragma unroll
                for (int ni = 0; ni < 2; ++ni) {
                    acc[mi][ni] = __builtin_amdgcn_mfma_f32_16x16x32_bf16(ah[mi], bh[ni], acc[mi][ni], 0, 0, 0);
                    acc[mi][ni] = __builtin_amdgcn_mfma_f32_16x16x32_bf16(ah[mi], bl[ni], acc[mi][ni], 0, 0, 0);
                    acc[mi][ni] = __builtin_amdgcn_mfma_f32_16x16x32_bf16(al[mi], bh[ni], acc[mi][ni], 0, 0, 0);
                }
        }
        __syncthreads();
    }
#pragma unroll
    for (int mi = 0; mi < 2; ++mi)
#pragma unroll
        for (int ni = 0; ni < 2; ++ni)
#pragma unroll
            for (int r = 0; r < 4; ++r) {
                int gi = i0 + wr * 32 + mi * 16 + quad * 4 + r;
                int gj = j0 + wc * 32 + ni * 16 + m;
                atomicAdd(&C[(size_t)gi * ldc + gj], acc[mi][ni][r]);
            }
}

__global__ void build_yT_z(const float* __restrict__ xw, const float* __restrict__ dinv,
                           ushort* __restrict__ Bhi, ushort* __restrict__ Blo,
                           float* __restrict__ Cp, int n, int f) {
    __shared__ float t[64][65];
    int k0 = blockIdx.x * 64, c0 = blockIdx.y * 64;
#pragma unroll
    for (int v = 0; v < 16; ++v) {
        int idx = threadIdx.x + v * 256;
        int r = idx >> 6, c = idx & 63;
        t[r][c] = xw[(size_t)(k0 + r) * f + (c0 + c)] * dinv[k0 + r];
        Cp[(size_t)(k0 + r) * f + (c0 + c)] = 0.f;
    }
    __syncthreads();
#pragma unroll
    for (int v = 0; v < 16; ++v) {
        int idx = threadIdx.x + v * 256;
        int c = idx >> 6, k = idx & 63;
        float val = t[k][c];
        ushort hi = f32_to_bf16(val);
        size_t o = (size_t)(c0 + c) * n + (k0 + k);
        Bhi[o] = hi;
        Blo[o] = f32_to_bf16(val - bf2f(hi));
    }
}

__global__ void gcn_epilogue(const float* __restrict__ C, const float* __restrict__ xw,
                             const float* __restrict__ dinv, const float* __restrict__ selfw,
                             const float* __restrict__ b, float* __restrict__ out,
                             int n, int f, int relu) {
    int id = blockIdx.x * TPB + threadIdx.x;
    if (id >= n * f) return;
    int i = id / f, c = id - i * f;
    float y = xw[id] * dinv[i];
    float v = dinv[i] * (C[id] + selfw[i] * y) + b[c];
    if (relu) v = fmaxf(v, 0.f);
    out[id] = v;
}

// ---------------- up path: fused unpool ----------------
__global__ void unpool_add(const float* __restrict__ xsrc, const float* __restrict__ h,
                           const int* __restrict__ invp, int n, int f, float* __restrict__ t) {
    int id = blockIdx.x * TPB + threadIdx.x;
    if (id >= n * f) return;
    int i = id / f, c = id - i * f;
    int r = invp[i];
    float v = xsrc[id];
    if (r >= 0) v += h[(size_t)r * f + c];
    t[id] = v;
}

// ---------------- layernorm ----------------
__global__ void layernorm(const float* __restrict__ h, const float* __restrict__ g,
                          const float* __restrict__ b, float* __restrict__ u, int n) {
    int i = blockIdx.x;
    int t = threadIdx.x;
    float v = h[(size_t)i * 128 + t];
    __shared__ float s0[2], s1[2];
    float sum = v;
    for (int o = 32; o; o >>= 1) sum += __shfl_xor(sum, o);
    if ((t & 63) == 0) s0[t >> 6] = sum;
    __syncthreads();
    float mu = (s0[0] + s0[1]) * (1.0f / 128.0f);
    float d = v - mu;
    float sq = d * d;
    for (int o = 32; o; o >>= 1) sq += __shfl_xor(sq, o);
    if ((t & 63) == 0) s1[t >> 6] = sq;
    __syncthreads();
    float var = (s1[0] + s1[1]) * (1.0f / 128.0f);
    u[(size_t)i * 128 + t] = d / sqrtf(var + 1e-6f) * g[t] + b[t];
}

// ---------------- dense projections via split-bf16 MFMA --------------------
__global__ void transpose_split(const float* __restrict__ W, ushort* __restrict__ Bhi,
                                ushort* __restrict__ Blo, int K, int N) {
    __shared__ float tile[64][65];
    int n0 = blockIdx.x * 64, k0 = blockIdx.y * 64;
    for (int t = threadIdx.x; t < 4096; t += TPB) {
        int r = t >> 6, c = t & 63;
        tile[r][c] = W[(size_t)(k0 + r) * N + (n0 + c)];
    }
    __syncthreads();
    for (int t = threadIdx.x; t < 4096; t += TPB) {
        int c = t >> 6, r = t & 63;
        float v = tile[r][c];
        ushort hi = f32_to_bf16(v);
        size_t o = (size_t)(n0 + c) * K + (k0 + r);
        Bhi[o] = hi;
        Blo[o] = f32_to_bf16(v - bf2f(hi));
    }
}

__global__ void __launch_bounds__(256)
gemm_bt_store(const float* __restrict__ A, const ushort* __restrict__ Bhi,
              const ushort* __restrict__ Blo, const float* __restrict__ bias,
              float* __restrict__ C, int K, int N) {
    __shared__ __align__(16) ushort sAh[64 * LDK];
    __shared__ __align__(16) ushort sAl[64 * LDK];
    __shared__ __align__(16) ushort sBh[64 * LDK];
    __shared__ __align__(16) ushort sBl[64 * LDK];
    int tid = threadIdx.x;
    int wave = tid >> 6, lane = tid & 63;
    int wr = wave >> 1, wc = wave & 1;
    int m = lane & 15, quad = lane >> 4;
    int i0 = blockIdx.y * 64, j0 = blockIdx.x * 64;
    f32x4 acc[2][2];
#pragma unroll
    for (int a = 0; a < 2; ++a)
#pragma unroll
        for (int b = 0; b < 2; ++b) acc[a][b] = (f32x4){0.f, 0.f, 0.f, 0.f};
    for (int k0 = 0; k0 < K; k0 += 64) {
#pragma unroll
        for (int v = 0; v < 2; ++v) {
            int idx = tid + (v << 8);
            int r = idx >> 3, c8 = idx & 7;
            size_t boff = (size_t)(j0 + r) * K + k0 + c8 * 8;
            *(uint4*)&sBh[r * LDK + c8 * 8] = *(const uint4*)&Bhi[boff];
            *(uint4*)&sBl[r * LDK + c8 * 8] = *(const uint4*)&Blo[boff];
            size_t aoff = (size_t)(i0 + r) * K + k0 + c8 * 8;
            float4 fa = *(const float4*)&A[aoff];
            float4 fb = *(const float4*)&A[aoff + 4];
            ushort h0 = f32_to_bf16(fa.x), h1 = f32_to_bf16(fa.y);
            ushort h2 = f32_to_bf16(fa.z), h3 = f32_to_bf16(fa.w);
            ushort h4 = f32_to_bf16(fb.x), h5 = f32_to_bf16(fb.y);
            ushort h6 = f32_to_bf16(fb.z), h7 = f32_to_bf16(fb.w);
            uint4 ph, pl;
            ph.x = (uint)h0 | ((uint)h1 << 16);
            ph.y = (uint)h2 | ((uint)h3 << 16);
            ph.z = (uint)h4 | ((uint)h5 << 16);
            ph.w = (uint)h6 | ((uint)h7 << 16);
            pl.x = (uint)f32_to_bf16(fa.x - bf2f(h0)) | ((uint)f32_to_bf16(fa.y - bf2f(h1)) << 16);
            pl.y = (uint)f32_to_bf16(fa.z - bf2f(h2)) | ((uint)f32_to_bf16(fa.w - bf2f(h3)) << 16);
            pl.z = (uint)f32_to_bf16(fb.x - bf2f(h4)) | ((uint)f32_to_bf16(fb.y - bf2f(h5)) << 16);
            pl.w = (uint)f32_to_bf16(fb.z - bf2f(h6)) | ((uint)f32_to_bf16(fb.w - bf2f(h7)) << 16);
            *(uint4*)&sAh[r * LDK + c8 * 8] = ph;
            *(uint4*)&sAl[r * LDK + c8 * 8] = pl;
        }
        __syncthreads();
#pragma unroll
        for (int kk = 0; kk < 2; ++kk) {
            bf16x8 ah[2], al[2], bh[2], bl[2];
#pragma unroll
            for (int mi = 0; mi < 2; ++mi) {
                ah[mi] = *(const bf16x8*)&sAh[(wr * 32 + mi * 16 + m) * LDK + kk * 32 + quad * 8];
                al[mi] = *(const bf16x8*)&sAl[(wr * 32 + mi * 16 + m) * LDK + kk * 32 + quad * 8];
            }
#pragma unroll
            for (int ni = 0; ni < 2; ++ni) {
                bh[ni] = *(const bf16x8*)&sBh[(wc * 32 + ni * 16 + m) * LDK + kk * 32 + quad * 8];
                bl[ni] = *(const bf16x8*)&sBl[(wc * 32 + ni * 16 + m) * LDK + kk * 32 + quad * 8];
            }
#pragma unroll
            for (int mi = 0; mi < 2; ++mi)
#pragma unroll
                for (int ni = 0; ni < 2; ++ni) {
                    acc[mi][ni] = __builtin_amdgcn_mfma_f32_16x16x32_bf16(ah[mi], bh[ni], acc[mi][ni], 0, 0, 0);
                    acc[mi][ni] = __builtin_amdgcn_mfma_f32_16x16x32_bf16(ah[mi], bl[ni], acc[mi][ni], 0, 0, 0);
                    acc[mi][ni] = __builtin_amdgcn_mfma_f32_16x16x32_bf16(al[mi], bh[ni], acc[mi][ni], 0, 0, 0);
                }
        }
        __syncthreads();
    }
#pragma unroll
    for (int mi = 0; mi < 2; ++mi)
#pragma unroll
        for (int ni = 0; ni < 2; ++ni)
#pragma unroll
            for (int r = 0; r < 4; ++r) {
                int gi = i0 + wr * 32 + mi * 16 + quad * 4 + r;
                int gj = j0 + wc * 32 + ni * 16 + m;
                float v = acc[mi][ni][r];
                if (bias) v += bias[gj];
                C[(size_t)gi * N + gj] = v;
            }
}

__global__ void __launch_bounds__(256)
gemm_bt_split(const float* __restrict__ A, const ushort* __restrict__ Bhi,
              const ushort* __restrict__ Blo, float* __restrict__ C,
              int K, int N, int kpb) {
    __shared__ __align__(16) ushort sAh[64 * LDK];
    __shared__ __align__(16) ushort sAl[64 * LDK];
    __shared__ __align__(16) ushort sBh[64 * LDK];
    __shared__ __align__(16) ushort sBl[64 * LDK];
    int tid = threadIdx.x;
    int wave = tid >> 6, lane = tid & 63;
    int wr = wave >> 1, wc = wave & 1;
    int m = lane & 15, quad = lane >> 4;
    int i0 = blockIdx.y * 64, j0 = blockIdx.x * 64;
    int kbeg = blockIdx.z * kpb;
    f32x4 acc[2][2];
#pragma unroll
    for (int a = 0; a < 2; ++a)
#pragma unroll
        for (int b = 0; b < 2; ++b) acc[a][b] = (f32x4){0.f, 0.f, 0.f, 0.f};
    for (int k0 = kbeg; k0 < kbeg + kpb; k0 += 64) {
#pragma unroll
        for (int v = 0; v < 2; ++v) {
            int idx = tid + (v << 8);
            int r = idx >> 3, c8 = idx & 7;
            size_t boff = (size_t)(j0 + r) * K + k0 + c8 * 8;
            *(uint4*)&sBh[r * LDK + c8 * 8] = *(const uint4*)&Bhi[boff];
            *(uint4*)&sBl[r * LDK + c8 * 8] = *(const uint4*)&Blo[boff];
            size_t aoff = (size_t)(i0 + r) * K + k0 + c8 * 8;
            float4 fa = *(const float4*)&A[aoff];
            float4 fb = *(const float4*)&A[aoff + 4];
            ushort h0 = f32_to_bf16(fa.x), h1 = f32_to_bf16(fa.y);
            ushort h2 = f32_to_bf16(fa.z), h3 = f32_to_bf16(fa.w);
            ushort h4 = f32_to_bf16(fb.x), h5 = f32_to_bf16(fb.y);
            ushort h6 = f32_to_bf16(fb.z), h7 = f32_to_bf16(fb.w);
            uint4 ph, pl;
            ph.x = (uint)h0 | ((uint)h1 << 16);
            ph.y = (uint)h2 | ((uint)h3 << 16);
            ph.z = (uint)h4 | ((uint)h5 << 16);
            ph.w = (uint)h6 | ((uint)h7 << 16);
            pl.x = (uint)f32_to_bf16(fa.x - bf2f(h0)) | ((uint)f32_to_bf16(fa.y - bf2f(h1)) << 16);
            pl.y = (uint)f32_to_bf16(fa.z - bf2f(h2)) | ((uint)f32_to_bf16(fa.w - bf2f(h3)) << 16);
            pl.z = (uint)f32_to_bf16(fb.x - bf2f(h4)) | ((uint)f32_to_bf16(fb.y - bf2f(h5)) << 16);
            pl.w = (uint)f32_to_bf16(fb.z - bf2f(h6)) | ((uint)f32_to_bf16(fb.w - bf2f(h7)) << 16);
            *(uint4*)&sAh[r * LDK + c8 * 8] = ph;
            *(uint4*)&sAl[r * LDK + c8 * 8] = pl;
        }
        __syncthreads();
#pragma unroll
        for (int kk = 0; kk < 2; ++kk) {
            bf16x8 ah[2], al[2], bh[2], bl[2];
#pragma unroll
            for (int mi = 0; mi < 2; ++mi) {
                ah[mi] = *(const bf16x8*)&sAh[(wr * 32 + mi * 16 + m) * LDK + kk * 32 + quad * 8];
                al[mi] = *(const bf16x8*)&sAl[(wr * 32 + mi * 16 + m) * LDK + kk * 32 + quad * 8];
            }
#pragma unroll
            for (int ni = 0; ni < 2; ++ni) {
                bh[ni] = *(const bf16x8*)&sBh[(wc * 32 + ni * 16 + m) * LDK + kk * 32 + quad * 8];
                bl[ni] = *(const bf16x8*)&sBl[(wc * 32 + ni * 16 + m) * LDK + kk * 32 + quad * 8];
            }
#pragma unroll
            for (int mi = 0; mi < 2; ++mi)
#pragma unroll
                for (int ni = 0; ni < 2; ++ni) {
                    acc[mi][ni] = __builtin_amdgcn_mfma_f32_16x16x32_bf16(ah[mi], bh[ni], acc[mi][ni], 0, 0, 0);
                    acc[mi][ni] = __builtin_amdgcn_mfma_f32_16x16x32_bf16(ah[mi], bl[ni], acc[mi][ni], 0, 0, 0);
                    acc[mi][ni] = __builtin_amdgcn_mfma_f32_16x16x32_bf16(al[mi], bh[ni], acc[mi][ni], 0, 0, 0);
                }
        }
        __syncthreads();
    }
#pragma unroll
    for (int mi = 0; mi < 2; ++mi)
#pragma unroll
        for (int ni = 0; ni < 2; ++ni)
#pragma unroll
            for (int r = 0; r < 4; ++r) {
                int gi = i0 + wr * 32 + mi * 16 + quad * 4 + r;
                int gj = j0 + wc * 32 + ni * 16 + m;
                atomicAdd(&C[(size_t)gi * N + gj], acc[mi][ni][r]);
            }
}

// ---------------- GAT ----------------
__global__ void attn_coef2(const float* __restrict__ hf, const float* __restrict__ asrc,
                           const float* __restrict__ adst, float* __restrict__ es,
                           float* __restrict__ ed, int heads) {
    int j = blockIdx.x;
    int wave = threadIdx.x >> 6, lane = threadIdx.x & 63;
    if (wave >= heads) return;
    const float* hp = hf + (size_t)j * heads * 128 + wave * 128;
    float v0 = hp[lane], v1 = hp[lane + 64];
    float a = v0 * asrc[wave * 128 + lane] + v1 * asrc[wave * 128 + lane + 64];
    float d = v0 * adst[wave * 128 + lane] + v1 * adst[wave * 128 + lane + 64];
    for (int o = 32; o; o >>= 1) { a += __shfl_xor(a, o); d += __shfl_xor(d, o); }
    if (lane == 0) { es[j * heads + wave] = a; ed[j * heads + wave] = d; }
}

__global__ void gat_sparse(const int* __restrict__ nbr, const int* __restrict__ ncnt, int n,
                           const float* __restrict__ hf, const float* __restrict__ es,
                           const float* __restrict__ ed, const float* __restrict__ bias,
                           const float* __restrict__ resid, float* __restrict__ out,
                           int heads, int mode) {
    int i = blockIdx.x;
    int tid = threadIdx.x;
    __shared__ int idx[MAXN];
    __shared__ float lg[MAXN * 4];
    __shared__ float hmax[4], hsum[4];
    int m = ncnt[i];
    for (int t = tid; t < m; t += TPB) idx[t] = nbr[i * MAXN + t];
    __syncthreads();
    for (int t = tid; t < m * heads; t += TPB) {
        int jl = t / heads, h = t - jl * heads;
        float l = ed[i * heads + h] + es[idx[jl] * heads + h];
        lg[jl * heads + h] = (l > 0.f) ? l : 0.2f * l;
    }
    __syncthreads();
    int h = tid >> 6, lane = tid & 63;
    if (h < heads) {
        float mx = -3.4e38f;
        for (int jl = lane; jl < m; jl += 64) mx = fmaxf(mx, lg[jl * heads + h]);
        for (int o = 32; o; o >>= 1) mx = fmaxf(mx, __shfl_xor(mx, o));
        if (lane == 0) hmax[h] = mx;
    }
    __syncthreads();
    if (h < heads) {
        float mx = hmax[h];
        float sm = 0.f;
        for (int jl = lane; jl < m; jl += 64) {
            float p = expf(lg[jl * heads + h] - mx);
            lg[jl * heads + h] = p;
            sm += p;
        }
        for (int o = 32; o; o >>= 1) sm += __shfl_xor(sm, o);
        if (lane == 0) hsum[h] = sm;
    }
    __syncthreads();
    int width = heads * 128;
    for (int o = tid; o < width; o += TPB) {
        int hh = o >> 7;
        float acc = 0.f;
        for (int jl = 0; jl < m; ++jl)
            acc += lg[jl * heads + hh] * hf[(size_t)idx[jl] * width + o];
        float v = acc / hsum[hh] + bias[o];
        if (mode == 0) v = (v > 0.f) ? v : expm1f(v);
        else v += resid[(size_t)i * width + o];
        out[(size_t)i * width + o] = v;
    }
}

// ---------------------------------------------------------------------------
static inline int cdiv(int a, int b) { return (a + b - 1) / b; }

static int pick_z(int gx, int gy, int K) {
    int z = 1;
    while (gx * gy * z < 384 && K / (2 * z) >= 64) z <<= 1;
    return z;
}

static void run_gcn_dense(hipStream_t stream, const ushort* Ahi, const ushort* Alo,
                          int n, const float* xin, int fin,
                          const float* W, const float* bias, int f,
                          const float* dinv, const float* selfw,
                          float* xw, ushort* yThi, ushort* yTlo, float* Cp,
                          float* out, int relu) {
    xw_gemm<<<cdiv(n, TPB / f), TPB, 0, stream>>>(xin, W, xw, n, fin, f);
    build_yT_z<<<dim3(n / 64, f / 64), TPB, 0, stream>>>(xw, dinv, yThi, yTlo, Cp, n, f);
    int z = pick_z(f / 64, n / 64, n);
    gcn_gemm<<<dim3(f / 64, n / 64, z), TPB, 0, stream>>>(Ahi, Alo, yThi, yTlo, Cp, n, f, n / z);
    gcn_epilogue<<<cdiv(n * f, TPB), TPB, 0, stream>>>(Cp, xw, dinv, selfw, bias, out, n, f, relu);
}

static void run_gcn_sparse(hipStream_t stream, const int* nbr, const float* awt,
                           const int* acnt, int n, const float* xin, int fin,
                           const float* W, const float* bias, int f,
                           const float* dinv, const float* selfw,
                           float* xw, float* out, int relu) {
    xw_gemm<<<cdiv(n, TPB / f), TPB, 0, stream>>>(xin, W, xw, n, fin, f);
    spmv_gcn<<<n, f, 0, stream>>>(nbr, awt, acnt, xw, dinv, selfw, bias, out, f, relu);
}

static void run_topk(hipStream_t stream, const float* score, int n, int k, int* rank,
                     int* perm, float* vals, int* invp) {
    hipMemsetAsync(rank, 0, n * sizeof(int), stream);
    rank_count<<<dim3(n / 256, n / 256), 256, 0, stream>>>(score, n, rank);
    scatter_topk_all<<<cdiv(n, TPB), TPB, 0, stream>>>(score, rank, n, k, perm, vals, invp);
}

static void run_aug_dense(hipStream_t stream, const ushort* Ahi, const ushort* Alo, int n,
                          const int* perm, int k, ushort* Tbf, ushort* Agb, ushort* Bgb,
                          float* Caug, ushort* Chi, ushort* Clo, float* dinv, float* selfw) {
    transpose_aug_hl<<<dim3(n / 64, n / 64), TPB, 0, stream>>>(Ahi, Alo, Tbf, n);
    gather_rows_aug_hl<<<cdiv(k * n, TPB), TPB, 0, stream>>>(Ahi, Alo, perm, Agb, n, k);
    gather_rows_u16<<<cdiv(k * n, TPB), TPB, 0, stream>>>(Tbf, perm, Bgb, n, k);
    hipMemsetAsync(Caug, 0, (size_t)k * k * sizeof(float), stream);
    int z = 8;
    aug_gemm_acc<<<dim3(k / 64, k / 64, z), TPB, 0, stream>>>(Agb, Bgb, Caug, n, k, n / z);
    aug_finalize<<<k, TPB, 0, stream>>>(Caug, k, Chi, Clo, dinv, selfw);
}

extern "C" void kernel_launch(void* const* d_in, const int* in_sizes, int n_in,
                              void* d_out, int out_size, void* d_ws, size_t ws_size,
                              hipStream_t stream) {
    const float* x   = (const float*)d_in[0];
    const int*   ei  = (const int*)d_in[1];
    const float* w0  = (const float*)d_in[2];  const float* b0  = (const float*)d_in[3];
    const float* w1  = (const float*)d_in[4];  const float* b1  = (const float*)d_in[5];
    const float* w2  = (const float*)d_in[6];  const float* b2  = (const float*)d_in[7];
    const float* w3  = (const float*)d_in[8];  const float* b3  = (const float*)d_in[9];
    const float* p1  = (const float*)d_in[10];
    const float* p2  = (const float*)d_in[11];
    const float* p3  = (const float*)d_in[12];
    const float* uw0 = (const float*)d_in[13]; const float* ub0 = (const float*)d_in[14];
    const float* uw1 = (const float*)d_in[15]; const float* ub1 = (const float*)d_in[16];
    const float* uw2 = (const float*)d_in[17]; const float* ub2 = (const float*)d_in[18];
    const float* lng = (const float*)d_in[19]; const float* lnb = (const float*)d_in[20];
    const float* rw  = (const float*)d_in[21]; const float* rb  = (const float*)d_in[22];
    const float* g1w = (const float*)d_in[23];
    const float* g1as = (const float*)d_in[24]; const float* g1ad = (const float*)d_in[25];
    const float* g1b = (const float*)d_in[26];
    const float* g2w = (const float*)d_in[27];
    const float* g2as = (const float*)d_in[28]; const float* g2ad = (const float*)d_in[29];
    const float* g2b = (const float*)d_in[30];

    const int N = 4096, E = 65536;
    const int K1 = 2048, K2 = 1024, K3 = 512;

    float* base = (float*)d_ws;
    size_t off = 0;
    auto alloc = [&](size_t nf) { float* p = base + off; off += (nf + 63) & ~(size_t)63; return p; };

    ushort* A1hi = (ushort*)alloc((size_t)K1 * K1 / 2);
    ushort* A1lo = (ushort*)alloc((size_t)K1 * K1 / 2);
    ushort* A2hi = (ushort*)alloc((size_t)K2 * K2 / 2);
    ushort* A2lo = (ushort*)alloc((size_t)K2 * K2 / 2);
    ushort* A3hi = (ushort*)alloc((size_t)K3 * K3 / 2);
    ushort* A3lo = (ushort*)alloc((size_t)K3 * K3 / 2);
    ushort* Tbf  = (ushort*)alloc((size_t)K1 * K1 / 2);
    ushort* Agb  = (ushort*)alloc((size_t)K2 * K1 / 2);
    ushort* Bgb  = (ushort*)alloc((size_t)K2 * K1 / 2);
    ushort* yThi = (ushort*)alloc((size_t)128 * N / 2);
    ushort* yTlo = (ushort*)alloc((size_t)128 * N / 2);
    ushort* Whi  = (ushort*)alloc((size_t)512 * 128 / 2);
    ushort* Wlo  = (ushort*)alloc((size_t)512 * 128 / 2);
    float* Caug  = alloc((size_t)K2 * K2);
    float* Cp    = alloc((size_t)N * 128);
    float* x0    = alloc((size_t)N * 64);
    float* x1    = alloc((size_t)K1 * 64);
    float* x2    = alloc((size_t)K2 * 64);
    float* x3    = alloc((size_t)K3 * 64);
    float* h1    = alloc((size_t)K1 * 64);
    float* h2    = alloc((size_t)K2 * 64);
    float* h3    = alloc((size_t)K3 * 64);
    float* xw    = alloc((size_t)N * 128);
    float* dinv0 = alloc(N);  float* selfw0 = alloc(N);
    float* dinv1 = alloc(K1); float* selfw1 = alloc(K1);
    float* dinv2 = alloc(K2); float* selfw2 = alloc(K2);
    float* dinv3 = alloc(K3); float* selfw3 = alloc(K3);
    int*   cursor= (int*)alloc(N);
    int*   buck  = (int*)alloc((size_t)N * MAXN);
    float* score = alloc(N);
    int*   rank  = (int*)alloc(N);
    float* vals1 = alloc(K1); float* vals2 = alloc(K2); float* vals3 = alloc(K3);
    int*   perm1 = (int*)alloc(K1); int* perm2 = (int*)alloc(K2); int* perm3 = (int*)alloc(K3);
    int*   invp1 = (int*)alloc(N);  int* invp2 = (int*)alloc(K1); int* invp3 = (int*)alloc(K2);
    int*   nbr   = (int*)alloc((size_t)N * MAXN);
    float* awt   = alloc((size_t)N * MAXN);
    int*   acnt  = (int*)alloc(N);
    float* t2    = alloc((size_t)K2 * 64);
    float* t1    = alloc((size_t)K1 * 64);
    float* t0    = alloc((size_t)N * 64);
    float* hfin  = alloc((size_t)N * 128);
    float* u     = alloc((size_t)N * 128);
    float* resid = alloc((size_t)N * 128);
    float* hf1   = alloc((size_t)N * 512);
    float* es1   = alloc((size_t)N * 4); float* ed1 = alloc((size_t)N * 4);
    float* g1    = alloc((size_t)N * 512);
    float* hf2   = alloc((size_t)N * 128);
    float* es2   = alloc(N); float* ed2 = alloc(N);
    (void)ws_size; (void)n_in; (void)in_sizes; (void)out_size;

    // ---- CSR build: bucket scatter + per-row dedupe ----
    hipMemsetAsync(cursor, 0, N * sizeof(int), stream);
    bucket_scatter<<<cdiv(E, TPB), TPB, 0, stream>>>(ei, E, buck, cursor);
    build_csr<<<N, 64, 0, stream>>>(buck, cursor, N, nbr, awt, acnt, dinv0, selfw0);

    // ---- down level 0 (sparse) ----
    run_gcn_sparse(stream, nbr, awt, acnt, N, x, 3, w0, b0, 64, dinv0, selfw0, xw, x0, 1);

    // ---- level 1: topk + sparse SpGEMM augment ----
    score_kernel2<<<cdiv(N, TPB), TPB, 0, stream>>>(x0, p1, score, N);
    run_topk(stream, score, N, K1, rank, perm1, vals1, invp1);
    spgemm_aug<<<K1, TPB, 0, stream>>>(nbr, awt, acnt, perm1, invp1, K1,
                                       A1hi, A1lo, dinv1, selfw1);
    gather_feat<<<cdiv(K1 * 64, TPB), TPB, 0, stream>>>(x0, perm1, vals1, K1, 64, h1);
    run_gcn_dense(stream, A1hi, A1lo, K1, h1, 64, w1, b1, 64,
                  dinv1, selfw1, xw, yThi, yTlo, Cp, x1, 1);

    // ---- level 2 (dense split-K augment) ----
    score_kernel2<<<cdiv(K1, TPB), TPB, 0, stream>>>(x1, p2, score, K1);
    run_topk(stream, score, K1, K2, rank, perm2, vals2, invp2);
    run_aug_dense(stream, A1hi, A1lo, K1, perm2, K2, Tbf, Agb, Bgb, Caug,
                  A2hi, A2lo, dinv2, selfw2);
    gather_feat<<<cdiv(K2 * 64, TPB), TPB, 0, stream>>>(x1, perm2, vals2, K2, 64, h2);
    run_gcn_dense(stream, A2hi, A2lo, K2, h2, 64, w2, b2, 64,
                  dinv2, selfw2, xw, yThi, yTlo, Cp, x2, 1);

    // ---- level 3 (dense split-K augment) ----
    score_kernel2<<<cdiv(K2, TPB), TPB, 0, stream>>>(x2, p3, score, K2);
    run_topk(stream, score, K2, K3, rank, perm3, vals3, invp3);
    run_aug_dense(stream, A2hi, A2lo, K2, perm3, K3, Tbf, Agb, Bgb, Caug,
                  A3hi, A3lo, dinv3, selfw3);
    gather_feat<<<cdiv(K3 * 64, TPB), TPB, 0, stream>>>(x2, perm3, vals3, K3, 64, h3);
    run_gcn_dense(stream, A3hi, A3lo, K3, h3, 64, w3, b3, 64,
                  dinv3, selfw3, xw, yThi, yTlo, Cp, x3, 1);

    // ---- up path (fused unpool) ----
    unpool_add<<<cdiv(K2 * 64, TPB), TPB, 0, stream>>>(x2, x3, invp3, K2, 64, t2);
    run_gcn_dense(stream, A2hi, A2lo, K2, t2, 64, uw0, ub0, 64,
                  dinv2, selfw2, xw, yThi, yTlo, Cp, h2, 1);

    unpool_add<<<cdiv(K1 * 64, TPB), TPB, 0, stream>>>(x1, h2, invp2, K1, 64, t1);
    run_gcn_dense(stream, A1hi, A1lo, K1, t1, 64, uw1, ub1, 64,
                  dinv1, selfw1, xw, yThi, yTlo, Cp, h1, 1);

    unpool_add<<<cdiv(N * 64, TPB), TPB, 0, stream>>>(x0, h1, invp1, N, 64, t0);
    run_gcn_sparse(stream, nbr, awt, acnt, N, t0, 64, uw2, ub2, 128,
                   dinv0, selfw0, xw, hfin, 0);

    // ---- layernorm + residual (direct store) ----
    layernorm<<<N, 128, 0, stream>>>(hfin, lng, lnb, u, N);
    transpose_split<<<dim3(2, 2), TPB, 0, stream>>>(rw, Whi, Wlo, 128, 128);
    gemm_bt_store<<<dim3(2, N / 64), TPB, 0, stream>>>(u, Whi, Wlo, rb, resid, 128, 128);

    // ---- GAT layer 1 (4 heads, concat, ELU) ----
    transpose_split<<<dim3(8, 2), TPB, 0, stream>>>(g1w, Whi, Wlo, 128, 512);
    gemm_bt_store<<<dim3(8, N / 64), TPB, 0, stream>>>(u, Whi, Wlo, nullptr, hf1, 128, 512);
    attn_coef2<<<N, 256, 0, stream>>>(hf1, g1as, g1ad, es1, ed1, 4);
    gat_sparse<<<N, TPB, 0, stream>>>(nbr, acnt, N, hf1, es1, ed1, g1b, nullptr, g1, 4, 0);

    // ---- GAT layer 2 (1 head) + residual ----
    transpose_split<<<dim3(2, 8), TPB, 0, stream>>>(g2w, Whi, Wlo, 512, 128);
    hipMemsetAsync(hf2, 0, (size_t)N * 128 * sizeof(float), stream);
    gemm_bt_split<<<dim3(2, N / 64, 4), TPB, 0, stream>>>(g1, Whi, Wlo, hf2, 512, 128, 128);
    attn_coef2<<<N, 64, 0, stream>>>(hf2, g2as, g2ad, es2, ed2, 1);
    gat_sparse<<<N, TPB, 0, stream>>>(nbr, acnt, N, hf2, es2, ed2, g2b, resid, (float*)d_out, 1, 1);
}

// Round 11
// 457.565 us; speedup vs baseline: 1.5147x; 1.0632x over previous
//
#include <hip/hip_runtime.h>
#include <math.h>

// ---------------------------------------------------------------------------
// GraphUNet + GAT pipeline. N=4096, E=65536, IN=3, H=64, OUT=128, HEADS=4
// Round 11: dispatch-chain reduction with big-grid fusions:
//  - fused_in_gemm: (gather|unpool) + xw projection + yT split + Cp zero
//  - xw_gemm_unpool: final level-0 unpool + 64->128 projection
//  - prep_weights: all three projection-weight transpose/splits in one kernel
// ---------------------------------------------------------------------------

#define TPB 256
#define LDK 88
#define MAXN 128

typedef __attribute__((ext_vector_type(8))) short bf16x8;
typedef __attribute__((ext_vector_type(4))) float f32x4;

__device__ inline ushort f32_to_bf16(float v) {
    unsigned b = __float_as_uint(v);
    return (ushort)((b + 0x7FFF + ((b >> 16) & 1)) >> 16);
}
__device__ inline float bf2f(ushort u) { return __uint_as_float(((unsigned)u) << 16); }

// ---------------- CSR build (bucket scatter + dedupe) ----------------
__global__ void bucket_scatter(const int* __restrict__ ei, int E, int* __restrict__ buck,
                               int* __restrict__ cursor) {
    int e = blockIdx.x * TPB + threadIdx.x;
    if (e >= E) return;
    int src = ei[e];
    int dst = ei[E + e];
    int pos = atomicAdd(&cursor[dst], 1);
    if (pos < MAXN) buck[dst * MAXN + pos] = src;
}

__global__ void build_csr(const int* __restrict__ buck, const int* __restrict__ cursor,
                          int n, int* __restrict__ nbr, float* __restrict__ awt,
                          int* __restrict__ acnt, float* __restrict__ dinv,
                          float* __restrict__ selfw) {
    int i = blockIdx.x;
    int tid = threadIdx.x;          // 64 threads
    __shared__ int s[MAXN];
    __shared__ int outcnt, selfFound;
    int raw = cursor[i];
    int d = min(raw, MAXN);
    if (tid == 0) { outcnt = 0; selfFound = 0; }
    for (int p = tid; p < d; p += 64) s[p] = buck[i * MAXN + p];
    __syncthreads();
    for (int p = tid; p < d; p += 64)
        if (s[p] == i) atomicOr(&selfFound, 1);
    __syncthreads();
    for (int p = tid; p < d; p += 64) {
        int v = s[p];
        bool first = true;
        for (int q = 0; q < p; ++q)
            if (s[q] == v) { first = false; break; }
        if (first) {
            int w = 1;
            for (int q = p + 1; q < d; ++q) w += (s[q] == v);
            int slot = atomicAdd(&outcnt, 1);
            nbr[i * MAXN + slot] = v;
            awt[i * MAXN + slot] = (float)w + (v == i ? 1.0f : 0.0f);
        }
    }
    __syncthreads();
    if (tid == 0) {
        int cnt = outcnt;
        if (!selfFound && cnt < MAXN) {
            nbr[i * MAXN + cnt] = i;
            awt[i * MAXN + cnt] = 1.0f;
            ++cnt;
        }
        acnt[i] = cnt;
        float sw = selfFound ? 0.f : 2.f;
        dinv[i] = 1.0f / sqrtf((float)raw + sw);
        selfw[i] = sw;
    }
}

// ---------------- xw projection (level-0 down, fin=3) ----------------
__global__ void xw_gemm(const float* __restrict__ xin, const float* __restrict__ W,
                        float* __restrict__ C, int n, int fin, int f) {
    __shared__ float sW[64 * 128];
    int tid = threadIdx.x;
    for (int t = tid; t < fin * f; t += TPB) sW[t] = W[t];
    __syncthreads();
    int rpb = TPB / f;
    int r = blockIdx.x * rpb + tid / f;
    int c = tid - (tid / f) * f;
    if (r >= n) return;
    const float* xr = xin + (size_t)r * fin;
    float acc = 0.f;
    for (int k = 0; k < fin; ++k) acc += xr[k] * sW[k * f + c];
    C[(size_t)r * f + c] = acc;
}

// level-0 up: in = xsrc + unpool(hprev); C = in @ W (64 -> 128)
__global__ void xw_gemm_unpool(const float* __restrict__ xsrc, const float* __restrict__ hprev,
                               const int* __restrict__ invp, const float* __restrict__ W,
                               float* __restrict__ C, int n) {
    __shared__ float sW[64 * 128];
    __shared__ float sin_[2][64];
    int tid = threadIdx.x;
    for (int t = tid; t < 8192; t += TPB) sW[t] = W[t];
    int r0 = blockIdx.x * 2;
    int lr = tid >> 7, c = tid & 127;
    int r = r0 + lr;
    if (c < 64) {
        float v = xsrc[(size_t)r * 64 + c];
        int q = invp[r];
        if (q >= 0) v += hprev[(size_t)q * 64 + c];
        sin_[lr][c] = v;
    }
    __syncthreads();
    float acc = 0.f;
#pragma unroll
    for (int k = 0; k < 64; ++k) acc += sin_[lr][k] * sW[k * 128 + c];
    C[(size_t)r * 128 + c] = acc;
}

// ---------------- fused dense-level input + projection + yT --------------
// mode 0: in[r] = xsrc[perm[r]] * vals[r]
// mode 1: in[r] = xsrc[r] + (invp[r]>=0 ? hprev[invp[r]] : 0)
// Writes xw (n x 64), yThi/yTlo (64 x n, scaled by dinv), zeros Cp (n x 64).
__global__ void fused_in_gemm(const float* __restrict__ xsrc, const int* __restrict__ perm,
                              const float* __restrict__ vals, const float* __restrict__ hprev,
                              const int* __restrict__ invp, const float* __restrict__ W,
                              const float* __restrict__ dinv, float* __restrict__ xw,
                              ushort* __restrict__ yThi, ushort* __restrict__ yTlo,
                              float* __restrict__ Cp, int n, int mode) {
    __shared__ float sW[64 * 64];
    __shared__ float sin_[4][64];
    __shared__ float sy[4][64];
    int tid = threadIdx.x;
    for (int t = tid; t < 4096; t += TPB) sW[t] = W[t];
    int r0 = blockIdx.x * 4;
    int lr = tid >> 6, c = tid & 63;
    int r = r0 + lr;
    float v;
    if (mode == 0) {
        v = xsrc[(size_t)perm[r] * 64 + c] * vals[r];
    } else {
        v = xsrc[(size_t)r * 64 + c];
        int q = invp[r];
        if (q >= 0) v += hprev[(size_t)q * 64 + c];
    }
    sin_[lr][c] = v;
    __syncthreads();
    float acc = 0.f;
#pragma unroll
    for (int k = 0; k < 64; ++k) acc += sin_[lr][k] * sW[k * 64 + c];
    size_t o = (size_t)r * 64 + c;
    xw[o] = acc;
    Cp[o] = 0.f;
    sy[lr][c] = acc * dinv[r];
    __syncthreads();
    if (lr == 0) {
        float y0 = sy[0][c], y1 = sy[1][c], y2 = sy[2][c], y3 = sy[3][c];
        ushort h0 = f32_to_bf16(y0), h1 = f32_to_bf16(y1);
        ushort h2 = f32_to_bf16(y2), h3 = f32_to_bf16(y3);
        uint2 ph, pl;
        ph.x = (uint)h0 | ((uint)h1 << 16);
        ph.y = (uint)h2 | ((uint)h3 << 16);
        pl.x = (uint)f32_to_bf16(y0 - bf2f(h0)) | ((uint)f32_to_bf16(y1 - bf2f(h1)) << 16);
        pl.y = (uint)f32_to_bf16(y2 - bf2f(h2)) | ((uint)f32_to_bf16(y3 - bf2f(h3)) << 16);
        *(uint2*)&yThi[(size_t)c * n + r0] = ph;
        *(uint2*)&yTlo[(size_t)c * n + r0] = pl;
    }
}

// ---------------- level-0 GCN: fused sparse SpMV ----------------
__global__ void spmv_gcn(const int* __restrict__ nbr, const float* __restrict__ awt,
                         const int* __restrict__ acnt, const float* __restrict__ xw,
                         const float* __restrict__ dinv, const float* __restrict__ selfw,
                         const float* __restrict__ bias, float* __restrict__ out,
                         int f, int relu) {
    int i = blockIdx.x;
    int o = threadIdx.x;
    __shared__ int sj[MAXN];
    __shared__ float sw_[MAXN];
    int cnt = acnt[i];
    for (int a = o; a < cnt; a += blockDim.x) {
        sj[a] = nbr[i * MAXN + a];
        sw_[a] = awt[i * MAXN + a];
    }
    __syncthreads();
    if (o >= f) return;
    float sum = 0.f;
    for (int a = 0; a < cnt; ++a) {
        int j = sj[a];
        sum += sw_[a] * (xw[(size_t)j * f + o] * dinv[j]);
    }
    float yi = xw[(size_t)i * f + o] * dinv[i];
    sum -= yi;
    float v = dinv[i] * (sum + selfw[i] * yi) + bias[o];
    if (relu) v = fmaxf(v, 0.f);
    out[(size_t)i * f + o] = v;
}

// ---------------- pooling: score + 2D rank-count top-k ----------------
__global__ void score_kernel2(const float* __restrict__ x, const float* __restrict__ p,
                              float* __restrict__ s, int n) {
    int i = blockIdx.x * TPB + threadIdx.x;
    if (i >= n) return;
    float a = 0.f, nrm = 0.f;
    for (int c = 0; c < 64; ++c) {
        float pc = p[c];
        nrm += pc * pc;
        a += x[(size_t)i * 64 + c] * pc;
    }
    s[i] = tanhf(a / sqrtf(nrm));
}

__global__ void rank_count(const float* __restrict__ s, int n, int* __restrict__ rank) {
    __shared__ float sj[256];
    int i = blockIdx.x * 256 + threadIdx.x;
    int j0 = blockIdx.y * 256;
    sj[threadIdx.x] = s[j0 + threadIdx.x];
    float si = s[i];
    __syncthreads();
    int r = 0;
#pragma unroll 8
    for (int jj = 0; jj < 256; ++jj) {
        float v = sj[jj];
        r += (v > si) || (v == si && (j0 + jj) < i);
    }
    atomicAdd(&rank[i], r);
}

__global__ void scatter_topk_all(const float* __restrict__ s, const int* __restrict__ rank,
                                 int n, int k, int* __restrict__ perm,
                                 float* __restrict__ vals, int* __restrict__ invp) {
    int i = blockIdx.x * TPB + threadIdx.x;
    if (i >= n) return;
    int r = rank[i];
    if (r < k) { perm[r] = i; vals[r] = s[i]; invp[i] = r; }
    else invp[i] = -1;
}

// ---------------- level-1 augment: sparse SpGEMM ----------------
__global__ void spgemm_aug(const int* __restrict__ nbr, const float* __restrict__ awt,
                           const int* __restrict__ acnt, const int* __restrict__ perm,
                           const int* __restrict__ invp, int k,
                           ushort* __restrict__ Chi, ushort* __restrict__ Clo,
                           float* __restrict__ dinv, float* __restrict__ selfw) {
    __shared__ float row[2048];
    int r = blockIdx.x, tid = threadIdx.x;
    int pi = perm[r];
    for (int j = tid; j < k; j += TPB) row[j] = 0.f;
    __syncthreads();
    int cnt = acnt[pi];
    for (int a = 0; a < cnt; ++a) {
        int t = nbr[pi * MAXN + a];
        float w1 = awt[pi * MAXN + a];
        int c2 = acnt[t];
        for (int b = tid; b < c2; b += TPB) {
            int s = nbr[t * MAXN + b];
            int j = invp[s];
            if (j >= 0) atomicAdd(&row[j], w1 * awt[t * MAXN + b]);
        }
    }
    __syncthreads();
    float psum = 0.f;
    for (int j = tid; j < k; j += TPB) {
        float v = (j == r) ? 0.f : row[j];
        psum += v;
        ushort hi = f32_to_bf16(v);
        size_t o = (size_t)r * k + j;
        Chi[o] = hi;
        Clo[o] = f32_to_bf16(v - bf2f(hi));
    }
    for (int o = 32; o; o >>= 1) psum += __shfl_xor(psum, o);
    __shared__ float sh[4];
    if ((tid & 63) == 0) sh[tid >> 6] = psum;
    __syncthreads();
    if (tid == 0) {
        float tot = sh[0] + sh[1] + sh[2] + sh[3];
        dinv[r] = 1.0f / sqrtf(tot + 2.0f);
        selfw[r] = 2.0f;
    }
}

// ---------------- dense augment (levels 2,3) ----------------
__global__ void transpose_aug_hl(const ushort* __restrict__ Ahi, const ushort* __restrict__ Alo,
                                 ushort* __restrict__ T, int n) {
    __shared__ float tile[64][65];
    int c0 = blockIdx.x * 64, r0 = blockIdx.y * 64;
    for (int t = threadIdx.x; t < 4096; t += TPB) {
        int r = t >> 6, c = t & 63;
        size_t o = (size_t)(r0 + r) * n + (c0 + c);
        float v = bf2f(Ahi[o]) + bf2f(Alo[o]);
        if (r0 + r == c0 + c) v += 1.0f;
        tile[c][r] = v;
    }
    __syncthreads();
    for (int t = threadIdx.x; t < 4096; t += TPB) {
        int c = t >> 6, r = t & 63;
        T[(size_t)(c0 + c) * n + (r0 + r)] = f32_to_bf16(tile[c][r]);
    }
}

__global__ void gather_rows_aug_hl(const ushort* __restrict__ Ahi, const ushort* __restrict__ Alo,
                                   const int* __restrict__ perm, ushort* __restrict__ Ag,
                                   int n, int rows) {
    int id = blockIdx.x * TPB + threadIdx.x;
    if (id >= rows * n) return;
    int r = id / n, t = id - r * n;
    int pr = perm[r];
    size_t o = (size_t)pr * n + t;
    float v = bf2f(Ahi[o]) + bf2f(Alo[o]);
    if (pr == t) v += 1.0f;
    Ag[id] = f32_to_bf16(v);
}

__global__ void gather_rows_u16(const ushort* __restrict__ T, const int* __restrict__ perm,
                                ushort* __restrict__ Bg, int n, int rows) {
    int id = blockIdx.x * TPB + threadIdx.x;
    if (id >= rows * n) return;
    int r = id / n, t = id - r * n;
    Bg[id] = T[(size_t)perm[r] * n + t];
}

__global__ void __launch_bounds__(256)
aug_gemm_acc(const ushort* __restrict__ Ag, const ushort* __restrict__ Bg,
             float* __restrict__ Caug, int K, int ldc, int kpb) {
    __shared__ __align__(16) ushort As[64 * LDK];
    __shared__ __align__(16) ushort Bs[64 * LDK];
    int tid = threadIdx.x;
    int wave = tid >> 6, lane = tid & 63;
    int wr = wave >> 1, wc = wave & 1;
    int m = lane & 15, quad = lane >> 4;
    int i0 = blockIdx.y * 64, j0 = blockIdx.x * 64;
    int kbeg = blockIdx.z * kpb;
    f32x4 acc[2][2];
#pragma unroll
    for (int a = 0; a < 2; ++a)
#pragma unroll
        for (int b = 0; b < 2; ++b) acc[a][b] = (f32x4){0.f, 0.f, 0.f, 0.f};
    const ushort* Ab = Ag + (size_t)i0 * K;
    const ushort* Bb = Bg + (size_t)j0 * K;
    for (int k0 = kbeg; k0 < kbeg + kpb; k0 += 64) {
#pragma unroll
        for (int v = 0; v < 2; ++v) {
            int idx = tid + (v << 8);
            int r = idx >> 3, c8 = idx & 7;
            *(uint4*)&As[r * LDK + c8 * 8] = *(const uint4*)&Ab[(size_t)r * K + k0 + c8 * 8];
            *(uint4*)&Bs[r * LDK + c8 * 8] = *(const uint4*)&Bb[(size_t)r * K + k0 + c8 * 8];
        }
        __syncthreads();
#pragma unroll
        for (int kk = 0; kk < 2; ++kk) {
            bf16x8 af[2], bfr[2];
#pragma unroll
            for (int mi = 0; mi < 2; ++mi)
                af[mi] = *(const bf16x8*)&As[(wr * 32 + mi * 16 + m) * LDK + kk * 32 + quad * 8];
#pragma unroll
            for (int ni = 0; ni < 2; ++ni)
                bfr[ni] = *(const bf16x8*)&Bs[(wc * 32 + ni * 16 + m) * LDK + kk * 32 + quad * 8];
#pragma unroll
            for (int mi = 0; mi < 2; ++mi)
#pragma unroll
                for (int ni = 0; ni < 2; ++ni)
                    acc[mi][ni] = __builtin_amdgcn_mfma_f32_16x16x32_bf16(
                        af[mi], bfr[ni], acc[mi][ni], 0, 0, 0);
        }
        __syncthreads();
    }
#pragma unroll
    for (int mi = 0; mi < 2; ++mi)
#pragma unroll
        for (int ni = 0; ni < 2; ++ni)
#pragma unroll
            for (int r = 0; r < 4; ++r) {
                int gi = i0 + wr * 32 + mi * 16 + quad * 4 + r;
                int gj = j0 + wc * 32 + ni * 16 + m;
                atomicAdd(&Caug[(size_t)gi * ldc + gj], acc[mi][ni][r]);
            }
}

__global__ void aug_finalize(const float* __restrict__ Caug, int k,
                             ushort* __restrict__ Chi, ushort* __restrict__ Clo,
                             float* __restrict__ dinv, float* __restrict__ selfw) {
    int r = blockIdx.x, tid = threadIdx.x;
    const float* row = Caug + (size_t)r * k;
    float psum = 0.f;
    for (int j = tid; j < k; j += TPB) {
        float v = (j == r) ? 0.f : row[j];
        psum += v;
        ushort hi = f32_to_bf16(v);
        size_t o = (size_t)r * k + j;
        Chi[o] = hi;
        Clo[o] = f32_to_bf16(v - bf2f(hi));
    }
    for (int o = 32; o; o >>= 1) psum += __shfl_xor(psum, o);
    __shared__ float sh[4];
    if ((tid & 63) == 0) sh[tid >> 6] = psum;
    __syncthreads();
    if (tid == 0) {
        float tot = sh[0] + sh[1] + sh[2] + sh[3];
        dinv[r] = 1.0f / sqrtf(tot + 2.0f);
        selfw[r] = 2.0f;
    }
}

// ---------------- dense GCN aggregation (levels >=1) ----------------
__global__ void __launch_bounds__(256)
gcn_gemm(const ushort* __restrict__ Ahi, const ushort* __restrict__ Alo,
         const ushort* __restrict__ Bhi, const ushort* __restrict__ Blo,
         float* __restrict__ C, int K, int ldc, int kpb) {
    __shared__ __align__(16) ushort sAh[64 * LDK];
    __shared__ __align__(16) ushort sAl[64 * LDK];
    __shared__ __align__(16) ushort sBh[64 * LDK];
    __shared__ __align__(16) ushort sBl[64 * LDK];
    int tid = threadIdx.x;
    int wave = tid >> 6, lane = tid & 63;
    int wr = wave >> 1, wc = wave & 1;
    int m = lane & 15, quad = lane >> 4;
    int i0 = blockIdx.y * 64, j0 = blockIdx.x * 64;
    int kbeg = blockIdx.z * kpb;
    f32x4 acc[2][2];
#pragma unroll
    for (int a = 0; a < 2; ++a)
#pragma unroll
        for (int b = 0; b < 2; ++b) acc[a][b] = (f32x4){0.f, 0.f, 0.f, 0.f};
    for (int k0 = kbeg; k0 < kbeg + kpb; k0 += 64) {
#pragma unroll
        for (int v = 0; v < 2; ++v) {
            int idx = tid + (v << 8);
            int r = idx >> 3, c8 = idx & 7;
            size_t boff = (size_t)(j0 + r) * K + k0 + c8 * 8;
            *(uint4*)&sBh[r * LDK + c8 * 8] = *(const uint4*)&Bhi[boff];
            *(uint4*)&sBl[r * LDK + c8 * 8] = *(const uint4*)&Blo[boff];
            size_t aoff = (size_t)(i0 + r) * K + k0 + c8 * 8;
            *(uint4*)&sAh[r * LDK + c8 * 8] = *(const uint4*)&Ahi[aoff];
            *(uint4*)&sAl[r * LDK + c8 * 8] = *(const uint4*)&Alo[aoff];
        }
        __syncthreads();
#pragma unroll
        for (int kk = 0; kk < 2; ++kk) {
            bf16x8 ah[2], al[2], bh[2], bl[2];
#pragma unroll
            for (int mi = 0; mi < 2; ++mi) {
                ah[mi] = *(const bf16x8*)&sAh[(wr * 32 + mi * 16 + m) * LDK + kk * 32 + quad * 8];
                al[mi] = *(const bf16x8*)&sAl[(wr * 32 + mi * 16 + m) * LDK + kk * 32 + quad * 8];
            }
#pragma unroll
            for (int ni = 0; ni < 2; ++ni) {
                bh[ni] = *(const bf16x8*)&sBh[(wc * 32 + ni * 16 + m) * LDK + kk * 32 + quad * 8];
                bl[ni] = *(const bf16x8*)&sBl[(wc * 32 + ni * 16 + m) * LDK + kk * 32 + quad * 8];
            }
#pragma unroll
            for (int mi = 0; mi < 2; ++mi)
#pragma unroll
                for (int ni = 0; ni < 2; ++ni) {
                    acc[mi][ni] = __builtin_amdgcn_mfma_f32_16x16x32_bf16(ah[mi], bh[ni], acc[mi][ni], 0, 0, 0);
                    acc[mi][ni] = __builtin_amdgcn_mfma_f32_16x16x32_bf16(ah[mi], bl[ni], acc[mi][ni], 0, 0, 0);
                    acc[mi][ni] = __builtin_amdgcn_mfma_f32_16x16x32_bf16(al[mi], bh[ni], acc[mi][ni], 0, 0, 0);
                }
        }
        __syncthreads();
    }
#pragma unroll
    for (int mi = 0; mi < 2; ++mi)
#pragma unroll
        for (int ni = 0; ni < 2; ++ni)
#pragma unroll
            for (int r = 0; r < 4; ++r) {
                int gi = i0 + wr * 32 + mi * 16 + quad * 4 + r;
                int gj = j0 + wc * 32 + ni * 16 + m;
                atomicAdd(&C[(size_t)gi * ldc + gj], acc[mi][ni][r]);
            }
}

__global__ void gcn_epilogue(const float* __restrict__ C, const float* __restrict__ xw,
                             const float* __restrict__ dinv, const float* __restrict__ selfw,
                             const float* __restrict__ b, float* __restrict__ out,
                             int n, int f, int relu) {
    int id = blockIdx.x * TPB + threadIdx.x;
    if (id >= n * f) return;
    int i = id / f, c = id - i * f;
    float y = xw[id] * dinv[i];
    float v = dinv[i] * (C[id] + selfw[i] * y) + b[c];
    if (relu) v = fmaxf(v, 0.f);
    out[id] = v;
}

// ---------------- layernorm ----------------
__global__ void layernorm(const float* __restrict__ h, const float* __restrict__ g,
                          const float* __restrict__ b, float* __restrict__ u, int n) {
    int i = blockIdx.x;
    int t = threadIdx.x;
    float v = h[(size_t)i * 128 + t];
    __shared__ float s0[2], s1[2];
    float sum = v;
    for (int o = 32; o; o >>= 1) sum += __shfl_xor(sum, o);
    if ((t & 63) == 0) s0[t >> 6] = sum;
    __syncthreads();
    float mu = (s0[0] + s0[1]) * (1.0f / 128.0f);
    float d = v - mu;
    float sq = d * d;
    for (int o = 32; o; o >>= 1) sq += __shfl_xor(sq, o);
    if ((t & 63) == 0) s1[t >> 6] = sq;
    __syncthreads();
    float var = (s1[0] + s1[1]) * (1.0f / 128.0f);
    u[(size_t)i * 128 + t] = d / sqrtf(var + 1e-6f) * g[t] + b[t];
}

// ---------------- weight prep: all three transpose/splits in one ----------
__global__ void prep_weights(const float* __restrict__ rw, const float* __restrict__ g1w,
                             const float* __restrict__ g2w,
                             ushort* __restrict__ W1hi, ushort* __restrict__ W1lo,
                             ushort* __restrict__ W2hi, ushort* __restrict__ W2lo,
                             ushort* __restrict__ W3hi, ushort* __restrict__ W3lo) {
    __shared__ float tile[64][65];
    int b = blockIdx.x;
    const float* W; ushort *Bhi, *Blo; int K, Nn, bx, by;
    if (b < 4)       { W = rw;  Bhi = W1hi; Blo = W1lo; K = 128; Nn = 128; bx = b & 1;        by = b >> 1; }
    else if (b < 20) { int t = b - 4;  W = g1w; Bhi = W2hi; Blo = W2lo; K = 128; Nn = 512; bx = t & 7; by = t >> 3; }
    else             { int t = b - 20; W = g2w; Bhi = W3hi; Blo = W3lo; K = 512; Nn = 128; bx = t & 1; by = t >> 1; }
    int n0 = bx * 64, k0 = by * 64;
    for (int t = threadIdx.x; t < 4096; t += TPB) {
        int r = t >> 6, c = t & 63;
        tile[r][c] = W[(size_t)(k0 + r) * Nn + (n0 + c)];
    }
    __syncthreads();
    for (int t = threadIdx.x; t < 4096; t += TPB) {
        int c = t >> 6, r = t & 63;
        float v = tile[r][c];
        ushort hi = f32_to_bf16(v);
        size_t o = (size_t)(n0 + c) * K + (k0 + r);
        Bhi[o] = hi;
        Blo[o] = f32_to_bf16(v - bf2f(hi));
    }
}

// ---------------- dense projections via split-bf16 MFMA --------------------
__global__ void __launch_bounds__(256)
gemm_bt_store(const float* __restrict__ A, const ushort* __restrict__ Bhi,
              const ushort* __restrict__ Blo, const float* __restrict__ bias,
              float* __restrict__ C, int K, int N) {
    __shared__ __align__(16) ushort sAh[64 * LDK];
    __shared__ __align__(16) ushort sAl[64 * LDK];
    __shared__ __align__(16) ushort sBh[64 * LDK];
    __shared__ __align__(16) ushort sBl[64 * LDK];
    int tid = threadIdx.x;
    int wave = tid >> 6, lane = tid & 63;
    int wr = wave >> 1, wc = wave & 1;
    int m = lane & 15, quad = lane >> 4;
    int i0 = blockIdx.y * 64, j0 = blockIdx.x * 64;
    f32x4 acc[2][2];
#pragma unroll
    for (int a = 0; a < 2; ++a)
#pragma unroll
        for (int b = 0; b < 2; ++b) acc[a][b] = (f32x4){0.f, 0.f, 0.f, 0.f};
    for (int k0 = 0; k0 < K; k0 += 64) {
#pragma unroll
        for (int v = 0; v < 2; ++v) {
            int idx = tid + (v << 8);
            int r = idx >> 3, c8 = idx & 7;
            size_t boff = (size_t)(j0 + r) * K + k0 + c8 * 8;
            *(uint4*)&sBh[r * LDK + c8 * 8] = *(const uint4*)&Bhi[boff];
            *(uint4*)&sBl[r * LDK + c8 * 8] = *(const uint4*)&Blo[boff];
            size_t aoff = (size_t)(i0 + r) * K + k0 + c8 * 8;
            float4 fa = *(const float4*)&A[aoff];
            float4 fb = *(const float4*)&A[aoff + 4];
            ushort h0 = f32_to_bf16(fa.x), h1 = f32_to_bf16(fa.y);
            ushort h2 = f32_to_bf16(fa.z), h3 = f32_to_bf16(fa.w);
            ushort h4 = f32_to_bf16(fb.x), h5 = f32_to_bf16(fb.y);
            ushort h6 = f32_to_bf16(fb.z), h7 = f32_to_bf16(fb.w);
            uint4 ph, pl;
            ph.x = (uint)h0 | ((uint)h1 << 16);
            ph.y = (uint)h2 | ((uint)h3 << 16);
            ph.z = (uint)h4 | ((uint)h5 << 16);
            ph.w = (uint)h6 | ((uint)h7 << 16);
            pl.x = (uint)f32_to_bf16(fa.x - bf2f(h0)) | ((uint)f32_to_bf16(fa.y - bf2f(h1)) << 16);
            pl.y = (uint)f32_to_bf16(fa.z - bf2f(h2)) | ((uint)f32_to_bf16(fa.w - bf2f(h3)) << 16);
            pl.z = (uint)f32_to_bf16(fb.x - bf2f(h4)) | ((uint)f32_to_bf16(fb.y - bf2f(h5)) << 16);
            pl.w = (uint)f32_to_bf16(fb.z - bf2f(h6)) | ((uint)f32_to_bf16(fb.w - bf2f(h7)) << 16);
            *(uint4*)&sAh[r * LDK + c8 * 8] = ph;
            *(uint4*)&sAl[r * LDK + c8 * 8] = pl;
        }
        __syncthreads();
#pragma unroll
        for (int kk = 0; kk < 2; ++kk) {
            bf16x8 ah[2], al[2], bh[2], bl[2];
#pragma unroll
            for (int mi = 0; mi < 2; ++mi) {
                ah[mi] = *(const bf16x8*)&sAh[(wr * 32 + mi * 16 + m) * LDK + kk * 32 + quad * 8];
                al[mi] = *(const bf16x8*)&sAl[(wr * 32 + mi * 16 + m) * LDK + kk * 32 + quad * 8];
            }
#pragma unroll
            for (int ni = 0; ni < 2; ++ni) {
                bh[ni] = *(const bf16x8*)&sBh[(wc * 32 + ni * 16 + m) * LDK + kk * 32 + quad * 8];
                bl[ni] = *(const bf16x8*)&sBl[(wc * 32 + ni * 16 + m) * LDK + kk * 32 + quad * 8];
            }
#pragma unroll
            for (int mi = 0; mi < 2; ++mi)
#pragma unroll
                for (int ni = 0; ni < 2; ++ni) {
                    acc[mi][ni] = __builtin_amdgcn_mfma_f32_16x16x32_bf16(ah[mi], bh[ni], acc[mi][ni], 0, 0, 0);
                    acc[mi][ni] = __builtin_amdgcn_mfma_f32_16x16x32_bf16(ah[mi], bl[ni], acc[mi][ni], 0, 0, 0);
                    acc[mi][ni] = __builtin_amdgcn_mfma_f32_16x16x32_bf16(al[mi], bh[ni], acc[mi][ni], 0, 0, 0);
                }
        }
        __syncthreads();
    }
#pragma unroll
    for (int mi = 0; mi < 2; ++mi)
#pragma unroll
        for (int ni = 0; ni < 2; ++ni)
#pragma unroll
            for (int r = 0; r < 4; ++r) {
                int gi = i0 + wr * 32 + mi * 16 + quad * 4 + r;
                int gj = j0 + wc * 32 + ni * 16 + m;
                float v = acc[mi][ni][r];
                if (bias) v += bias[gj];
                C[(size_t)gi * N + gj] = v;
            }
}

__global__ void __launch_bounds__(256)
gemm_bt_split(const float* __restrict__ A, const ushort* __restrict__ Bhi,
              const ushort* __restrict__ Blo, float* __restrict__ C,
              int K, int N, int kpb) {
    __shared__ __align__(16) ushort sAh[64 * LDK];
    __shared__ __align__(16) ushort sAl[64 * LDK];
    __shared__ __align__(16) ushort sBh[64 * LDK];
    __shared__ __align__(16) ushort sBl[64 * LDK];
    int tid = threadIdx.x;
    int wave = tid >> 6, lane = tid & 63;
    int wr = wave >> 1, wc = wave & 1;
    int m = lane & 15, quad = lane >> 4;
    int i0 = blockIdx.y * 64, j0 = blockIdx.x * 64;
    int kbeg = blockIdx.z * kpb;
    f32x4 acc[2][2];
#pragma unroll
    for (int a = 0; a < 2; ++a)
#pragma unroll
        for (int b = 0; b < 2; ++b) acc[a][b] = (f32x4){0.f, 0.f, 0.f, 0.f};
    for (int k0 = kbeg; k0 < kbeg + kpb; k0 += 64) {
#pragma unroll
        for (int v = 0; v < 2; ++v) {
            int idx = tid + (v << 8);
            int r = idx >> 3, c8 = idx & 7;
            size_t boff = (size_t)(j0 + r) * K + k0 + c8 * 8;
            *(uint4*)&sBh[r * LDK + c8 * 8] = *(const uint4*)&Bhi[boff];
            *(uint4*)&sBl[r * LDK + c8 * 8] = *(const uint4*)&Blo[boff];
            size_t aoff = (size_t)(i0 + r) * K + k0 + c8 * 8;
            float4 fa = *(const float4*)&A[aoff];
            float4 fb = *(const float4*)&A[aoff + 4];
            ushort h0 = f32_to_bf16(fa.x), h1 = f32_to_bf16(fa.y);
            ushort h2 = f32_to_bf16(fa.z), h3 = f32_to_bf16(fa.w);
            ushort h4 = f32_to_bf16(fb.x), h5 = f32_to_bf16(fb.y);
            ushort h6 = f32_to_bf16(fb.z), h7 = f32_to_bf16(fb.w);
            uint4 ph, pl;
            ph.x = (uint)h0 | ((uint)h1 << 16);
            ph.y = (uint)h2 | ((uint)h3 << 16);
            ph.z = (uint)h4 | ((uint)h5 << 16);
            ph.w = (uint)h6 | ((uint)h7 << 16);
            pl.x = (uint)f32_to_bf16(fa.x - bf2f(h0)) | ((uint)f32_to_bf16(fa.y - bf2f(h1)) << 16);
            pl.y = (uint)f32_to_bf16(fa.z - bf2f(h2)) | ((uint)f32_to_bf16(fa.w - bf2f(h3)) << 16);
            pl.z = (uint)f32_to_bf16(fb.x - bf2f(h4)) | ((uint)f32_to_bf16(fb.y - bf2f(h5)) << 16);
            pl.w = (uint)f32_to_bf16(fb.z - bf2f(h6)) | ((uint)f32_to_bf16(fb.w - bf2f(h7)) << 16);
            *(uint4*)&sAh[r * LDK + c8 * 8] = ph;
            *(uint4*)&sAl[r * LDK + c8 * 8] = pl;
        }
        __syncthreads();
#pragma unroll
        for (int kk = 0; kk < 2; ++kk) {
            bf16x8 ah[2], al[2], bh[2], bl[2];
#pragma unroll
            for (int mi = 0; mi < 2; ++mi) {
                ah[mi] = *(const bf16x8*)&sAh[(wr * 32 + mi * 16 + m) * LDK + kk * 32 + quad * 8];
                al[mi] = *(const bf16x8*)&sAl[(wr * 32 + mi * 16 + m) * LDK + kk * 32 + quad * 8];
            }
#pragma unroll
            for (int ni = 0; ni < 2; ++ni) {
                bh[ni] = *(const bf16x8*)&sBh[(wc * 32 + ni * 16 + m) * LDK + kk * 32 + quad * 8];
                bl[ni] = *(const bf16x8*)&sBl[(wc * 32 + ni * 16 + m) * LDK + kk * 32 + quad * 8];
            }
#pragma unroll
            for (int mi = 0; mi < 2; ++mi)
#pragma unroll
                for (int ni = 0; ni < 2; ++ni) {
                    acc[mi][ni] = __builtin_amdgcn_mfma_f32_16x16x32_bf16(ah[mi], bh[ni], acc[mi][ni], 0, 0, 0);
                    acc[mi][ni] = __builtin_amdgcn_mfma_f32_16x16x32_bf16(ah[mi], bl[ni], acc[mi][ni], 0, 0, 0);
                    acc[mi][ni] = __builtin_amdgcn_mfma_f32_16x16x32_bf16(al[mi], bh[ni], acc[mi][ni], 0, 0, 0);
                }
        }
        __syncthreads();
    }
#pragma unroll
    for (int mi = 0; mi < 2; ++mi)
#pragma unroll
        for (int ni = 0; ni < 2; ++ni)
#pragma unroll
            for (int r = 0; r < 4; ++r) {
                int gi = i0 + wr * 32 + mi * 16 + quad * 4 + r;
                int gj = j0 + wc * 32 + ni * 16 + m;
                atomicAdd(&C[(size_t)gi * N + gj], acc[mi][ni][r]);
            }
}

// ---------------- GAT ----------------
__global__ void attn_coef2(const float* __restrict__ hf, const float* __restrict__ asrc,
                           const float* __restrict__ adst, float* __restrict__ es,
                           float* __restrict__ ed, int heads) {
    int j = blockIdx.x;
    int wave = threadIdx.x >> 6, lane = threadIdx.x & 63;
    if (wave >= heads) return;
    const float* hp = hf + (size_t)j * heads * 128 + wave * 128;
    float v0 = hp[lane], v1 = hp[lane + 64];
    float a = v0 * asrc[wave * 128 + lane] + v1 * asrc[wave * 128 + lane + 64];
    float d = v0 * adst[wave * 128 + lane] + v1 * adst[wave * 128 + lane + 64];
    for (int o = 32; o; o >>= 1) { a += __shfl_xor(a, o); d += __shfl_xor(d, o); }
    if (lane == 0) { es[j * heads + wave] = a; ed[j * heads + wave] = d; }
}

__global__ void gat_sparse(const int* __restrict__ nbr, const int* __restrict__ ncnt, int n,
                           const float* __restrict__ hf, const float* __restrict__ es,
                           const float* __restrict__ ed, const float* __restrict__ bias,
                           const float* __restrict__ resid, float* __restrict__ out,
                           int heads, int mode) {
    int i = blockIdx.x;
    int tid = threadIdx.x;
    __shared__ int idx[MAXN];
    __shared__ float lg[MAXN * 4];
    __shared__ float hmax[4], hsum[4];
    int m = ncnt[i];
    for (int t = tid; t < m; t += TPB) idx[t] = nbr[i * MAXN + t];
    __syncthreads();
    for (int t = tid; t < m * heads; t += TPB) {
        int jl = t / heads, h = t - jl * heads;
        float l = ed[i * heads + h] + es[idx[jl] * heads + h];
        lg[jl * heads + h] = (l > 0.f) ? l : 0.2f * l;
    }
    __syncthreads();
    int h = tid >> 6, lane = tid & 63;
    if (h < heads) {
        float mx = -3.4e38f;
        for (int jl = lane; jl < m; jl += 64) mx = fmaxf(mx, lg[jl * heads + h]);
        for (int o = 32; o; o >>= 1) mx = fmaxf(mx, __shfl_xor(mx, o));
        if (lane == 0) hmax[h] = mx;
    }
    __syncthreads();
    if (h < heads) {
        float mx = hmax[h];
        float sm = 0.f;
        for (int jl = lane; jl < m; jl += 64) {
            float p = expf(lg[jl * heads + h] - mx);
            lg[jl * heads + h] = p;
            sm += p;
        }
        for (int o = 32; o; o >>= 1) sm += __shfl_xor(sm, o);
        if (lane == 0) hsum[h] = sm;
    }
    __syncthreads();
    int width = heads * 128;
    for (int o = tid; o < width; o += TPB) {
        int hh = o >> 7;
        float acc = 0.f;
        for (int jl = 0; jl < m; ++jl)
            acc += lg[jl * heads + hh] * hf[(size_t)idx[jl] * width + o];
        float v = acc / hsum[hh] + bias[o];
        if (mode == 0) v = (v > 0.f) ? v : expm1f(v);
        else v += resid[(size_t)i * width + o];
        out[(size_t)i * width + o] = v;
    }
}

// ---------------------------------------------------------------------------
static inline int cdiv(int a, int b) { return (a + b - 1) / b; }

static int pick_z(int gx, int gy, int K) {
    int z = 1;
    while (gx * gy * z < 384 && K / (2 * z) >= 64) z <<= 1;
    return z;
}

// dense GCN (all 64->64): fused input+projection+yT, split-K MFMA agg, epilogue
static void run_gcn_dense(hipStream_t stream, const ushort* Ahi, const ushort* Alo,
                          int n, const float* xsrc, const int* perm, const float* vals,
                          const float* hprev, const int* invp, int mode,
                          const float* W, const float* bias,
                          const float* dinv, const float* selfw,
                          float* xw, ushort* yThi, ushort* yTlo, float* Cp,
                          float* out, int relu) {
    fused_in_gemm<<<n / 4, TPB, 0, stream>>>(xsrc, perm, vals, hprev, invp, W, dinv,
                                             xw, yThi, yTlo, Cp, n, mode);
    int z = pick_z(1, n / 64, n);
    gcn_gemm<<<dim3(1, n / 64, z), TPB, 0, stream>>>(Ahi, Alo, yThi, yTlo, Cp, n, 64, n / z);
    gcn_epilogue<<<cdiv(n * 64, TPB), TPB, 0, stream>>>(Cp, xw, dinv, selfw, bias, out, n, 64, relu);
}

static void run_topk(hipStream_t stream, const float* score, int n, int k, int* rank,
                     int* perm, float* vals, int* invp) {
    hipMemsetAsync(rank, 0, n * sizeof(int), stream);
    rank_count<<<dim3(n / 256, n / 256), 256, 0, stream>>>(score, n, rank);
    scatter_topk_all<<<cdiv(n, TPB), TPB, 0, stream>>>(score, rank, n, k, perm, vals, invp);
}

static void run_aug_dense(hipStream_t stream, const ushort* Ahi, const ushort* Alo, int n,
                          const int* perm, int k, ushort* Tbf, ushort* Agb, ushort* Bgb,
                          float* Caug, ushort* Chi, ushort* Clo, float* dinv, float* selfw) {
    transpose_aug_hl<<<dim3(n / 64, n / 64), TPB, 0, stream>>>(Ahi, Alo, Tbf, n);
    gather_rows_aug_hl<<<cdiv(k * n, TPB), TPB, 0, stream>>>(Ahi, Alo, perm, Agb, n, k);
    gather_rows_u16<<<cdiv(k * n, TPB), TPB, 0, stream>>>(Tbf, perm, Bgb, n, k);
    hipMemsetAsync(Caug, 0, (size_t)k * k * sizeof(float), stream);
    int z = 8;
    aug_gemm_acc<<<dim3(k / 64, k / 64, z), TPB, 0, stream>>>(Agb, Bgb, Caug, n, k, n / z);
    aug_finalize<<<k, TPB, 0, stream>>>(Caug, k, Chi, Clo, dinv, selfw);
}

extern "C" void kernel_launch(void* const* d_in, const int* in_sizes, int n_in,
                              void* d_out, int out_size, void* d_ws, size_t ws_size,
                              hipStream_t stream) {
    const float* x   = (const float*)d_in[0];
    const int*   ei  = (const int*)d_in[1];
    const float* w0  = (const float*)d_in[2];  const float* b0  = (const float*)d_in[3];
    const float* w1  = (const float*)d_in[4];  const float* b1  = (const float*)d_in[5];
    const float* w2  = (const float*)d_in[6];  const float* b2  = (const float*)d_in[7];
    const float* w3  = (const float*)d_in[8];  const float* b3  = (const float*)d_in[9];
    const float* p1  = (const float*)d_in[10];
    const float* p2  = (const float*)d_in[11];
    const float* p3  = (const float*)d_in[12];
    const float* uw0 = (const float*)d_in[13]; const float* ub0 = (const float*)d_in[14];
    const float* uw1 = (const float*)d_in[15]; const float* ub1 = (const float*)d_in[16];
    const float* uw2 = (const float*)d_in[17]; const float* ub2 = (const float*)d_in[18];
    const float* lng = (const float*)d_in[19]; const float* lnb = (const float*)d_in[20];
    const float* rw  = (const float*)d_in[21]; const float* rb  = (const float*)d_in[22];
    const float* g1w = (const float*)d_in[23];
    const float* g1as = (const float*)d_in[24]; const float* g1ad = (const float*)d_in[25];
    const float* g1b = (const float*)d_in[26];
    const float* g2w = (const float*)d_in[27];
    const float* g2as = (const float*)d_in[28]; const float* g2ad = (const float*)d_in[29];
    const float* g2b = (const float*)d_in[30];

    const int N = 4096, E = 65536;
    const int K1 = 2048, K2 = 1024, K3 = 512;

    float* base = (float*)d_ws;
    size_t off = 0;
    auto alloc = [&](size_t nf) { float* p = base + off; off += (nf + 63) & ~(size_t)63; return p; };

    ushort* A1hi = (ushort*)alloc((size_t)K1 * K1 / 2);
    ushort* A1lo = (ushort*)alloc((size_t)K1 * K1 / 2);
    ushort* A2hi = (ushort*)alloc((size_t)K2 * K2 / 2);
    ushort* A2lo = (ushort*)alloc((size_t)K2 * K2 / 2);
    ushort* A3hi = (ushort*)alloc((size_t)K3 * K3 / 2);
    ushort* A3lo = (ushort*)alloc((size_t)K3 * K3 / 2);
    ushort* Tbf  = (ushort*)alloc((size_t)K1 * K1 / 2);
    ushort* Agb  = (ushort*)alloc((size_t)K2 * K1 / 2);
    ushort* Bgb  = (ushort*)alloc((size_t)K2 * K1 / 2);
    ushort* yThi = (ushort*)alloc((size_t)64 * N / 2);
    ushort* yTlo = (ushort*)alloc((size_t)64 * N / 2);
    ushort* W1hi = (ushort*)alloc((size_t)128 * 128 / 2);
    ushort* W1lo = (ushort*)alloc((size_t)128 * 128 / 2);
    ushort* W2hi = (ushort*)alloc((size_t)512 * 128 / 2);
    ushort* W2lo = (ushort*)alloc((size_t)512 * 128 / 2);
    ushort* W3hi = (ushort*)alloc((size_t)128 * 512 / 2);
    ushort* W3lo = (ushort*)alloc((size_t)128 * 512 / 2);
    float* Caug  = alloc((size_t)K2 * K2);
    float* Cp    = alloc((size_t)N * 64);
    float* x0    = alloc((size_t)N * 64);
    float* x1    = alloc((size_t)K1 * 64);
    float* x2    = alloc((size_t)K2 * 64);
    float* x3    = alloc((size_t)K3 * 64);
    float* h2    = alloc((size_t)K2 * 64);
    float* h1    = alloc((size_t)K1 * 64);
    float* xw    = alloc((size_t)N * 128);
    float* dinv0 = alloc(N);  float* selfw0 = alloc(N);
    float* dinv1 = alloc(K1); float* selfw1 = alloc(K1);
    float* dinv2 = alloc(K2); float* selfw2 = alloc(K2);
    float* dinv3 = alloc(K3); float* selfw3 = alloc(K3);
    int*   cursor= (int*)alloc(N);
    int*   buck  = (int*)alloc((size_t)N * MAXN);
    float* score = alloc(N);
    int*   rank  = (int*)alloc(N);
    float* vals1 = alloc(K1); float* vals2 = alloc(K2); float* vals3 = alloc(K3);
    int*   perm1 = (int*)alloc(K1); int* perm2 = (int*)alloc(K2); int* perm3 = (int*)alloc(K3);
    int*   invp1 = (int*)alloc(N);  int* invp2 = (int*)alloc(K1); int* invp3 = (int*)alloc(K2);
    int*   nbr   = (int*)alloc((size_t)N * MAXN);
    float* awt   = alloc((size_t)N * MAXN);
    int*   acnt  = (int*)alloc(N);
    float* hfin  = alloc((size_t)N * 128);
    float* u     = alloc((size_t)N * 128);
    float* resid = alloc((size_t)N * 128);
    float* hf1   = alloc((size_t)N * 512);
    float* es1   = alloc((size_t)N * 4); float* ed1 = alloc((size_t)N * 4);
    float* g1    = alloc((size_t)N * 512);
    float* hf2   = alloc((size_t)N * 128);
    float* es2   = alloc(N); float* ed2 = alloc(N);
    (void)ws_size; (void)n_in; (void)in_sizes; (void)out_size;

    // ---- weight prep (independent of UNet) ----
    prep_weights<<<36, TPB, 0, stream>>>(rw, g1w, g2w, W1hi, W1lo, W2hi, W2lo, W3hi, W3lo);

    // ---- CSR build: bucket scatter + per-row dedupe ----
    hipMemsetAsync(cursor, 0, N * sizeof(int), stream);
    bucket_scatter<<<cdiv(E, TPB), TPB, 0, stream>>>(ei, E, buck, cursor);
    build_csr<<<N, 64, 0, stream>>>(buck, cursor, N, nbr, awt, acnt, dinv0, selfw0);

    // ---- down level 0 (sparse) ----
    xw_gemm<<<cdiv(N, TPB / 64), TPB, 0, stream>>>(x, w0, xw, N, 3, 64);
    spmv_gcn<<<N, 64, 0, stream>>>(nbr, awt, acnt, xw, dinv0, selfw0, b0, x0, 64, 1);

    // ---- level 1: topk + sparse SpGEMM augment ----
    score_kernel2<<<cdiv(N, TPB), TPB, 0, stream>>>(x0, p1, score, N);
    run_topk(stream, score, N, K1, rank, perm1, vals1, invp1);
    spgemm_aug<<<K1, TPB, 0, stream>>>(nbr, awt, acnt, perm1, invp1, K1,
                                       A1hi, A1lo, dinv1, selfw1);
    run_gcn_dense(stream, A1hi, A1lo, K1, x0, perm1, vals1, nullptr, nullptr, 0,
                  w1, b1, dinv1, selfw1, xw, yThi, yTlo, Cp, x1, 1);

    // ---- level 2 (dense split-K augment) ----
    score_kernel2<<<cdiv(K1, TPB), TPB, 0, stream>>>(x1, p2, score, K1);
    run_topk(stream, score, K1, K2, rank, perm2, vals2, invp2);
    run_aug_dense(stream, A1hi, A1lo, K1, perm2, K2, Tbf, Agb, Bgb, Caug,
                  A2hi, A2lo, dinv2, selfw2);
    run_gcn_dense(stream, A2hi, A2lo, K2, x1, perm2, vals2, nullptr, nullptr, 0,
                  w2, b2, dinv2, selfw2, xw, yThi, yTlo, Cp, x2, 1);

    // ---- level 3 (dense split-K augment) ----
    score_kernel2<<<cdiv(K2, TPB), TPB, 0, stream>>>(x2, p3, score, K2);
    run_topk(stream, score, K2, K3, rank, perm3, vals3, invp3);
    run_aug_dense(stream, A2hi, A2lo, K2, perm3, K3, Tbf, Agb, Bgb, Caug,
                  A3hi, A3lo, dinv3, selfw3);
    run_gcn_dense(stream, A3hi, A3lo, K3, x2, perm3, vals3, nullptr, nullptr, 0,
                  w3, b3, dinv3, selfw3, xw, yThi, yTlo, Cp, x3, 1);

    // ---- up path (fused unpool inside projection) ----
    run_gcn_dense(stream, A2hi, A2lo, K2, x2, nullptr, nullptr, x3, invp3, 1,
                  uw0, ub0, dinv2, selfw2, xw, yThi, yTlo, Cp, h2, 1);

    run_gcn_dense(stream, A1hi, A1lo, K1, x1, nullptr, nullptr, h2, invp2, 1,
                  uw1, ub1, dinv1, selfw1, xw, yThi, yTlo, Cp, h1, 1);

    xw_gemm_unpool<<<N / 2, TPB, 0, stream>>>(x0, h1, invp1, uw2, xw, N);
    spmv_gcn<<<N, 128, 0, stream>>>(nbr, awt, acnt, xw, dinv0, selfw0, ub2, hfin, 128, 0);

    // ---- layernorm + residual (direct store) ----
    layernorm<<<N, 128, 0, stream>>>(hfin, lng, lnb, u, N);
    gemm_bt_store<<<dim3(2, N / 64), TPB, 0, stream>>>(u, W1hi, W1lo, rb, resid, 128, 128);

    // ---- GAT layer 1 (4 heads, concat, ELU) ----
    gemm_bt_store<<<dim3(8, N / 64), TPB, 0, stream>>>(u, W2hi, W2lo, nullptr, hf1, 128, 512);
    attn_coef2<<<N, 256, 0, stream>>>(hf1, g1as, g1ad, es1, ed1, 4);
    gat_sparse<<<N, TPB, 0, stream>>>(nbr, acnt, N, hf1, es1, ed1, g1b, nullptr, g1, 4, 0);

    // ---- GAT layer 2 (1 head) + residual ----
    hipMemsetAsync(hf2, 0, (size_t)N * 128 * sizeof(float), stream);
    gemm_bt_split<<<dim3(2, N / 64, 4), TPB, 0, stream>>>(g1, W3hi, W3lo, hf2, 512, 128, 128);
    attn_coef2<<<N, 64, 0, stream>>>(hf2, g2as, g2ad, es2, ed2, 1);
    gat_sparse<<<N, TPB, 0, stream>>>(nbr, acnt, N, hf2, es2, ed2, g2b, resid, (float*)d_out, 1, 1);
}

// Round 12
// 438.602 us; speedup vs baseline: 1.5802x; 1.0432x over previous
//
#include <hip/hip_runtime.h>
#include <math.h>

// ---------------------------------------------------------------------------
// GraphUNet + GAT pipeline. N=4096, E=65536, IN=3, H=64, OUT=128, HEADS=4
// Round 12: bf16 hf1 (combined resid+hf1 projection, bf16 GAT gather),
// LN fused into final SpMV, rank-zero fused into score, augment gathers
// fused (+Caug zero), hf2 zero fused into gat layer-1.
// ---------------------------------------------------------------------------

#define TPB 256
#define LDK 88
#define MAXN 128

typedef __attribute__((ext_vector_type(8))) short bf16x8;
typedef __attribute__((ext_vector_type(4))) float f32x4;

__device__ inline ushort f32_to_bf16(float v) {
    unsigned b = __float_as_uint(v);
    return (ushort)((b + 0x7FFF + ((b >> 16) & 1)) >> 16);
}
__device__ inline float bf2f(ushort u) { return __uint_as_float(((unsigned)u) << 16); }

// ---------------- CSR build ----------------
__global__ void bucket_scatter(const int* __restrict__ ei, int E, int* __restrict__ buck,
                               int* __restrict__ cursor) {
    int e = blockIdx.x * TPB + threadIdx.x;
    if (e >= E) return;
    int src = ei[e];
    int dst = ei[E + e];
    int pos = atomicAdd(&cursor[dst], 1);
    if (pos < MAXN) buck[dst * MAXN + pos] = src;
}

__global__ void build_csr(const int* __restrict__ buck, const int* __restrict__ cursor,
                          int n, int* __restrict__ nbr, float* __restrict__ awt,
                          int* __restrict__ acnt, float* __restrict__ dinv,
                          float* __restrict__ selfw) {
    int i = blockIdx.x;
    int tid = threadIdx.x;          // 64 threads
    __shared__ int s[MAXN];
    __shared__ int outcnt, selfFound;
    int raw = cursor[i];
    int d = min(raw, MAXN);
    if (tid == 0) { outcnt = 0; selfFound = 0; }
    for (int p = tid; p < d; p += 64) s[p] = buck[i * MAXN + p];
    __syncthreads();
    for (int p = tid; p < d; p += 64)
        if (s[p] == i) atomicOr(&selfFound, 1);
    __syncthreads();
    for (int p = tid; p < d; p += 64) {
        int v = s[p];
        bool first = true;
        for (int q = 0; q < p; ++q)
            if (s[q] == v) { first = false; break; }
        if (first) {
            int w = 1;
            for (int q = p + 1; q < d; ++q) w += (s[q] == v);
            int slot = atomicAdd(&outcnt, 1);
            nbr[i * MAXN + slot] = v;
            awt[i * MAXN + slot] = (float)w + (v == i ? 1.0f : 0.0f);
        }
    }
    __syncthreads();
    if (tid == 0) {
        int cnt = outcnt;
        if (!selfFound && cnt < MAXN) {
            nbr[i * MAXN + cnt] = i;
            awt[i * MAXN + cnt] = 1.0f;
            ++cnt;
        }
        acnt[i] = cnt;
        float sw = selfFound ? 0.f : 2.f;
        dinv[i] = 1.0f / sqrtf((float)raw + sw);
        selfw[i] = sw;
    }
}

// ---------------- xw projection (level-0 down, fin=3) ----------------
__global__ void xw_gemm(const float* __restrict__ xin, const float* __restrict__ W,
                        float* __restrict__ C, int n, int fin, int f) {
    __shared__ float sW[64 * 128];
    int tid = threadIdx.x;
    for (int t = tid; t < fin * f; t += TPB) sW[t] = W[t];
    __syncthreads();
    int rpb = TPB / f;
    int r = blockIdx.x * rpb + tid / f;
    int c = tid - (tid / f) * f;
    if (r >= n) return;
    const float* xr = xin + (size_t)r * fin;
    float acc = 0.f;
    for (int k = 0; k < fin; ++k) acc += xr[k] * sW[k * f + c];
    C[(size_t)r * f + c] = acc;
}

// level-0 up: in = xsrc + unpool(hprev); C = in @ W (64 -> 128)
__global__ void xw_gemm_unpool(const float* __restrict__ xsrc, const float* __restrict__ hprev,
                               const int* __restrict__ invp, const float* __restrict__ W,
                               float* __restrict__ C, int n) {
    __shared__ float sW[64 * 128];
    __shared__ float sin_[2][64];
    int tid = threadIdx.x;
    for (int t = tid; t < 8192; t += TPB) sW[t] = W[t];
    int r0 = blockIdx.x * 2;
    int lr = tid >> 7, c = tid & 127;
    int r = r0 + lr;
    if (c < 64) {
        float v = xsrc[(size_t)r * 64 + c];
        int q = invp[r];
        if (q >= 0) v += hprev[(size_t)q * 64 + c];
        sin_[lr][c] = v;
    }
    __syncthreads();
    float acc = 0.f;
#pragma unroll
    for (int k = 0; k < 64; ++k) acc += sin_[lr][k] * sW[k * 128 + c];
    C[(size_t)r * 128 + c] = acc;
}

// ---------------- fused dense-level input + projection + yT --------------
__global__ void fused_in_gemm(const float* __restrict__ xsrc, const int* __restrict__ perm,
                              const float* __restrict__ vals, const float* __restrict__ hprev,
                              const int* __restrict__ invp, const float* __restrict__ W,
                              const float* __restrict__ dinv, float* __restrict__ xw,
                              ushort* __restrict__ yThi, ushort* __restrict__ yTlo,
                              float* __restrict__ Cp, int n, int mode) {
    __shared__ float sW[64 * 64];
    __shared__ float sin_[4][64];
    __shared__ float sy[4][64];
    int tid = threadIdx.x;
    for (int t = tid; t < 4096; t += TPB) sW[t] = W[t];
    int r0 = blockIdx.x * 4;
    int lr = tid >> 6, c = tid & 63;
    int r = r0 + lr;
    float v;
    if (mode == 0) {
        v = xsrc[(size_t)perm[r] * 64 + c] * vals[r];
    } else {
        v = xsrc[(size_t)r * 64 + c];
        int q = invp[r];
        if (q >= 0) v += hprev[(size_t)q * 64 + c];
    }
    sin_[lr][c] = v;
    __syncthreads();
    float acc = 0.f;
#pragma unroll
    for (int k = 0; k < 64; ++k) acc += sin_[lr][k] * sW[k * 64 + c];
    size_t o = (size_t)r * 64 + c;
    xw[o] = acc;
    Cp[o] = 0.f;
    sy[lr][c] = acc * dinv[r];
    __syncthreads();
    if (lr == 0) {
        float y0 = sy[0][c], y1 = sy[1][c], y2 = sy[2][c], y3 = sy[3][c];
        ushort h0 = f32_to_bf16(y0), h1 = f32_to_bf16(y1);
        ushort h2 = f32_to_bf16(y2), h3 = f32_to_bf16(y3);
        uint2 ph, pl;
        ph.x = (uint)h0 | ((uint)h1 << 16);
        ph.y = (uint)h2 | ((uint)h3 << 16);
        pl.x = (uint)f32_to_bf16(y0 - bf2f(h0)) | ((uint)f32_to_bf16(y1 - bf2f(h1)) << 16);
        pl.y = (uint)f32_to_bf16(y2 - bf2f(h2)) | ((uint)f32_to_bf16(y3 - bf2f(h3)) << 16);
        *(uint2*)&yThi[(size_t)c * n + r0] = ph;
        *(uint2*)&yTlo[(size_t)c * n + r0] = pl;
    }
}

// ---------------- level-0 GCN: fused sparse SpMV ----------------
__global__ void spmv_gcn(const int* __restrict__ nbr, const float* __restrict__ awt,
                         const int* __restrict__ acnt, const float* __restrict__ xw,
                         const float* __restrict__ dinv, const float* __restrict__ selfw,
                         const float* __restrict__ bias, float* __restrict__ out,
                         int f, int relu) {
    int i = blockIdx.x;
    int o = threadIdx.x;
    __shared__ int sj[MAXN];
    __shared__ float sw_[MAXN];
    int cnt = acnt[i];
    for (int a = o; a < cnt; a += blockDim.x) {
        sj[a] = nbr[i * MAXN + a];
        sw_[a] = awt[i * MAXN + a];
    }
    __syncthreads();
    if (o >= f) return;
    float sum = 0.f;
    for (int a = 0; a < cnt; ++a) {
        int j = sj[a];
        sum += sw_[a] * (xw[(size_t)j * f + o] * dinv[j]);
    }
    float yi = xw[(size_t)i * f + o] * dinv[i];
    sum -= yi;
    float v = dinv[i] * (sum + selfw[i] * yi) + bias[o];
    if (relu) v = fmaxf(v, 0.f);
    out[(size_t)i * f + o] = v;
}

// final up-conv SpMV with fused LayerNorm (f=128, one block per node)
__global__ void spmv_gcn_ln(const int* __restrict__ nbr, const float* __restrict__ awt,
                            const int* __restrict__ acnt, const float* __restrict__ xw,
                            const float* __restrict__ dinv, const float* __restrict__ selfw,
                            const float* __restrict__ bias, const float* __restrict__ g,
                            const float* __restrict__ lb, float* __restrict__ u) {
    int i = blockIdx.x;
    int o = threadIdx.x;  // 128
    __shared__ int sj[MAXN];
    __shared__ float sw_[MAXN];
    __shared__ float s0[2], s1[2];
    int cnt = acnt[i];
    for (int a = o; a < cnt; a += 128) {
        sj[a] = nbr[i * MAXN + a];
        sw_[a] = awt[i * MAXN + a];
    }
    __syncthreads();
    float sum = 0.f;
    for (int a = 0; a < cnt; ++a) {
        int j = sj[a];
        sum += sw_[a] * (xw[(size_t)j * 128 + o] * dinv[j]);
    }
    float yi = xw[(size_t)i * 128 + o] * dinv[i];
    sum -= yi;
    float v = dinv[i] * (sum + selfw[i] * yi) + bias[o];
    float s = v;
    for (int off = 32; off; off >>= 1) s += __shfl_xor(s, off);
    if ((o & 63) == 0) s0[o >> 6] = s;
    __syncthreads();
    float mu = (s0[0] + s0[1]) * (1.0f / 128.0f);
    float d = v - mu;
    float sq = d * d;
    for (int off = 32; off; off >>= 1) sq += __shfl_xor(sq, off);
    if ((o & 63) == 0) s1[o >> 6] = sq;
    __syncthreads();
    float var = (s1[0] + s1[1]) * (1.0f / 128.0f);
    u[(size_t)i * 128 + o] = d / sqrtf(var + 1e-6f) * g[o] + lb[o];
}

// ---------------- pooling: score (+rank zero) + 2D rank-count top-k --------
__global__ void score_kernel2(const float* __restrict__ x, const float* __restrict__ p,
                              float* __restrict__ s, int* __restrict__ rank, int n) {
    int i = blockIdx.x * TPB + threadIdx.x;
    if (i >= n) return;
    float a = 0.f, nrm = 0.f;
    for (int c = 0; c < 64; ++c) {
        float pc = p[c];
        nrm += pc * pc;
        a += x[(size_t)i * 64 + c] * pc;
    }
    s[i] = tanhf(a / sqrtf(nrm));
    rank[i] = 0;
}

__global__ void rank_count(const float* __restrict__ s, int n, int* __restrict__ rank) {
    __shared__ float sj[256];
    int i = blockIdx.x * 256 + threadIdx.x;
    int j0 = blockIdx.y * 256;
    sj[threadIdx.x] = s[j0 + threadIdx.x];
    float si = s[i];
    __syncthreads();
    int r = 0;
#pragma unroll 8
    for (int jj = 0; jj < 256; ++jj) {
        float v = sj[jj];
        r += (v > si) || (v == si && (j0 + jj) < i);
    }
    atomicAdd(&rank[i], r);
}

__global__ void scatter_topk_all(const float* __restrict__ s, const int* __restrict__ rank,
                                 int n, int k, int* __restrict__ perm,
                                 float* __restrict__ vals, int* __restrict__ invp) {
    int i = blockIdx.x * TPB + threadIdx.x;
    if (i >= n) return;
    int r = rank[i];
    if (r < k) { perm[r] = i; vals[r] = s[i]; invp[i] = r; }
    else invp[i] = -1;
}

// ---------------- level-1 augment: sparse SpGEMM ----------------
__global__ void spgemm_aug(const int* __restrict__ nbr, const float* __restrict__ awt,
                           const int* __restrict__ acnt, const int* __restrict__ perm,
                           const int* __restrict__ invp, int k,
                           ushort* __restrict__ Chi, ushort* __restrict__ Clo,
                           float* __restrict__ dinv, float* __restrict__ selfw) {
    __shared__ float row[2048];
    int r = blockIdx.x, tid = threadIdx.x;
    int pi = perm[r];
    for (int j = tid; j < k; j += TPB) row[j] = 0.f;
    __syncthreads();
    int cnt = acnt[pi];
    for (int a = 0; a < cnt; ++a) {
        int t = nbr[pi * MAXN + a];
        float w1 = awt[pi * MAXN + a];
        int c2 = acnt[t];
        for (int b = tid; b < c2; b += TPB) {
            int s = nbr[t * MAXN + b];
            int j = invp[s];
            if (j >= 0) atomicAdd(&row[j], w1 * awt[t * MAXN + b]);
        }
    }
    __syncthreads();
    float psum = 0.f;
    for (int j = tid; j < k; j += TPB) {
        float v = (j == r) ? 0.f : row[j];
        psum += v;
        ushort hi = f32_to_bf16(v);
        size_t o = (size_t)r * k + j;
        Chi[o] = hi;
        Clo[o] = f32_to_bf16(v - bf2f(hi));
    }
    for (int o = 32; o; o >>= 1) psum += __shfl_xor(psum, o);
    __shared__ float sh[4];
    if ((tid & 63) == 0) sh[tid >> 6] = psum;
    __syncthreads();
    if (tid == 0) {
        float tot = sh[0] + sh[1] + sh[2] + sh[3];
        dinv[r] = 1.0f / sqrtf(tot + 2.0f);
        selfw[r] = 2.0f;
    }
}

// ---------------- dense augment (levels 2,3) ----------------
__global__ void transpose_aug_hl(const ushort* __restrict__ Ahi, const ushort* __restrict__ Alo,
                                 ushort* __restrict__ T, int n) {
    __shared__ float tile[64][65];
    int c0 = blockIdx.x * 64, r0 = blockIdx.y * 64;
    for (int t = threadIdx.x; t < 4096; t += TPB) {
        int r = t >> 6, c = t & 63;
        size_t o = (size_t)(r0 + r) * n + (c0 + c);
        float v = bf2f(Ahi[o]) + bf2f(Alo[o]);
        if (r0 + r == c0 + c) v += 1.0f;
        tile[c][r] = v;
    }
    __syncthreads();
    for (int t = threadIdx.x; t < 4096; t += TPB) {
        int c = t >> 6, r = t & 63;
        T[(size_t)(c0 + c) * n + (r0 + r)] = f32_to_bf16(tile[c][r]);
    }
}

// fused: A-row gather (+I) | T-row gather, plus Caug zeroing in branch 0
__global__ void gather_both(const ushort* __restrict__ Ahi, const ushort* __restrict__ Alo,
                            const ushort* __restrict__ T, const int* __restrict__ perm,
                            ushort* __restrict__ Ag, ushort* __restrict__ Bg,
                            float* __restrict__ Caug, int n, int k) {
    int id = blockIdx.x * TPB + threadIdx.x;
    if (id >= k * n) return;
    int r = id / n, t = id - r * n;
    if (blockIdx.y == 0) {
        int pr = perm[r];
        size_t o = (size_t)pr * n + t;
        float v = bf2f(Ahi[o]) + bf2f(Alo[o]);
        if (pr == t) v += 1.0f;
        Ag[id] = f32_to_bf16(v);
        if (t < k) Caug[(size_t)r * k + t] = 0.f;
    } else {
        Bg[id] = T[(size_t)perm[r] * n + t];
    }
}

__global__ void __launch_bounds__(256)
aug_gemm_acc(const ushort* __restrict__ Ag, const ushort* __restrict__ Bg,
             float* __restrict__ Caug, int K, int ldc, int kpb) {
    __shared__ __align__(16) ushort As[64 * LDK];
    __shared__ __align__(16) ushort Bs[64 * LDK];
    int tid = threadIdx.x;
    int wave = tid >> 6, lane = tid & 63;
    int wr = wave >> 1, wc = wave & 1;
    int m = lane & 15, quad = lane >> 4;
    int i0 = blockIdx.y * 64, j0 = blockIdx.x * 64;
    int kbeg = blockIdx.z * kpb;
    f32x4 acc[2][2];
#pragma unroll
    for (int a = 0; a < 2; ++a)
#pragma unroll
        for (int b = 0; b < 2; ++b) acc[a][b] = (f32x4){0.f, 0.f, 0.f, 0.f};
    const ushort* Ab = Ag + (size_t)i0 * K;
    const ushort* Bb = Bg + (size_t)j0 * K;
    for (int k0 = kbeg; k0 < kbeg + kpb; k0 += 64) {
#pragma unroll
        for (int v = 0; v < 2; ++v) {
            int idx = tid + (v << 8);
            int r = idx >> 3, c8 = idx & 7;
            *(uint4*)&As[r * LDK + c8 * 8] = *(const uint4*)&Ab[(size_t)r * K + k0 + c8 * 8];
            *(uint4*)&Bs[r * LDK + c8 * 8] = *(const uint4*)&Bb[(size_t)r * K + k0 + c8 * 8];
        }
        __syncthreads();
#pragma unroll
        for (int kk = 0; kk < 2; ++kk) {
            bf16x8 af[2], bfr[2];
#pragma unroll
            for (int mi = 0; mi < 2; ++mi)
                af[mi] = *(const bf16x8*)&As[(wr * 32 + mi * 16 + m) * LDK + kk * 32 + quad * 8];
#pragma unroll
            for (int ni = 0; ni < 2; ++ni)
                bfr[ni] = *(const bf16x8*)&Bs[(wc * 32 + ni * 16 + m) * LDK + kk * 32 + quad * 8];
#pragma unroll
            for (int mi = 0; mi < 2; ++mi)
#pragma unroll
                for (int ni = 0; ni < 2; ++ni)
                    acc[mi][ni] = __builtin_amdgcn_mfma_f32_16x16x32_bf16(
                        af[mi], bfr[ni], acc[mi][ni], 0, 0, 0);
        }
        __syncthreads();
    }
#pragma unroll
    for (int mi = 0; mi < 2; ++mi)
#pragma unroll
        for (int ni = 0; ni < 2; ++ni)
#pragma unroll
            for (int r = 0; r < 4; ++r) {
                int gi = i0 + wr * 32 + mi * 16 + quad * 4 + r;
                int gj = j0 + wc * 32 + ni * 16 + m;
                atomicAdd(&Caug[(size_t)gi * ldc + gj], acc[mi][ni][r]);
            }
}

__global__ void aug_finalize(const float* __restrict__ Caug, int k,
                             ushort* __restrict__ Chi, ushort* __restrict__ Clo,
                             float* __restrict__ dinv, float* __restrict__ selfw) {
    int r = blockIdx.x, tid = threadIdx.x;
    const float* row = Caug + (size_t)r * k;
    float psum = 0.f;
    for (int j = tid; j < k; j += TPB) {
        float v = (j == r) ? 0.f : row[j];
        psum += v;
        ushort hi = f32_to_bf16(v);
        size_t o = (size_t)r * k + j;
        Chi[o] = hi;
        Clo[o] = f32_to_bf16(v - bf2f(hi));
    }
    for (int o = 32; o; o >>= 1) psum += __shfl_xor(psum, o);
    __shared__ float sh[4];
    if ((tid & 63) == 0) sh[tid >> 6] = psum;
    __syncthreads();
    if (tid == 0) {
        float tot = sh[0] + sh[1] + sh[2] + sh[3];
        dinv[r] = 1.0f / sqrtf(tot + 2.0f);
        selfw[r] = 2.0f;
    }
}

// ---------------- dense GCN aggregation (levels >=1) ----------------
__global__ void __launch_bounds__(256)
gcn_gemm(const ushort* __restrict__ Ahi, const ushort* __restrict__ Alo,
         const ushort* __restrict__ Bhi, const ushort* __restrict__ Blo,
         float* __restrict__ C, int K, int ldc, int kpb) {
    __shared__ __align__(16) ushort sAh[64 * LDK];
    __shared__ __align__(16) ushort sAl[64 * LDK];
    __shared__ __align__(16) ushort sBh[64 * LDK];
    __shared__ __align__(16) ushort sBl[64 * LDK];
    int tid = threadIdx.x;
    int wave = tid >> 6, lane = tid & 63;
    int wr = wave >> 1, wc = wave & 1;
    int m = lane & 15, quad = lane >> 4;
    int i0 = blockIdx.y * 64, j0 = blockIdx.x * 64;
    int kbeg = blockIdx.z * kpb;
    f32x4 acc[2][2];
#pragma unroll
    for (int a = 0; a < 2; ++a)
#pragma unroll
        for (int b = 0; b < 2; ++b) acc[a][b] = (f32x4){0.f, 0.f, 0.f, 0.f};
    for (int k0 = kbeg; k0 < kbeg + kpb; k0 += 64) {
#pragma unroll
        for (int v = 0; v < 2; ++v) {
            int idx = tid + (v << 8);
            int r = idx >> 3, c8 = idx & 7;
            size_t boff = (size_t)(j0 + r) * K + k0 + c8 * 8;
            *(uint4*)&sBh[r * LDK + c8 * 8] = *(const uint4*)&Bhi[boff];
            *(uint4*)&sBl[r * LDK + c8 * 8] = *(const uint4*)&Blo[boff];
            size_t aoff = (size_t)(i0 + r) * K + k0 + c8 * 8;
            *(uint4*)&sAh[r * LDK + c8 * 8] = *(const uint4*)&Ahi[aoff];
            *(uint4*)&sAl[r * LDK + c8 * 8] = *(const uint4*)&Alo[aoff];
        }
        __syncthreads();
#pragma unroll
        for (int kk = 0; kk < 2; ++kk) {
            bf16x8 ah[2], al[2], bh[2], bl[2];
#pragma unroll
            for (int mi = 0; mi < 2; ++mi) {
                ah[mi] = *(const bf16x8*)&sAh[(wr * 32 + mi * 16 + m) * LDK + kk * 32 + quad * 8];
                al[mi] = *(const bf16x8*)&sAl[(wr * 32 + mi * 16 + m) * LDK + kk * 32 + quad * 8];
            }
#pragma unroll
            for (int ni = 0; ni < 2; ++ni) {
                bh[ni] = *(const bf16x8*)&sBh[(wc * 32 + ni * 16 + m) * LDK + kk * 32 + quad * 8];
                bl[ni] = *(const bf16x8*)&sBl[(wc * 32 + ni * 16 + m) * LDK + kk * 32 + quad * 8];
            }
#pragma unroll
            for (int mi = 0; mi < 2; ++mi)
#pragma unroll
                for (int ni = 0; ni < 2; ++ni) {
                    acc[mi][ni] = __builtin_amdgcn_mfma_f32_16x16x32_bf16(ah[mi], bh[ni], acc[mi][ni], 0, 0, 0);
                    acc[mi][ni] = __builtin_amdgcn_mfma_f32_16x16x32_bf16(ah[mi], bl[ni], acc[mi][ni], 0, 0, 0);
                    acc[mi][ni] = __builtin_amdgcn_mfma_f32_16x16x32_bf16(al[mi], bh[ni], acc[mi][ni], 0, 0, 0);
                }
        }
        __syncthreads();
    }
#pragma unroll
    for (int mi = 0; mi < 2; ++mi)
#pragma unroll
        for (int ni = 0; ni < 2; ++ni)
#pragma unroll
            for (int r = 0; r < 4; ++r) {
                int gi = i0 + wr * 32 + mi * 16 + quad * 4 + r;
                int gj = j0 + wc * 32 + ni * 16 + m;
                atomicAdd(&C[(size_t)gi * ldc + gj], acc[mi][ni][r]);
            }
}

__global__ void gcn_epilogue(const float* __restrict__ C, const float* __restrict__ xw,
                             const float* __restrict__ dinv, const float* __restrict__ selfw,
                             const float* __restrict__ b, float* __restrict__ out,
                             int n, int f, int relu) {
    int id = blockIdx.x * TPB + threadIdx.x;
    if (id >= n * f) return;
    int i = id / f, c = id - i * f;
    float y = xw[id] * dinv[i];
    float v = dinv[i] * (C[id] + selfw[i] * y) + b[c];
    if (relu) v = fmaxf(v, 0.f);
    out[id] = v;
}

// ---------------- weight prep ----------------
__global__ void prep_weights(const float* __restrict__ rw, const float* __restrict__ g1w,
                             const float* __restrict__ g2w,
                             ushort* __restrict__ W1hi, ushort* __restrict__ W1lo,
                             ushort* __restrict__ W2hi, ushort* __restrict__ W2lo,
                             ushort* __restrict__ W3hi, ushort* __restrict__ W3lo) {
    __shared__ float tile[64][65];
    int b = blockIdx.x;
    const float* W; ushort *Bhi, *Blo; int K, Nn, bx, by;
    if (b < 4)       { W = rw;  Bhi = W1hi; Blo = W1lo; K = 128; Nn = 128; bx = b & 1;        by = b >> 1; }
    else if (b < 20) { int t = b - 4;  W = g1w; Bhi = W2hi; Blo = W2lo; K = 128; Nn = 512; bx = t & 7; by = t >> 3; }
    else             { int t = b - 20; W = g2w; Bhi = W3hi; Blo = W3lo; K = 512; Nn = 128; bx = t & 1; by = t >> 1; }
    int n0 = bx * 64, k0 = by * 64;
    for (int t = threadIdx.x; t < 4096; t += TPB) {
        int r = t >> 6, c = t & 63;
        tile[r][c] = W[(size_t)(k0 + r) * Nn + (n0 + c)];
    }
    __syncthreads();
    for (int t = threadIdx.x; t < 4096; t += TPB) {
        int c = t >> 6, r = t & 63;
        float v = tile[r][c];
        ushort hi = f32_to_bf16(v);
        size_t o = (size_t)(n0 + c) * K + (k0 + r);
        Bhi[o] = hi;
        Blo[o] = f32_to_bf16(v - bf2f(hi));
    }
}

// ---------------- combined resid + hf1(bf16) projection (K=128) -----------
__global__ void __launch_bounds__(256)
gemm_bt_multi(const float* __restrict__ A,
              const ushort* __restrict__ W1hi, const ushort* __restrict__ W1lo,
              const float* __restrict__ rb, float* __restrict__ resid,
              const ushort* __restrict__ W2hi, const ushort* __restrict__ W2lo,
              ushort* __restrict__ hf1b) {
    __shared__ __align__(16) ushort sAh[64 * LDK];
    __shared__ __align__(16) ushort sAl[64 * LDK];
    __shared__ __align__(16) ushort sBh[64 * LDK];
    __shared__ __align__(16) ushort sBl[64 * LDK];
    int tid = threadIdx.x;
    int wave = tid >> 6, lane = tid & 63;
    int wr = wave >> 1, wc = wave & 1;
    int m = lane & 15, quad = lane >> 4;
    int b = blockIdx.x;
    const ushort *Bhi, *Blo; int j0; bool tohf;
    if (b < 2) { Bhi = W1hi; Blo = W1lo; j0 = b * 64; tohf = false; }
    else       { Bhi = W2hi; Blo = W2lo; j0 = (b - 2) * 64; tohf = true; }
    int i0 = blockIdx.y * 64;
    f32x4 acc[2][2];
#pragma unroll
    for (int a = 0; a < 2; ++a)
#pragma unroll
        for (int bb = 0; bb < 2; ++bb) acc[a][bb] = (f32x4){0.f, 0.f, 0.f, 0.f};
    for (int k0 = 0; k0 < 128; k0 += 64) {
#pragma unroll
        for (int v = 0; v < 2; ++v) {
            int idx = tid + (v << 8);
            int r = idx >> 3, c8 = idx & 7;
            size_t boff = (size_t)(j0 + r) * 128 + k0 + c8 * 8;
            *(uint4*)&sBh[r * LDK + c8 * 8] = *(const uint4*)&Bhi[boff];
            *(uint4*)&sBl[r * LDK + c8 * 8] = *(const uint4*)&Blo[boff];
            size_t aoff = (size_t)(i0 + r) * 128 + k0 + c8 * 8;
            float4 fa = *(const float4*)&A[aoff];
            float4 fb = *(const float4*)&A[aoff + 4];
            ushort h0 = f32_to_bf16(fa.x), h1 = f32_to_bf16(fa.y);
            ushort h2 = f32_to_bf16(fa.z), h3 = f32_to_bf16(fa.w);
            ushort h4 = f32_to_bf16(fb.x), h5 = f32_to_bf16(fb.y);
            ushort h6 = f32_to_bf16(fb.z), h7 = f32_to_bf16(fb.w);
            uint4 ph, pl;
            ph.x = (uint)h0 | ((uint)h1 << 16);
            ph.y = (uint)h2 | ((uint)h3 << 16);
            ph.z = (uint)h4 | ((uint)h5 << 16);
            ph.w = (uint)h6 | ((uint)h7 << 16);
            pl.x = (uint)f32_to_bf16(fa.x - bf2f(h0)) | ((uint)f32_to_bf16(fa.y - bf2f(h1)) << 16);
            pl.y = (uint)f32_to_bf16(fa.z - bf2f(h2)) | ((uint)f32_to_bf16(fa.w - bf2f(h3)) << 16);
            pl.z = (uint)f32_to_bf16(fb.x - bf2f(h4)) | ((uint)f32_to_bf16(fb.y - bf2f(h5)) << 16);
            pl.w = (uint)f32_to_bf16(fb.z - bf2f(h6)) | ((uint)f32_to_bf16(fb.w - bf2f(h7)) << 16);
            *(uint4*)&sAh[r * LDK + c8 * 8] = ph;
            *(uint4*)&sAl[r * LDK + c8 * 8] = pl;
        }
        __syncthreads();
#pragma unroll
        for (int kk = 0; kk < 2; ++kk) {
            bf16x8 ah[2], al[2], bh[2], bl[2];
#pragma unroll
            for (int mi = 0; mi < 2; ++mi) {
                ah[mi] = *(const bf16x8*)&sAh[(wr * 32 + mi * 16 + m) * LDK + kk * 32 + quad * 8];
                al[mi] = *(const bf16x8*)&sAl[(wr * 32 + mi * 16 + m) * LDK + kk * 32 + quad * 8];
            }
#pragma unroll
            for (int ni = 0; ni < 2; ++ni) {
                bh[ni] = *(const bf16x8*)&sBh[(wc * 32 + ni * 16 + m) * LDK + kk * 32 + quad * 8];
                bl[ni] = *(const bf16x8*)&sBl[(wc * 32 + ni * 16 + m) * LDK + kk * 32 + quad * 8];
            }
#pragma unroll
            for (int mi = 0; mi < 2; ++mi)
#pragma unroll
                for (int ni = 0; ni < 2; ++ni) {
                    acc[mi][ni] = __builtin_amdgcn_mfma_f32_16x16x32_bf16(ah[mi], bh[ni], acc[mi][ni], 0, 0, 0);
                    acc[mi][ni] = __builtin_amdgcn_mfma_f32_16x16x32_bf16(ah[mi], bl[ni], acc[mi][ni], 0, 0, 0);
                    acc[mi][ni] = __builtin_amdgcn_mfma_f32_16x16x32_bf16(al[mi], bh[ni], acc[mi][ni], 0, 0, 0);
                }
        }
        __syncthreads();
    }
#pragma unroll
    for (int mi = 0; mi < 2; ++mi)
#pragma unroll
        for (int ni = 0; ni < 2; ++ni)
#pragma unroll
            for (int r = 0; r < 4; ++r) {
                int gi = i0 + wr * 32 + mi * 16 + quad * 4 + r;
                int gj = j0 + wc * 32 + ni * 16 + m;
                float v = acc[mi][ni][r];
                if (tohf) hf1b[(size_t)gi * 512 + gj] = f32_to_bf16(v);
                else      resid[(size_t)gi * 128 + gj] = v + rb[gj];
            }
}

// split-K atomic variant (hf2, K=512)
__global__ void __launch_bounds__(256)
gemm_bt_split(const float* __restrict__ A, const ushort* __restrict__ Bhi,
              const ushort* __restrict__ Blo, float* __restrict__ C,
              int K, int N, int kpb) {
    __shared__ __align__(16) ushort sAh[64 * LDK];
    __shared__ __align__(16) ushort sAl[64 * LDK];
    __shared__ __align__(16) ushort sBh[64 * LDK];
    __shared__ __align__(16) ushort sBl[64 * LDK];
    int tid = threadIdx.x;
    int wave = tid >> 6, lane = tid & 63;
    int wr = wave >> 1, wc = wave & 1;
    int m = lane & 15, quad = lane >> 4;
    int i0 = blockIdx.y * 64, j0 = blockIdx.x * 64;
    int kbeg = blockIdx.z * kpb;
    f32x4 acc[2][2];
#pragma unroll
    for (int a = 0; a < 2; ++a)
#pragma unroll
        for (int b = 0; b < 2; ++b) acc[a][b] = (f32x4){0.f, 0.f, 0.f, 0.f};
    for (int k0 = kbeg; k0 < kbeg + kpb; k0 += 64) {
#pragma unroll
        for (int v = 0; v < 2; ++v) {
            int idx = tid + (v << 8);
            int r = idx >> 3, c8 = idx & 7;
            size_t boff = (size_t)(j0 + r) * K + k0 + c8 * 8;
            *(uint4*)&sBh[r * LDK + c8 * 8] = *(const uint4*)&Bhi[boff];
            *(uint4*)&sBl[r * LDK + c8 * 8] = *(const uint4*)&Blo[boff];
            size_t aoff = (size_t)(i0 + r) * K + k0 + c8 * 8;
            float4 fa = *(const float4*)&A[aoff];
            float4 fb = *(const float4*)&A[aoff + 4];
            ushort h0 = f32_to_bf16(fa.x), h1 = f32_to_bf16(fa.y);
            ushort h2 = f32_to_bf16(fa.z), h3 = f32_to_bf16(fa.w);
            ushort h4 = f32_to_bf16(fb.x), h5 = f32_to_bf16(fb.y);
            ushort h6 = f32_to_bf16(fb.z), h7 = f32_to_bf16(fb.w);
            uint4 ph, pl;
            ph.x = (uint)h0 | ((uint)h1 << 16);
            ph.y = (uint)h2 | ((uint)h3 << 16);
            ph.z = (uint)h4 | ((uint)h5 << 16);
            ph.w = (uint)h6 | ((uint)h7 << 16);
            pl.x = (uint)f32_to_bf16(fa.x - bf2f(h0)) | ((uint)f32_to_bf16(fa.y - bf2f(h1)) << 16);
            pl.y = (uint)f32_to_bf16(fa.z - bf2f(h2)) | ((uint)f32_to_bf16(fa.w - bf2f(h3)) << 16);
            pl.z = (uint)f32_to_bf16(fb.x - bf2f(h4)) | ((uint)f32_to_bf16(fb.y - bf2f(h5)) << 16);
            pl.w = (uint)f32_to_bf16(fb.z - bf2f(h6)) | ((uint)f32_to_bf16(fb.w - bf2f(h7)) << 16);
            *(uint4*)&sAh[r * LDK + c8 * 8] = ph;
            *(uint4*)&sAl[r * LDK + c8 * 8] = pl;
        }
        __syncthreads();
#pragma unroll
        for (int kk = 0; kk < 2; ++kk) {
            bf16x8 ah[2], al[2], bh[2], bl[2];
#pragma unroll
            for (int mi = 0; mi < 2; ++mi) {
                ah[mi] = *(const bf16x8*)&sAh[(wr * 32 + mi * 16 + m) * LDK + kk * 32 + quad * 8];
                al[mi] = *(const bf16x8*)&sAl[(wr * 32 + mi * 16 + m) * LDK + kk * 32 + quad * 8];
            }
#pragma unroll
            for (int ni = 0; ni < 2; ++ni) {
                bh[ni] = *(const bf16x8*)&sBh[(wc * 32 + ni * 16 + m) * LDK + kk * 32 + quad * 8];
                bl[ni] = *(const bf16x8*)&sBl[(wc * 32 + ni * 16 + m) * LDK + kk * 32 + quad * 8];
            }
#pragma unroll
            for (int mi = 0; mi < 2; ++mi)
#pragma unroll
                for (int ni = 0; ni < 2; ++ni) {
                    acc[mi][ni] = __builtin_amdgcn_mfma_f32_16x16x32_bf16(ah[mi], bh[ni], acc[mi][ni], 0, 0, 0);
                    acc[mi][ni] = __builtin_amdgcn_mfma_f32_16x16x32_bf16(ah[mi], bl[ni], acc[mi][ni], 0, 0, 0);
                    acc[mi][ni] = __builtin_amdgcn_mfma_f32_16x16x32_bf16(al[mi], bh[ni], acc[mi][ni], 0, 0, 0);
                }
        }
        __syncthreads();
    }
#pragma unroll
    for (int mi = 0; mi < 2; ++mi)
#pragma unroll
        for (int ni = 0; ni < 2; ++ni)
#pragma unroll
            for (int r = 0; r < 4; ++r) {
                int gi = i0 + wr * 32 + mi * 16 + quad * 4 + r;
                int gj = j0 + wc * 32 + ni * 16 + m;
                atomicAdd(&C[(size_t)gi * N + gj], acc[mi][ni][r]);
            }
}

// ---------------- GAT ----------------
__global__ void attn_coef2_b16(const ushort* __restrict__ hf, const float* __restrict__ asrc,
                               const float* __restrict__ adst, float* __restrict__ es,
                               float* __restrict__ ed, int heads) {
    int j = blockIdx.x;
    int wave = threadIdx.x >> 6, lane = threadIdx.x & 63;
    if (wave >= heads) return;
    const ushort* hp = hf + (size_t)j * heads * 128 + wave * 128;
    float v0 = bf2f(hp[lane]), v1 = bf2f(hp[lane + 64]);
    float a = v0 * asrc[wave * 128 + lane] + v1 * asrc[wave * 128 + lane + 64];
    float d = v0 * adst[wave * 128 + lane] + v1 * adst[wave * 128 + lane + 64];
    for (int o = 32; o; o >>= 1) { a += __shfl_xor(a, o); d += __shfl_xor(d, o); }
    if (lane == 0) { es[j * heads + wave] = a; ed[j * heads + wave] = d; }
}

__global__ void attn_coef2(const float* __restrict__ hf, const float* __restrict__ asrc,
                           const float* __restrict__ adst, float* __restrict__ es,
                           float* __restrict__ ed, int heads) {
    int j = blockIdx.x;
    int wave = threadIdx.x >> 6, lane = threadIdx.x & 63;
    if (wave >= heads) return;
    const float* hp = hf + (size_t)j * heads * 128 + wave * 128;
    float v0 = hp[lane], v1 = hp[lane + 64];
    float a = v0 * asrc[wave * 128 + lane] + v1 * asrc[wave * 128 + lane + 64];
    float d = v0 * adst[wave * 128 + lane] + v1 * adst[wave * 128 + lane + 64];
    for (int o = 32; o; o >>= 1) { a += __shfl_xor(a, o); d += __shfl_xor(d, o); }
    if (lane == 0) { es[j * heads + wave] = a; ed[j * heads + wave] = d; }
}

// layer-1 GAT: bf16 features, ELU, also zeroes hf2 accumulator
__global__ void gat_sparse_b16(const int* __restrict__ nbr, const int* __restrict__ ncnt, int n,
                               const ushort* __restrict__ hf, const float* __restrict__ es,
                               const float* __restrict__ ed, const float* __restrict__ bias,
                               float* __restrict__ out, float* __restrict__ zbuf) {
    const int heads = 4;
    int i = blockIdx.x;
    int tid = threadIdx.x;
    __shared__ int idx[MAXN];
    __shared__ float lg[MAXN * 4];
    __shared__ float hmax[4], hsum[4];
    for (int o2 = tid; o2 < 128; o2 += TPB) zbuf[(size_t)i * 128 + o2] = 0.f;
    int m = ncnt[i];
    for (int t = tid; t < m; t += TPB) idx[t] = nbr[i * MAXN + t];
    __syncthreads();
    for (int t = tid; t < m * heads; t += TPB) {
        int jl = t / heads, h = t - jl * heads;
        float l = ed[i * heads + h] + es[idx[jl] * heads + h];
        lg[jl * heads + h] = (l > 0.f) ? l : 0.2f * l;
    }
    __syncthreads();
    int h = tid >> 6, lane = tid & 63;
    {
        float mx = -3.4e38f;
        for (int jl = lane; jl < m; jl += 64) mx = fmaxf(mx, lg[jl * heads + h]);
        for (int o = 32; o; o >>= 1) mx = fmaxf(mx, __shfl_xor(mx, o));
        if (lane == 0) hmax[h] = mx;
    }
    __syncthreads();
    {
        float mx = hmax[h];
        float sm = 0.f;
        for (int jl = lane; jl < m; jl += 64) {
            float p = expf(lg[jl * heads + h] - mx);
            lg[jl * heads + h] = p;
            sm += p;
        }
        for (int o = 32; o; o >>= 1) sm += __shfl_xor(sm, o);
        if (lane == 0) hsum[h] = sm;
    }
    __syncthreads();
    for (int o = tid; o < 512; o += TPB) {
        int hh = o >> 7;
        float acc = 0.f;
        for (int jl = 0; jl < m; ++jl)
            acc += lg[jl * heads + hh] * bf2f(hf[(size_t)idx[jl] * 512 + o]);
        float v = acc / hsum[hh] + bias[o];
        v = (v > 0.f) ? v : expm1f(v);
        out[(size_t)i * 512 + o] = v;
    }
}

// layer-2 GAT: fp32 features, +residual
__global__ void gat_sparse(const int* __restrict__ nbr, const int* __restrict__ ncnt, int n,
                           const float* __restrict__ hf, const float* __restrict__ es,
                           const float* __restrict__ ed, const float* __restrict__ bias,
                           const float* __restrict__ resid, float* __restrict__ out) {
    int i = blockIdx.x;
    int tid = threadIdx.x;
    __shared__ int idx[MAXN];
    __shared__ float lg[MAXN];
    __shared__ float hmax1, hsum1;
    int m = ncnt[i];
    for (int t = tid; t < m; t += TPB) idx[t] = nbr[i * MAXN + t];
    __syncthreads();
    for (int t = tid; t < m; t += TPB) {
        float l = ed[i] + es[idx[t]];
        lg[t] = (l > 0.f) ? l : 0.2f * l;
    }
    __syncthreads();
    int lane = tid & 63;
    if (tid < 64) {
        float mx = -3.4e38f;
        for (int jl = lane; jl < m; jl += 64) mx = fmaxf(mx, lg[jl]);
        for (int o = 32; o; o >>= 1) mx = fmaxf(mx, __shfl_xor(mx, o));
        if (lane == 0) hmax1 = mx;
    }
    __syncthreads();
    if (tid < 64) {
        float mx = hmax1;
        float sm = 0.f;
        for (int jl = lane; jl < m; jl += 64) {
            float p = expf(lg[jl] - mx);
            lg[jl] = p;
            sm += p;
        }
        for (int o = 32; o; o >>= 1) sm += __shfl_xor(sm, o);
        if (lane == 0) hsum1 = sm;
    }
    __syncthreads();
    for (int o = tid; o < 128; o += TPB) {
        float acc = 0.f;
        for (int jl = 0; jl < m; ++jl)
            acc += lg[jl] * hf[(size_t)idx[jl] * 128 + o];
        out[(size_t)i * 128 + o] = acc / hsum1 + bias[o] + resid[(size_t)i * 128 + o];
    }
}

// ---------------------------------------------------------------------------
static inline int cdiv(int a, int b) { return (a + b - 1) / b; }

static int pick_z(int gx, int gy, int K) {
    int z = 1;
    while (gx * gy * z < 384 && K / (2 * z) >= 64) z <<= 1;
    return z;
}

static void run_gcn_dense(hipStream_t stream, const ushort* Ahi, const ushort* Alo,
                          int n, const float* xsrc, const int* perm, const float* vals,
                          const float* hprev, const int* invp, int mode,
                          const float* W, const float* bias,
                          const float* dinv, const float* selfw,
                          float* xw, ushort* yThi, ushort* yTlo, float* Cp,
                          float* out, int relu) {
    fused_in_gemm<<<n / 4, TPB, 0, stream>>>(xsrc, perm, vals, hprev, invp, W, dinv,
                                             xw, yThi, yTlo, Cp, n, mode);
    int z = pick_z(1, n / 64, n);
    gcn_gemm<<<dim3(1, n / 64, z), TPB, 0, stream>>>(Ahi, Alo, yThi, yTlo, Cp, n, 64, n / z);
    gcn_epilogue<<<cdiv(n * 64, TPB), TPB, 0, stream>>>(Cp, xw, dinv, selfw, bias, out, n, 64, relu);
}

static void run_topk(hipStream_t stream, const float* score, int n, int k, int* rank,
                     int* perm, float* vals, int* invp) {
    rank_count<<<dim3(n / 256, n / 256), 256, 0, stream>>>(score, n, rank);
    scatter_topk_all<<<cdiv(n, TPB), TPB, 0, stream>>>(score, rank, n, k, perm, vals, invp);
}

static void run_aug_dense(hipStream_t stream, const ushort* Ahi, const ushort* Alo, int n,
                          const int* perm, int k, ushort* Tbf, ushort* Agb, ushort* Bgb,
                          float* Caug, ushort* Chi, ushort* Clo, float* dinv, float* selfw) {
    transpose_aug_hl<<<dim3(n / 64, n / 64), TPB, 0, stream>>>(Ahi, Alo, Tbf, n);
    gather_both<<<dim3(cdiv(k * n, TPB), 2), TPB, 0, stream>>>(Ahi, Alo, Tbf, perm,
                                                               Agb, Bgb, Caug, n, k);
    int z = 8;
    aug_gemm_acc<<<dim3(k / 64, k / 64, z), TPB, 0, stream>>>(Agb, Bgb, Caug, n, k, n / z);
    aug_finalize<<<k, TPB, 0, stream>>>(Caug, k, Chi, Clo, dinv, selfw);
}

extern "C" void kernel_launch(void* const* d_in, const int* in_sizes, int n_in,
                              void* d_out, int out_size, void* d_ws, size_t ws_size,
                              hipStream_t stream) {
    const float* x   = (const float*)d_in[0];
    const int*   ei  = (const int*)d_in[1];
    const float* w0  = (const float*)d_in[2];  const float* b0  = (const float*)d_in[3];
    const float* w1  = (const float*)d_in[4];  const float* b1  = (const float*)d_in[5];
    const float* w2  = (const float*)d_in[6];  const float* b2  = (const float*)d_in[7];
    const float* w3  = (const float*)d_in[8];  const float* b3  = (const float*)d_in[9];
    const float* p1  = (const float*)d_in[10];
    const float* p2  = (const float*)d_in[11];
    const float* p3  = (const float*)d_in[12];
    const float* uw0 = (const float*)d_in[13]; const float* ub0 = (const float*)d_in[14];
    const float* uw1 = (const float*)d_in[15]; const float* ub1 = (const float*)d_in[16];
    const float* uw2 = (const float*)d_in[17]; const float* ub2 = (const float*)d_in[18];
    const float* lng = (const float*)d_in[19]; const float* lnb = (const float*)d_in[20];
    const float* rw  = (const float*)d_in[21]; const float* rb  = (const float*)d_in[22];
    const float* g1w = (const float*)d_in[23];
    const float* g1as = (const float*)d_in[24]; const float* g1ad = (const float*)d_in[25];
    const float* g1b = (const float*)d_in[26];
    const float* g2w = (const float*)d_in[27];
    const float* g2as = (const float*)d_in[28]; const float* g2ad = (const float*)d_in[29];
    const float* g2b = (const float*)d_in[30];

    const int N = 4096, E = 65536;
    const int K1 = 2048, K2 = 1024, K3 = 512;

    float* base = (float*)d_ws;
    size_t off = 0;
    auto alloc = [&](size_t nf) { float* p = base + off; off += (nf + 63) & ~(size_t)63; return p; };

    ushort* A1hi = (ushort*)alloc((size_t)K1 * K1 / 2);
    ushort* A1lo = (ushort*)alloc((size_t)K1 * K1 / 2);
    ushort* A2hi = (ushort*)alloc((size_t)K2 * K2 / 2);
    ushort* A2lo = (ushort*)alloc((size_t)K2 * K2 / 2);
    ushort* A3hi = (ushort*)alloc((size_t)K3 * K3 / 2);
    ushort* A3lo = (ushort*)alloc((size_t)K3 * K3 / 2);
    ushort* Tbf  = (ushort*)alloc((size_t)K1 * K1 / 2);
    ushort* Agb  = (ushort*)alloc((size_t)K2 * K1 / 2);
    ushort* Bgb  = (ushort*)alloc((size_t)K2 * K1 / 2);
    ushort* yThi = (ushort*)alloc((size_t)64 * N / 2);
    ushort* yTlo = (ushort*)alloc((size_t)64 * N / 2);
    ushort* W1hi = (ushort*)alloc((size_t)128 * 128 / 2);
    ushort* W1lo = (ushort*)alloc((size_t)128 * 128 / 2);
    ushort* W2hi = (ushort*)alloc((size_t)512 * 128 / 2);
    ushort* W2lo = (ushort*)alloc((size_t)512 * 128 / 2);
    ushort* W3hi = (ushort*)alloc((size_t)128 * 512 / 2);
    ushort* W3lo = (ushort*)alloc((size_t)128 * 512 / 2);
    float* Caug  = alloc((size_t)K2 * K2);
    float* Cp    = alloc((size_t)N * 64);
    float* x0    = alloc((size_t)N * 64);
    float* x1    = alloc((size_t)K1 * 64);
    float* x2    = alloc((size_t)K2 * 64);
    float* x3    = alloc((size_t)K3 * 64);
    float* h2    = alloc((size_t)K2 * 64);
    float* h1    = alloc((size_t)K1 * 64);
    float* xw    = alloc((size_t)N * 128);
    float* dinv0 = alloc(N);  float* selfw0 = alloc(N);
    float* dinv1 = alloc(K1); float* selfw1 = alloc(K1);
    float* dinv2 = alloc(K2); float* selfw2 = alloc(K2);
    float* dinv3 = alloc(K3); float* selfw3 = alloc(K3);
    int*   cursor= (int*)alloc(N);
    int*   buck  = (int*)alloc((size_t)N * MAXN);
    float* score = alloc(N);
    int*   rank  = (int*)alloc(N);
    float* vals1 = alloc(K1); float* vals2 = alloc(K2); float* vals3 = alloc(K3);
    int*   perm1 = (int*)alloc(K1); int* perm2 = (int*)alloc(K2); int* perm3 = (int*)alloc(K3);
    int*   invp1 = (int*)alloc(N);  int* invp2 = (int*)alloc(K1); int* invp3 = (int*)alloc(K2);
    int*   nbr   = (int*)alloc((size_t)N * MAXN);
    float* awt   = alloc((size_t)N * MAXN);
    int*   acnt  = (int*)alloc(N);
    float* u     = alloc((size_t)N * 128);
    float* resid = alloc((size_t)N * 128);
    ushort* hf1b = (ushort*)alloc((size_t)N * 512 / 2);
    float* es1   = alloc((size_t)N * 4); float* ed1 = alloc((size_t)N * 4);
    float* g1    = alloc((size_t)N * 512);
    float* hf2   = alloc((size_t)N * 128);
    float* es2   = alloc(N); float* ed2 = alloc(N);
    (void)ws_size; (void)n_in; (void)in_sizes; (void)out_size;

    // ---- weight prep (independent of UNet) ----
    prep_weights<<<36, TPB, 0, stream>>>(rw, g1w, g2w, W1hi, W1lo, W2hi, W2lo, W3hi, W3lo);

    // ---- CSR build ----
    hipMemsetAsync(cursor, 0, N * sizeof(int), stream);
    bucket_scatter<<<cdiv(E, TPB), TPB, 0, stream>>>(ei, E, buck, cursor);
    build_csr<<<N, 64, 0, stream>>>(buck, cursor, N, nbr, awt, acnt, dinv0, selfw0);

    // ---- down level 0 (sparse) ----
    xw_gemm<<<cdiv(N, TPB / 64), TPB, 0, stream>>>(x, w0, xw, N, 3, 64);
    spmv_gcn<<<N, 64, 0, stream>>>(nbr, awt, acnt, xw, dinv0, selfw0, b0, x0, 64, 1);

    // ---- level 1: topk + sparse SpGEMM augment ----
    score_kernel2<<<cdiv(N, TPB), TPB, 0, stream>>>(x0, p1, score, rank, N);
    run_topk(stream, score, N, K1, rank, perm1, vals1, invp1);
    spgemm_aug<<<K1, TPB, 0, stream>>>(nbr, awt, acnt, perm1, invp1, K1,
                                       A1hi, A1lo, dinv1, selfw1);
    run_gcn_dense(stream, A1hi, A1lo, K1, x0, perm1, vals1, nullptr, nullptr, 0,
                  w1, b1, dinv1, selfw1, xw, yThi, yTlo, Cp, x1, 1);

    // ---- level 2 (dense split-K augment) ----
    score_kernel2<<<cdiv(K1, TPB), TPB, 0, stream>>>(x1, p2, score, rank, K1);
    run_topk(stream, score, K1, K2, rank, perm2, vals2, invp2);
    run_aug_dense(stream, A1hi, A1lo, K1, perm2, K2, Tbf, Agb, Bgb, Caug,
                  A2hi, A2lo, dinv2, selfw2);
    run_gcn_dense(stream, A2hi, A2lo, K2, x1, perm2, vals2, nullptr, nullptr, 0,
                  w2, b2, dinv2, selfw2, xw, yThi, yTlo, Cp, x2, 1);

    // ---- level 3 (dense split-K augment) ----
    score_kernel2<<<cdiv(K2, TPB), TPB, 0, stream>>>(x2, p3, score, rank, K2);
    run_topk(stream, score, K2, K3, rank, perm3, vals3, invp3);
    run_aug_dense(stream, A2hi, A2lo, K2, perm3, K3, Tbf, Agb, Bgb, Caug,
                  A3hi, A3lo, dinv3, selfw3);
    run_gcn_dense(stream, A3hi, A3lo, K3, x2, perm3, vals3, nullptr, nullptr, 0,
                  w3, b3, dinv3, selfw3, xw, yThi, yTlo, Cp, x3, 1);

    // ---- up path (fused unpool inside projection) ----
    run_gcn_dense(stream, A2hi, A2lo, K2, x2, nullptr, nullptr, x3, invp3, 1,
                  uw0, ub0, dinv2, selfw2, xw, yThi, yTlo, Cp, h2, 1);

    run_gcn_dense(stream, A1hi, A1lo, K1, x1, nullptr, nullptr, h2, invp2, 1,
                  uw1, ub1, dinv1, selfw1, xw, yThi, yTlo, Cp, h1, 1);

    xw_gemm_unpool<<<N / 2, TPB, 0, stream>>>(x0, h1, invp1, uw2, xw, N);
    spmv_gcn_ln<<<N, 128, 0, stream>>>(nbr, awt, acnt, xw, dinv0, selfw0, ub2, lng, lnb, u);

    // ---- resid + hf1(bf16) projection (combined) ----
    gemm_bt_multi<<<dim3(10, N / 64), TPB, 0, stream>>>(u, W1hi, W1lo, rb, resid,
                                                        W2hi, W2lo, hf1b);

    // ---- GAT layer 1 (4 heads, concat, ELU; zeroes hf2) ----
    attn_coef2_b16<<<N, 256, 0, stream>>>(hf1b, g1as, g1ad, es1, ed1, 4);
    gat_sparse_b16<<<N, TPB, 0, stream>>>(nbr, acnt, N, hf1b, es1, ed1, g1b, g1, hf2);

    // ---- GAT layer 2 (1 head) + residual ----
    gemm_bt_split<<<dim3(2, N / 64, 4), TPB, 0, stream>>>(g1, W3hi, W3lo, hf2, 512, 128, 128);
    attn_coef2<<<N, 64, 0, stream>>>(hf2, g2as, g2ad, es2, ed2, 1);
    gat_sparse<<<N, TPB, 0, stream>>>(nbr, acnt, N, hf2, es2, ed2, g2b, resid, (float*)d_out);
}